// Round 3
// baseline (456.113 us; speedup 1.0000x reference)
//
#include <hip/hip_runtime.h>
#include <hip/hip_bf16.h>

#define B_ 16
#define T_ 12
#define N_ 2000
#define E_ 8000
#define M_ 32000                 // B_*N_
#define ETOT (B_*E_ + M_)        // 160000 edges incl. self loops
#define D_ 64

typedef __hip_bfloat16 bf16;
typedef unsigned short u16;
typedef __attribute__((ext_vector_type(8))) _Float16 half8;
typedef __attribute__((ext_vector_type(2))) _Float16 h2v;
typedef __attribute__((ext_vector_type(4))) float f32x4;

__device__ __forceinline__ float bfu(u16 u){ return __uint_as_float(((unsigned int)u)<<16); }
__device__ __forceinline__ u16 f2bu(float f){
  unsigned int x = __float_as_uint(f);
  x += 0x7FFFu + ((x >> 16) & 1u);
  return (u16)(x >> 16);
}
__device__ __forceinline__ u16 f2h(float f){
  _Float16 h = (_Float16)f; u16 r; __builtin_memcpy(&r, &h, 2); return r;
}
__device__ __forceinline__ float h2f(u16 u){
  _Float16 h; __builtin_memcpy(&h, &u, 2); return (float)h;
}
__device__ __forceinline__ h2v u2h(unsigned u){ h2v r; __builtin_memcpy(&r,&u,4); return r; }
__device__ __forceinline__ unsigned pkh2(float a, float b){
  return (unsigned)f2h(a) | ((unsigned)f2h(b)<<16);
}

// ---------------- weight prep: f16 MFMA B-fragments + PE table ----------------
__global__ void k_prep(const float* __restrict__ Wqkv, const float* __restrict__ Wo,
                       const float* __restrict__ Wf1, const float* __restrict__ Wf2,
                       u16* __restrict__ wqB, u16* __restrict__ woB,
                       u16* __restrict__ w1B, u16* __restrict__ w2B,
                       float* __restrict__ peT){
  int i = blockIdx.x*256 + threadIdx.x;    // 260 blocks
  if(i < 24576){
    int l=i/12288, r=i-l*12288;
    int nt=r>>10, r2=r&1023, c=r2>>9, r3=r2&511, lane=r3>>3, jj=r3&7;
    int m=lane&15, q=lane>>4;
    wqB[i] = f2h(Wqkv[l*12288 + (nt*16+m)*64 + c*32 + q*8 + jj]);
  } else if(i < 32768){
    int k2=i-24576;
    int l=k2>>12, r=k2&4095;
    int nt=r>>10, r2=r&1023, c=r2>>9, r3=r2&511, lane=r3>>3, jj=r3&7;
    int m=lane&15, q=lane>>4;
    woB[k2] = f2h(Wo[l*4096 + (nt*16+m)*64 + c*32 + q*8 + jj]);
  } else if(i < 49152){
    int k2=i-32768;
    int l=k2>>13, r=k2&8191;
    int nt=r>>10, r2=r&1023, c=r2>>9, r3=r2&511, lane=r3>>3, jj=r3&7;
    int m=lane&15, q=lane>>4;
    w1B[k2] = f2h(Wf1[l*8192 + (nt*16+m)*64 + c*32 + q*8 + jj]);
  } else if(i < 65536){
    int k2=i-49152;
    int l=k2>>13, r=k2&8191;
    int nt=r>>11, r2=r&2047, c=r2>>9, r3=r2&511, lane=r3>>3, jj=r3&7;
    int m=lane&15, q=lane>>4;
    w2B[k2] = f2h(Wf2[l*8192 + (nt*16+m)*128 + c*32 + q*8 + jj]);
  } else {
    int i2 = i - 65536;
    if(i2 < 768){
      int t=i2>>6, ch=i2&63;
      float ang = (float)t * __expf(-0.14391156463f * (float)(ch & ~1));
      peT[i2] = (ch&1) ? __cosf(ang) : __sinf(ang);
    }
  }
}

// ---------------- CSR build ----------------
__global__ void k_hist(const int* __restrict__ ei, int* __restrict__ deg){
  int e = blockIdx.x*256 + threadIdx.x; if(e>=ETOT) return;
  int dst;
  if (e < B_*E_){ int b = e / E_; int k = e - b*E_; dst = ei[E_ + k] + b*N_; }
  else dst = e - B_*E_;
  atomicAdd(&deg[dst], 1);
}

__global__ void k_scan1(const int* __restrict__ deg, int* __restrict__ offs, int* __restrict__ bsums){
  __shared__ int s[256];
  int tid = threadIdx.x; int g = blockIdx.x*256 + tid;
  s[tid] = deg[g]; __syncthreads();
  for(int off=1; off<256; off<<=1){
    int a = (tid>=off) ? s[tid-off] : 0; __syncthreads();
    s[tid] += a; __syncthreads();
  }
  offs[g+1] = s[tid];
  if(tid==255) bsums[blockIdx.x] = s[255];
}

__global__ void k_scan2(const int* __restrict__ bsums, int* __restrict__ boffs){
  __shared__ int s[128];
  int tid = threadIdx.x;
  int v = (tid<125) ? bsums[tid] : 0;
  s[tid] = v; __syncthreads();
  for(int off=1; off<128; off<<=1){
    int a = (tid>=off) ? s[tid-off] : 0; __syncthreads();
    s[tid] += a; __syncthreads();
  }
  if(tid<125) boffs[tid] = s[tid] - v;
}

__global__ void k_scan3(int* __restrict__ offs, const int* __restrict__ boffs){
  int tid = threadIdx.x; int g = blockIdx.x*256 + tid;
  offs[g+1] += boffs[blockIdx.x];
  if(g==0) offs[0]=0;
}

// csr stores LOCAL src index (all edges intra-graph) -> gat kernels skip /N_
__global__ void k_scatter(const int* __restrict__ ei, const int* __restrict__ offs,
                          int* __restrict__ cursor, int* __restrict__ csr){
  int e = blockIdx.x*256 + threadIdx.x; if(e>=ETOT) return;
  int srcl, dst;
  if (e < B_*E_){ int b=e/E_; int k=e-b*E_; srcl=ei[k]; dst=ei[E_+k]+b*N_; }
  else { dst = e - B_*E_; int b=dst/N_; srcl = dst - b*N_; }
  int pos = atomicAdd(&cursor[dst], 1);
  csr[offs[dst]+pos] = srcl;
}

// ---------------- fused GAT1 + GAT2 feature/score ----------------
// W2 staged as packed-f16 [c=64][k2=16] h2 pairs, PITCH 17 words: without the
// pad all 64 lanes land in one bank (l4*256 % 32 == 0) -> 4-way conflict on
// every read (round-2 regression). Pitch 17 -> 2-way max (free).
__global__ __launch_bounds__(256) void k_gat12(
  const float* __restrict__ x_seq, const float* __restrict__ W1,
  const float* __restrict__ as1, const float* __restrict__ ad1, const float* __restrict__ b1,
  const float* __restrict__ W2, const float* __restrict__ as2, const float* __restrict__ ad2,
  const int* __restrict__ offs, const int* __restrict__ csr,
  u16* __restrict__ h2u, float* __restrict__ asc, float* __restrict__ adc)
{
  __shared__ unsigned W2h[1088];    // [c=64][k2=16] pitch 17
  __shared__ float a2s[64], a2d[64];
  int tid = threadIdx.x;
  for(int i=tid;i<1024;i+=256){
    int c=i>>4, k2=i&15;
    W2h[c*17+k2] = pkh2(W2[(2*k2)*64+c], W2[(2*k2+1)*64+c]);
  }
  if(tid<64){ a2s[tid]=as2[tid]; a2d[tid]=ad2[tid]; }
  __syncthreads();

  int t = blockIdx.y;
  int id = blockIdx.x*256 + tid;     // 500*256 = M_*4
  int m = id>>2, l4 = id&3;

  float sS[4], sD[4];
  #pragma unroll
  for(int h=0;h<4;h++){
    float a=0.f, d=0.f;
    #pragma unroll
    for(int c=0;c<8;c++){ float w=W1[h*8+c]; a+=w*as1[h*8+c]; d+=w*ad1[h*8+c]; }
    sS[h]=a; sD[h]=d;
  }
  unsigned um=(unsigned)m, b=um/N_, n=um-b*N_;
  const float* xsl = x_seq + (size_t)(b*T_+t)*N_;
  float xm = xsl[n];
  int e0=offs[m], e1=offs[m+1];
  float sum[4]={0,0,0,0}, ax[4]={0,0,0,0};
  for(int e=e0+l4; e<e1; e+=4){
    float xv = xsl[csr[e]];           // csr holds local index
    #pragma unroll
    for(int h=0;h<4;h++){
      float ee = xv*sS[h] + xm*sD[h]; ee = ee>0.f ? ee : 0.2f*ee;
      float w = __expf(ee); sum[h]+=w; ax[h]+=w*xv;
    }
  }
  float A[4];
  #pragma unroll
  for(int h=0;h<4;h++){
    sum[h] += __shfl_xor(sum[h],1); sum[h] += __shfl_xor(sum[h],2);
    ax[h]  += __shfl_xor(ax[h],1);  ax[h]  += __shfl_xor(ax[h],2);
    A[h] = ax[h]/(sum[h]+1e-16f);
  }

  // v[k] = relu(out1)[k] packed to f16 pairs
  unsigned vh[16];
  #pragma unroll
  for(int k2=0;k2<16;k2++){
    int k = 2*k2;
    float v0 = A[k>>3]*W1[k] + b1[k];       v0 = v0>0.f ? v0 : 0.f;
    float v1 = A[(k+1)>>3]*W1[k+1] + b1[k+1]; v1 = v1>0.f ? v1 : 0.f;
    vh[k2] = pkh2(v0, v1);
  }
  float acc[16];
  #pragma unroll
  for(int c=0;c<16;c++){
    const unsigned* wr = &W2h[(l4*16+c)*17];
    float d=0.f;
    #pragma unroll
    for(int k2=0;k2<16;k2++)
      d = __builtin_amdgcn_fdot2(u2h(vh[k2]), u2h(wr[k2]), d, false);
    acc[c]=d;
  }
  uint2* hp = (uint2*)(h2u + ((size_t)t*M_ + m)*64 + l4*16);
  #pragma unroll
  for(int c2=0;c2<4;c2++){
    uint2 p;
    p.x = pkh2(acc[4*c2+0], acc[4*c2+1]);
    p.y = pkh2(acc[4*c2+2], acc[4*c2+3]);
    hp[c2] = p;
  }
  float ss=0.f, sd=0.f;
  #pragma unroll
  for(int c=0;c<16;c++){ ss += acc[c]*a2s[l4*16+c]; sd += acc[c]*a2d[l4*16+c]; }
  asc[((size_t)t*M_+m)*4+l4]=ss; adc[((size_t)t*M_+m)*4+l4]=sd;
}

// ---------------- GAT2 softmax-aggregate + bias + relu + PE(table); f16 out ------
__global__ __launch_bounds__(256) void k_gat2b(
  const u16* __restrict__ h2u, const float* __restrict__ asc, const float* __restrict__ adc,
  const float* __restrict__ b2, const int* __restrict__ offs, const int* __restrict__ csr,
  const float* __restrict__ peT, u16* __restrict__ seq)
{
  int t = blockIdx.y;
  int id = blockIdx.x*256 + threadIdx.x;
  int m = id>>2, h = id&3;
  unsigned um=(unsigned)m, b=um/N_;
  size_t base_s = (size_t)t*M_ + (size_t)b*N_;   // csr holds local indices
  float am = adc[((size_t)t*M_+m)*4+h];
  int e0=offs[m], e1=offs[m+1];
  float sum=0.f;
  float A[16];
  #pragma unroll
  for(int c=0;c<16;c++) A[c]=0.f;
  for(int e=e0;e<e1;e++){
    size_t s = base_s + (unsigned)csr[e];
    float ee = asc[s*4+h] + am; ee = ee>0.f ? ee : 0.2f*ee;
    float w = __expf(ee); sum += w;
    const uint2* hp = (const uint2*)(h2u + s*64 + h*16);
    #pragma unroll
    for(int c2=0;c2<4;c2++){
      uint2 p = hp[c2];
      h2v lo = u2h(p.x), hi = u2h(p.y);
      A[4*c2+0] += w*(float)lo[0];
      A[4*c2+1] += w*(float)lo[1];
      A[4*c2+2] += w*(float)hi[0];
      A[4*c2+3] += w*(float)hi[1];
    }
  }
  float inv = 1.f/(sum + 1e-16f);
  #pragma unroll
  for(int c=0;c<16;c++){
    int ch = h*16 + c;
    float v = A[c]*inv + b2[ch]; v = v>0.f ? v : 0.f;
    seq[((size_t)t*M_ + m)*64 + ch] = f2h(v + peT[t*64+ch]);
  }
}

// ---------------- BOTH transformer layers in one kernel (R16-measured form) -------
// X u16 [48][72]: layer input (wave-private rows). QKV u16 [3][48][72]; K,V
// overlaid by H[48][136]. A = activations (standard orientation; the operand
// swap was tried TWICE [R17, round-1] and both times tripled LDS bank
// conflicts and regressed -- do not retry). Layer-1 Wo residual comes from
// f32 registers (xres, saved at LN2 of layer 0) instead of re-reading X LDS.
__global__ __launch_bounds__(192) void k_layer2(
  u16* __restrict__ seq,
  const u16* __restrict__ wqB, const u16* __restrict__ woB,
  const u16* __restrict__ w1B, const u16* __restrict__ w2B,
  const float* __restrict__ bqkv, const float* __restrict__ bo,
  const float* __restrict__ bf1,  const float* __restrict__ bf2,
  const float* __restrict__ g1,   const float* __restrict__ be1,
  const float* __restrict__ g2,   const float* __restrict__ be2)
{
  __shared__ __align__(16) u16 X[3456];      // [48][72] f16
  __shared__ __align__(16) u16 QKV[10368];   // [3][48][72]
  u16* Hd = QKV + 3456;                      // H[48][136] overlays K,V
  int tid=threadIdx.x, w=tid>>6, lane=tid&63;
  int m=lane&15, q=lane>>4;
  int r = w*16 + m;

  int trr[4]; size_t base_rr[4];
  #pragma unroll
  for(int rg=0;rg<4;rg++){
    int rc = w*16 + q*4 + rg;
    int nn = rc/12; trr[rg] = rc - nn*12;
    base_rr[rg] = ((size_t)trr[rg]*M_ + (size_t)blockIdx.x*4 + nn)*64;
  }

  // stage X: wave w loads its own 16 rows (wave-private, no barrier needed)
  #pragma unroll
  for(int rr=0; rr<16; rr++){
    int row = w*16+rr;
    int nn = row/12, tt = row-nn*12;
    X[row*72+lane] = seq[((size_t)tt*M_ + (size_t)blockIdx.x*4+nn)*64 + lane];
  }

  float xres[4][4];   // layer-1 Wo residual: (row w*16+q*4+rg, col nt*16+m)

  #pragma unroll 1
  for(int l=0; l<2; l++){
    const half8* wqv = (const half8*)(wqB + (size_t)l*12288);
    const half8* wov = (const half8*)(woB + (size_t)l*4096);
    const half8* w1v = (const half8*)(w1B + (size_t)l*8192);
    const half8* w2v = (const half8*)(w2B + (size_t)l*8192);
    const float* bq = bqkv + l*192;
    const float* boL = bo + l*64;
    const float* b1L = bf1 + l*128;
    const float* b2L = bf2 + l*64;
    const float* g1L = g1 + l*64, *be1L = be1 + l*64;
    const float* g2L = g2 + l*64, *be2L = be2 + l*64;

    // ---- QKV projection: A-frags from X (wave-own rows) ----
    half8 xa0 = *(const half8*)&X[r*72 + q*8];
    half8 xa1 = *(const half8*)&X[r*72 + 32 + q*8];
    #pragma unroll
    for(int nt=0; nt<12; nt++){
      f32x4 acc={0.f,0.f,0.f,0.f};
      acc = __builtin_amdgcn_mfma_f32_16x16x32_f16(xa0, wqv[(nt*2+0)*64+lane], acc,0,0,0);
      acc = __builtin_amdgcn_mfma_f32_16x16x32_f16(xa1, wqv[(nt*2+1)*64+lane], acc,0,0,0);
      int cg = nt*16+m; float bias = bq[cg];
      int s = nt>>2, lc = cg&63;
      #pragma unroll
      for(int rg=0;rg<4;rg++){
        int row = w*16 + q*4 + rg;
        QKV[s*3456 + row*72 + lc] = f2h(acc[rg]+bias);
      }
    }
    __syncthreads();

    // ---- attention: 192 lanes = (node an, head ah, time at); fdot2 + pk_fma ----
    {
      int an = tid/48, rem = tid - an*48;
      int ah = rem/12, at = rem - ah*12;
      u16* qrow = &QKV[(an*12+at)*72 + ah*16];
      uint4 qa = ((const uint4*)qrow)[0], qb = ((const uint4*)qrow)[1];
      float s[12];
      #pragma unroll
      for(int t2=0;t2<12;t2++){
        const uint4* kp = (const uint4*)&QKV[3456 + (an*12+t2)*72 + ah*16];
        uint4 ka=kp[0], kb=kp[1];
        float d=0.f;
        d=__builtin_amdgcn_fdot2(u2h(qa.x),u2h(ka.x),d,false);
        d=__builtin_amdgcn_fdot2(u2h(qa.y),u2h(ka.y),d,false);
        d=__builtin_amdgcn_fdot2(u2h(qa.z),u2h(ka.z),d,false);
        d=__builtin_amdgcn_fdot2(u2h(qa.w),u2h(ka.w),d,false);
        d=__builtin_amdgcn_fdot2(u2h(qb.x),u2h(kb.x),d,false);
        d=__builtin_amdgcn_fdot2(u2h(qb.y),u2h(kb.y),d,false);
        d=__builtin_amdgcn_fdot2(u2h(qb.z),u2h(kb.z),d,false);
        d=__builtin_amdgcn_fdot2(u2h(qb.w),u2h(kb.w),d,false);
        s[t2] = d*0.25f;
      }
      float mx=s[0];
      #pragma unroll
      for(int t2=1;t2<12;t2++) mx=fmaxf(mx,s[t2]);
      float sum=0.f;
      #pragma unroll
      for(int t2=0;t2<12;t2++){ s[t2]=__expf(s[t2]-mx); sum+=s[t2]; }
      float inv=1.f/sum;
      half8 o0, o1;
      #pragma unroll
      for(int i=0;i<8;i++){ o0[i]=(_Float16)0.f; o1[i]=(_Float16)0.f; }
      #pragma unroll
      for(int t2=0;t2<12;t2++){
        const half8* vr = (const half8*)&QKV[6912 + (an*12+t2)*72 + ah*16];
        _Float16 wh = (_Float16)s[t2];
        o0 += vr[0]*wh; o1 += vr[1]*wh;
      }
      _Float16 ih = (_Float16)inv;
      ((half8*)qrow)[0]=o0*ih; ((half8*)qrow)[1]=o1*ih;
    }
    __syncthreads();

    // ---- Wo + residual + LN1 ----
    half8 oa0 = *(const half8*)&QKV[r*72 + q*8];
    half8 oa1 = *(const half8*)&QKV[r*72 + 32 + q*8];
    float y[4][4];
    #pragma unroll
    for(int nt=0;nt<4;nt++){
      f32x4 acc={0.f,0.f,0.f,0.f};
      acc = __builtin_amdgcn_mfma_f32_16x16x32_f16(oa0, wov[(nt*2+0)*64+lane], acc,0,0,0);
      acc = __builtin_amdgcn_mfma_f32_16x16x32_f16(oa1, wov[(nt*2+1)*64+lane], acc,0,0,0);
      int col=nt*16+m; float bias=boL[col];
      #pragma unroll
      for(int rg=0;rg<4;rg++){
        float res = (l==0) ? h2f(X[(w*16+q*4+rg)*72 + col]) : xres[nt][rg];
        y[nt][rg] = acc[rg] + bias + res;
      }
    }
    float mu[4], rs[4];
    #pragma unroll
    for(int rg=0;rg<4;rg++){
      float sm=(y[0][rg]+y[1][rg])+(y[2][rg]+y[3][rg]);
      sm+=__shfl_xor(sm,1); sm+=__shfl_xor(sm,2); sm+=__shfl_xor(sm,4); sm+=__shfl_xor(sm,8);
      mu[rg]=sm*(1.f/64.f);
      float d0=y[0][rg]-mu[rg],d1=y[1][rg]-mu[rg],d2=y[2][rg]-mu[rg],d3=y[3][rg]-mu[rg];
      float vv=(d0*d0+d1*d1)+(d2*d2+d3*d3);
      vv+=__shfl_xor(vv,1); vv+=__shfl_xor(vv,2); vv+=__shfl_xor(vv,4); vv+=__shfl_xor(vv,8);
      rs[rg]=rsqrtf(vv*(1.f/64.f)+1e-5f);
    }
    #pragma unroll
    for(int nt=0;nt<4;nt++){
      int col=nt*16+m; float g=g1L[col], be=be1L[col];
      #pragma unroll
      for(int rg=0;rg<4;rg++){
        float v=(y[nt][rg]-mu[rg])*rs[rg]*g+be;
        y[nt][rg]=v;                                  // FF residual (f32)
        QKV[(w*16+q*4+rg)*72 + col]=f2h(v);           // y -> wave-own rows
      }
    }

    // ---- FF1: y A-frags; H -> pitch-136 overlay ----
    half8 ya0 = *(const half8*)&QKV[r*72 + q*8];
    half8 ya1 = *(const half8*)&QKV[r*72 + 32 + q*8];
    #pragma unroll
    for(int nt=0;nt<8;nt++){
      f32x4 acc={0.f,0.f,0.f,0.f};
      acc = __builtin_amdgcn_mfma_f32_16x16x32_f16(ya0, w1v[(nt*2+0)*64+lane], acc,0,0,0);
      acc = __builtin_amdgcn_mfma_f32_16x16x32_f16(ya1, w1v[(nt*2+1)*64+lane], acc,0,0,0);
      float bias=b1L[nt*16+m];
      #pragma unroll
      for(int rg=0;rg<4;rg++)
        Hd[(w*16+q*4+rg)*136 + nt*16+m] = f2h(fmaxf(acc[rg]+bias, 0.f));
    }

    // ---- FF2 + residual y + LN2 ----
    half8 ha[4];
    #pragma unroll
    for(int c=0;c<4;c++)
      ha[c] = *(const half8*)&Hd[r*136 + c*32 + q*8];
    #pragma unroll
    for(int nt=0;nt<4;nt++){
      f32x4 acc={0.f,0.f,0.f,0.f};
      #pragma unroll
      for(int c=0;c<4;c++)
        acc = __builtin_amdgcn_mfma_f32_16x16x32_f16(ha[c], w2v[(nt*4+c)*64+lane], acc,0,0,0);
      int col=nt*16+m; float bias=b2L[col];
      #pragma unroll
      for(int rg=0;rg<4;rg++)
        y[nt][rg] = acc[rg] + bias + y[nt][rg];
    }
    #pragma unroll
    for(int rg=0;rg<4;rg++){
      float sm=(y[0][rg]+y[1][rg])+(y[2][rg]+y[3][rg]);
      sm+=__shfl_xor(sm,1); sm+=__shfl_xor(sm,2); sm+=__shfl_xor(sm,4); sm+=__shfl_xor(sm,8);
      mu[rg]=sm*(1.f/64.f);
      float d0=y[0][rg]-mu[rg],d1=y[1][rg]-mu[rg],d2=y[2][rg]-mu[rg],d3=y[3][rg]-mu[rg];
      float vv=(d0*d0+d1*d1)+(d2*d2+d3*d3);
      vv+=__shfl_xor(vv,1); vv+=__shfl_xor(vv,2); vv+=__shfl_xor(vv,4); vv+=__shfl_xor(vv,8);
      rs[rg]=rsqrtf(vv*(1.f/64.f)+1e-5f);
    }
    if(l==0){
      #pragma unroll
      for(int nt=0;nt<4;nt++){
        int col=nt*16+m; float g=g2L[col], be=be2L[col];
        #pragma unroll
        for(int rg=0;rg<4;rg++){
          float v = (y[nt][rg]-mu[rg])*rs[rg]*g + be;
          xres[nt][rg] = v;                           // layer-1 residual (f32)
          X[(w*16+q*4+rg)*72 + col] = f2h(v);
        }
      }
      __syncthreads();   // before next layer's QKV scatter overwrites QKV regions
    } else {
      #pragma unroll
      for(int nt=0;nt<4;nt++){
        int col=nt*16+m; float g=g2L[col], be=be2L[col];
        #pragma unroll
        for(int rg=0;rg<4;rg++){
          if(trr[rg]==11)
            seq[base_rr[rg] + col] = f2h((y[nt][rg]-mu[rg])*rs[rg]*g + be);
        }
      }
    }
  }
}

// ---------------- prediction head (f16 seq in) ----------------
__global__ void k_head(const u16* __restrict__ seq, const float* __restrict__ Wh,
                       const float* __restrict__ bh, float* __restrict__ out){
  int m = blockIdx.x*256 + threadIdx.x; if(m>=M_) return;
  const u16* row = seq + ((size_t)11*M_ + m)*64;
  float a0=bh[0], a1=bh[1], a2=bh[2];
  #pragma unroll
  for(int d=0;d<64;d++){
    float x = h2f(row[d]);
    a0 += x*Wh[d]; a1 += x*Wh[64+d]; a2 += x*Wh[128+d];
  }
  unsigned b=(unsigned)m/N_, n=(unsigned)m-b*N_;
  out[(b*3+0)*N_+n] = a0;
  out[(b*3+1)*N_+n] = a1;
  out[(b*3+2)*N_+n] = a2;
}

extern "C" void kernel_launch(void* const* d_in, const int* in_sizes, int n_in,
                              void* d_out, int out_size, void* d_ws, size_t ws_size,
                              hipStream_t stream)
{
  const float* x_seq=(const float*)d_in[0];
  const int*   ei   =(const int*)d_in[1];
  const float* W1   =(const float*)d_in[2];
  const float* as1  =(const float*)d_in[3];
  const float* ad1  =(const float*)d_in[4];
  const float* b1   =(const float*)d_in[5];
  const float* W2   =(const float*)d_in[6];
  const float* as2  =(const float*)d_in[7];
  const float* ad2  =(const float*)d_in[8];
  const float* b2   =(const float*)d_in[9];
  const float* Wqkv =(const float*)d_in[10];
  const float* bqkv =(const float*)d_in[11];
  const float* Wo   =(const float*)d_in[12];
  const float* bo   =(const float*)d_in[13];
  const float* Wf1  =(const float*)d_in[14];
  const float* bf1p =(const float*)d_in[15];
  const float* Wf2  =(const float*)d_in[16];
  const float* bf2p =(const float*)d_in[17];
  const float* g1   =(const float*)d_in[18];
  const float* be1  =(const float*)d_in[19];
  const float* g2   =(const float*)d_in[20];
  const float* be2  =(const float*)d_in[21];
  const float* Wh   =(const float*)d_in[22];
  const float* bh   =(const float*)d_in[23];

  // workspace layout (~112 MB)
  u16* seqh   = (u16*)d_ws;                     // [T][M][64] f16  24,576,000 u16
  float* asc  = (float*)(seqh + 24576000);      // [T][M][4]        1,536,000 f
  float* adc  = asc + 1536000;                  //                  1,536,000 f
  int* deg    = (int*)(adc + 1536000);
  int* cursor = deg + M_;
  int* offs   = cursor + M_;                    // M_+1 used
  int* bsums  = offs + (M_ + 2);
  int* boffs  = bsums + 128;
  int* csr    = boffs + 128;                    // ETOT
  u16* h2u    = (u16*)(csr + ETOT);             // [T][M][64]   24,576,000 u16
  u16* wqB    = h2u + (size_t)T_*M_*64;         // 24576
  u16* woB    = wqB + 24576;                    // 8192
  u16* w1B    = woB + 8192;                     // 16384
  u16* w2B    = w1B + 16384;                    // 16384
  float* peT  = (float*)(w2B + 16384);          // 768

  k_prep   <<<dim3(260), dim3(256), 0, stream>>>(Wqkv, Wo, Wf1, Wf2, wqB, woB, w1B, w2B, peT);

  // CSR build (edge list identical for all t)
  hipMemsetAsync(deg, 0, (size_t)2*M_*sizeof(int), stream);   // deg + cursor
  k_hist   <<<dim3((ETOT+255)/256), dim3(256), 0, stream>>>(ei, deg);
  k_scan1  <<<dim3(125), dim3(256), 0, stream>>>(deg, offs, bsums);
  k_scan2  <<<dim3(1),   dim3(128), 0, stream>>>(bsums, boffs);
  k_scan3  <<<dim3(125), dim3(256), 0, stream>>>(offs, boffs);
  k_scatter<<<dim3((ETOT+255)/256), dim3(256), 0, stream>>>(ei, offs, cursor, csr);

  k_gat12<<<dim3(500,T_), dim3(256), 0, stream>>>(x_seq, W1, as1, ad1, b1,
                                                  W2, as2, ad2, offs, csr, h2u, asc, adc);
  k_gat2b<<<dim3(500,T_), dim3(256), 0, stream>>>(h2u, asc, adc, b2, offs, csr, peT, seqh);

  k_layer2<<<dim3(8000), dim3(192), 0, stream>>>(seqh,
      wqB, woB, w1B, w2B,
      bqkv, bo, bf1p, bf2p,
      g1, be1, g2, be2);

  k_head<<<dim3(125), dim3(256), 0, stream>>>(seqh, Wh, bh, (float*)d_out);
}

// Round 4
// 400.783 us; speedup vs baseline: 1.1381x; 1.1381x over previous
//
#include <hip/hip_runtime.h>
#include <hip/hip_bf16.h>

#define B_ 16
#define T_ 12
#define N_ 2000
#define E_ 8000
#define M_ 32000                 // B_*N_
#define ETOT (B_*E_ + M_)        // 160000 edges incl. self loops
#define D_ 64

typedef __hip_bfloat16 bf16;
typedef unsigned short u16;
typedef __attribute__((ext_vector_type(8))) _Float16 half8;
typedef __attribute__((ext_vector_type(2))) _Float16 h2v;
typedef __attribute__((ext_vector_type(4))) float f32x4;

__device__ __forceinline__ float bfu(u16 u){ return __uint_as_float(((unsigned int)u)<<16); }
__device__ __forceinline__ u16 f2bu(float f){
  unsigned int x = __float_as_uint(f);
  x += 0x7FFFu + ((x >> 16) & 1u);
  return (u16)(x >> 16);
}
__device__ __forceinline__ u16 f2h(float f){
  _Float16 h = (_Float16)f; u16 r; __builtin_memcpy(&r, &h, 2); return r;
}
__device__ __forceinline__ float h2f(u16 u){
  _Float16 h; __builtin_memcpy(&h, &u, 2); return (float)h;
}
__device__ __forceinline__ h2v u2h(unsigned u){ h2v r; __builtin_memcpy(&r,&u,4); return r; }

// ---------------- weight prep: f16 MFMA B-fragments + PE table ----------------
__global__ void k_prep(const float* __restrict__ Wqkv, const float* __restrict__ Wo,
                       const float* __restrict__ Wf1, const float* __restrict__ Wf2,
                       u16* __restrict__ wqB, u16* __restrict__ woB,
                       u16* __restrict__ w1B, u16* __restrict__ w2B,
                       float* __restrict__ peT){
  int i = blockIdx.x*256 + threadIdx.x;    // 260 blocks
  if(i < 24576){
    int l=i/12288, r=i-l*12288;
    int nt=r>>10, r2=r&1023, c=r2>>9, r3=r2&511, lane=r3>>3, jj=r3&7;
    int m=lane&15, q=lane>>4;
    wqB[i] = f2h(Wqkv[l*12288 + (nt*16+m)*64 + c*32 + q*8 + jj]);
  } else if(i < 32768){
    int k2=i-24576;
    int l=k2>>12, r=k2&4095;
    int nt=r>>10, r2=r&1023, c=r2>>9, r3=r2&511, lane=r3>>3, jj=r3&7;
    int m=lane&15, q=lane>>4;
    woB[k2] = f2h(Wo[l*4096 + (nt*16+m)*64 + c*32 + q*8 + jj]);
  } else if(i < 49152){
    int k2=i-32768;
    int l=k2>>13, r=k2&8191;
    int nt=r>>10, r2=r&1023, c=r2>>9, r3=r2&511, lane=r3>>3, jj=r3&7;
    int m=lane&15, q=lane>>4;
    w1B[k2] = f2h(Wf1[l*8192 + (nt*16+m)*64 + c*32 + q*8 + jj]);
  } else if(i < 65536){
    int k2=i-49152;
    int l=k2>>13, r=k2&8191;
    int nt=r>>11, r2=r&2047, c=r2>>9, r3=r2&511, lane=r3>>3, jj=r3&7;
    int m=lane&15, q=lane>>4;
    w2B[k2] = f2h(Wf2[l*8192 + (nt*16+m)*128 + c*32 + q*8 + jj]);
  } else {
    int i2 = i - 65536;
    if(i2 < 768){
      int t=i2>>6, ch=i2&63;
      float ang = (float)t * __expf(-0.14391156463f * (float)(ch & ~1));
      peT[i2] = (ch&1) ? __cosf(ang) : __sinf(ang);
    }
  }
}

// ---------------- CSR build ----------------
__global__ void k_hist(const int* __restrict__ ei, int* __restrict__ deg){
  int e = blockIdx.x*256 + threadIdx.x; if(e>=ETOT) return;
  int dst;
  if (e < B_*E_){ int b = e / E_; int k = e - b*E_; dst = ei[E_ + k] + b*N_; }
  else dst = e - B_*E_;
  atomicAdd(&deg[dst], 1);
}

__global__ void k_scan1(const int* __restrict__ deg, int* __restrict__ offs, int* __restrict__ bsums){
  __shared__ int s[256];
  int tid = threadIdx.x; int g = blockIdx.x*256 + tid;
  s[tid] = deg[g]; __syncthreads();
  for(int off=1; off<256; off<<=1){
    int a = (tid>=off) ? s[tid-off] : 0; __syncthreads();
    s[tid] += a; __syncthreads();
  }
  offs[g+1] = s[tid];
  if(tid==255) bsums[blockIdx.x] = s[255];
}

__global__ void k_scan2(const int* __restrict__ bsums, int* __restrict__ boffs){
  __shared__ int s[128];
  int tid = threadIdx.x;
  int v = (tid<125) ? bsums[tid] : 0;
  s[tid] = v; __syncthreads();
  for(int off=1; off<128; off<<=1){
    int a = (tid>=off) ? s[tid-off] : 0; __syncthreads();
    s[tid] += a; __syncthreads();
  }
  if(tid<125) boffs[tid] = s[tid] - v;
}

__global__ void k_scan3(int* __restrict__ offs, const int* __restrict__ boffs){
  int tid = threadIdx.x; int g = blockIdx.x*256 + tid;
  offs[g+1] += boffs[blockIdx.x];
  if(g==0) offs[0]=0;
}

// csr stores LOCAL src index (all edges intra-graph) -> gat kernels skip /N_
__global__ void k_scatter(const int* __restrict__ ei, const int* __restrict__ offs,
                          int* __restrict__ cursor, int* __restrict__ csr){
  int e = blockIdx.x*256 + threadIdx.x; if(e>=ETOT) return;
  int srcl, dst;
  if (e < B_*E_){ int b=e/E_; int k=e-b*E_; srcl=ei[k]; dst=ei[E_+k]+b*N_; }
  else { dst = e - B_*E_; int b=dst/N_; srcl = dst - b*N_; }
  int pos = atomicAdd(&cursor[dst], 1);
  csr[offs[dst]+pos] = srcl;
}

// ---------------- fused GAT1 + GAT2 feature/score ----------------
__global__ __launch_bounds__(256) void k_gat12(
  const float* __restrict__ x_seq, const float* __restrict__ W1,
  const float* __restrict__ as1, const float* __restrict__ ad1, const float* __restrict__ b1,
  const float* __restrict__ W2, const float* __restrict__ as2, const float* __restrict__ ad2,
  const int* __restrict__ offs, const int* __restrict__ csr,
  u16* __restrict__ h2u, float* __restrict__ asc, float* __restrict__ adc)
{
  __shared__ float W2s[2048];       // [k=32][c=64] fp32
  __shared__ float a2s[64], a2d[64];
  int tid = threadIdx.x;
  for(int i=tid;i<2048;i+=256) W2s[i]=W2[i];
  if(tid<64){ a2s[tid]=as2[tid]; a2d[tid]=ad2[tid]; }
  __syncthreads();

  int t = blockIdx.y;
  int id = blockIdx.x*256 + tid;     // 500*256 = M_*4
  int m = id>>2, l4 = id&3;

  float sS[4], sD[4];
  #pragma unroll
  for(int h=0;h<4;h++){
    float a=0.f, d=0.f;
    #pragma unroll
    for(int c=0;c<8;c++){ float w=W1[h*8+c]; a+=w*as1[h*8+c]; d+=w*ad1[h*8+c]; }
    sS[h]=a; sD[h]=d;
  }
  unsigned um=(unsigned)m, b=um/N_, n=um-b*N_;
  const float* xsl = x_seq + (size_t)(b*T_+t)*N_;
  float xm = xsl[n];
  int e0=offs[m], e1=offs[m+1];
  float sum[4]={0,0,0,0}, ax[4]={0,0,0,0};
  for(int e=e0+l4; e<e1; e+=4){
    float xv = xsl[csr[e]];           // csr holds local index
    #pragma unroll
    for(int h=0;h<4;h++){
      float ee = xv*sS[h] + xm*sD[h]; ee = ee>0.f ? ee : 0.2f*ee;
      float w = __expf(ee); sum[h]+=w; ax[h]+=w*xv;
    }
  }
  float A[4];
  #pragma unroll
  for(int h=0;h<4;h++){
    sum[h] += __shfl_xor(sum[h],1); sum[h] += __shfl_xor(sum[h],2);
    ax[h]  += __shfl_xor(ax[h],1);  ax[h]  += __shfl_xor(ax[h],2);
    A[h] = ax[h]/(sum[h]+1e-16f);
  }

  float acc[16];
  #pragma unroll
  for(int c=0;c<16;c++) acc[c]=0.f;
  #pragma unroll
  for(int k=0;k<32;k++){
    int hs = k>>3;
    float v = A[hs]*W1[k] + b1[k]; v = v>0.f ? v : 0.f;   // relu(out1)
    #pragma unroll
    for(int c=0;c<16;c++) acc[c] += v*W2s[k*64 + l4*16 + c];
  }
  uint2* hp = (uint2*)(h2u + ((size_t)t*M_ + m)*64 + l4*16);
  #pragma unroll
  for(int c2=0;c2<4;c2++){
    uint2 p;
    p.x = (unsigned)f2bu(acc[4*c2+0]) | ((unsigned)f2bu(acc[4*c2+1])<<16);
    p.y = (unsigned)f2bu(acc[4*c2+2]) | ((unsigned)f2bu(acc[4*c2+3])<<16);
    hp[c2] = p;
  }
  float ss=0.f, sd=0.f;
  #pragma unroll
  for(int c=0;c<16;c++){ ss += acc[c]*a2s[l4*16+c]; sd += acc[c]*a2d[l4*16+c]; }
  asc[((size_t)t*M_+m)*4+l4]=ss; adc[((size_t)t*M_+m)*4+l4]=sd;
}

// ---------------- GAT2 softmax-aggregate + bias + relu + PE(table); f16 out ------
__global__ __launch_bounds__(256) void k_gat2b(
  const u16* __restrict__ h2u, const float* __restrict__ asc, const float* __restrict__ adc,
  const float* __restrict__ b2, const int* __restrict__ offs, const int* __restrict__ csr,
  const float* __restrict__ peT, u16* __restrict__ seq)
{
  int t = blockIdx.y;
  int id = blockIdx.x*256 + threadIdx.x;
  int m = id>>2, h = id&3;
  unsigned um=(unsigned)m, b=um/N_;
  size_t base_s = (size_t)t*M_ + (size_t)b*N_;   // csr holds local indices
  float am = adc[((size_t)t*M_+m)*4+h];
  int e0=offs[m], e1=offs[m+1];
  float sum=0.f;
  float A[16];
  #pragma unroll
  for(int c=0;c<16;c++) A[c]=0.f;
  for(int e=e0;e<e1;e++){
    size_t s = base_s + (unsigned)csr[e];
    float ee = asc[s*4+h] + am; ee = ee>0.f ? ee : 0.2f*ee;
    float w = __expf(ee); sum += w;
    const uint2* hp = (const uint2*)(h2u + s*64 + h*16);
    #pragma unroll
    for(int c2=0;c2<4;c2++){
      uint2 p = hp[c2];
      A[4*c2+0] += w*bfu((u16)(p.x));
      A[4*c2+1] += w*bfu((u16)(p.x>>16));
      A[4*c2+2] += w*bfu((u16)(p.y));
      A[4*c2+3] += w*bfu((u16)(p.y>>16));
    }
  }
  float inv = 1.f/(sum + 1e-16f);
  #pragma unroll
  for(int c=0;c<16;c++){
    int ch = h*16 + c;
    float v = A[c]*inv + b2[ch]; v = v>0.f ? v : 0.f;
    seq[((size_t)t*M_ + m)*64 + ch] = f2h(v + peT[t*64+ch]);
  }
}

// ---------------- BOTH transformer layers + fused head (R16-measured form) -------
// X u16 [48][72]: layer input (wave-private rows). QKV u16 [3][48][72]; K,V
// overlaid by H[48][136]. A = activations (standard orientation; the operand
// swap was tried TWICE and both times tripled LDS bank conflicts -- do not
// retry). Register-carried residual (xres) was tried once: VGPR 68->84,
// VALUBusy -15pts, +48us -- do not retry. Changes vs measured-402.7 form:
// (1) X staging via dwordx4 (2 loads vs 16 scalar), (2) head fused into the
// layer-1 epilogue (k_head kernel deleted; head computed from f32 registers).
__global__ __launch_bounds__(192) void k_layer2(
  const u16* __restrict__ seq,
  const u16* __restrict__ wqB, const u16* __restrict__ woB,
  const u16* __restrict__ w1B, const u16* __restrict__ w2B,
  const float* __restrict__ bqkv, const float* __restrict__ bo,
  const float* __restrict__ bf1,  const float* __restrict__ bf2,
  const float* __restrict__ g1,   const float* __restrict__ be1,
  const float* __restrict__ g2,   const float* __restrict__ be2,
  const float* __restrict__ Wh,   const float* __restrict__ bh,
  float* __restrict__ out)
{
  __shared__ __align__(16) u16 X[3456];      // [48][72] f16
  __shared__ __align__(16) u16 QKV[10368];   // [3][48][72]
  u16* Hd = QKV + 3456;                      // H[48][136] overlays K,V
  int tid=threadIdx.x, w=tid>>6, lane=tid&63;
  int m=lane&15, q=lane>>4;
  int r = w*16 + m;

  // stage X: wave w loads its own 16 rows (wave-private, no barrier needed).
  // Each row = 128B = 8 lanes x 16B; 2 dwordx4 loads/lane replace 16 scalar.
  #pragma unroll
  for(int half=0; half<2; half++){
    int rr = half*8 + (lane>>3);
    int row = w*16 + rr;
    int nn = row/12, tt = row-nn*12;
    const uint4* src = (const uint4*)(seq + ((size_t)tt*M_ + (size_t)blockIdx.x*4+nn)*64) + (lane&7);
    *((uint4*)&X[row*72] + (lane&7)) = *src;
  }

  #pragma unroll 1
  for(int l=0; l<2; l++){
    const half8* wqv = (const half8*)(wqB + (size_t)l*12288);
    const half8* wov = (const half8*)(woB + (size_t)l*4096);
    const half8* w1v = (const half8*)(w1B + (size_t)l*8192);
    const half8* w2v = (const half8*)(w2B + (size_t)l*8192);
    const float* bq = bqkv + l*192;
    const float* boL = bo + l*64;
    const float* b1L = bf1 + l*128;
    const float* b2L = bf2 + l*64;
    const float* g1L = g1 + l*64, *be1L = be1 + l*64;
    const float* g2L = g2 + l*64, *be2L = be2 + l*64;

    // ---- QKV projection: A-frags from X (wave-own rows) ----
    half8 xa0 = *(const half8*)&X[r*72 + q*8];
    half8 xa1 = *(const half8*)&X[r*72 + 32 + q*8];
    #pragma unroll
    for(int nt=0; nt<12; nt++){
      f32x4 acc={0.f,0.f,0.f,0.f};
      acc = __builtin_amdgcn_mfma_f32_16x16x32_f16(xa0, wqv[(nt*2+0)*64+lane], acc,0,0,0);
      acc = __builtin_amdgcn_mfma_f32_16x16x32_f16(xa1, wqv[(nt*2+1)*64+lane], acc,0,0,0);
      int cg = nt*16+m; float bias = bq[cg];
      int s = nt>>2, lc = cg&63;
      #pragma unroll
      for(int rg=0;rg<4;rg++){
        int row = w*16 + q*4 + rg;
        QKV[s*3456 + row*72 + lc] = f2h(acc[rg]+bias);
      }
    }
    __syncthreads();

    // ---- attention: 192 lanes = (node an, head ah, time at); fdot2 + pk_fma ----
    {
      int an = tid/48, rem = tid - an*48;
      int ah = rem/12, at = rem - ah*12;
      u16* qrow = &QKV[(an*12+at)*72 + ah*16];
      uint4 qa = ((const uint4*)qrow)[0], qb = ((const uint4*)qrow)[1];
      float s[12];
      #pragma unroll
      for(int t2=0;t2<12;t2++){
        const uint4* kp = (const uint4*)&QKV[3456 + (an*12+t2)*72 + ah*16];
        uint4 ka=kp[0], kb=kp[1];
        float d=0.f;
        d=__builtin_amdgcn_fdot2(u2h(qa.x),u2h(ka.x),d,false);
        d=__builtin_amdgcn_fdot2(u2h(qa.y),u2h(ka.y),d,false);
        d=__builtin_amdgcn_fdot2(u2h(qa.z),u2h(ka.z),d,false);
        d=__builtin_amdgcn_fdot2(u2h(qa.w),u2h(ka.w),d,false);
        d=__builtin_amdgcn_fdot2(u2h(qb.x),u2h(kb.x),d,false);
        d=__builtin_amdgcn_fdot2(u2h(qb.y),u2h(kb.y),d,false);
        d=__builtin_amdgcn_fdot2(u2h(qb.z),u2h(kb.z),d,false);
        d=__builtin_amdgcn_fdot2(u2h(qb.w),u2h(kb.w),d,false);
        s[t2] = d*0.25f;
      }
      float mx=s[0];
      #pragma unroll
      for(int t2=1;t2<12;t2++) mx=fmaxf(mx,s[t2]);
      float sum=0.f;
      #pragma unroll
      for(int t2=0;t2<12;t2++){ s[t2]=__expf(s[t2]-mx); sum+=s[t2]; }
      float inv=1.f/sum;
      half8 o0, o1;
      #pragma unroll
      for(int i=0;i<8;i++){ o0[i]=(_Float16)0.f; o1[i]=(_Float16)0.f; }
      #pragma unroll
      for(int t2=0;t2<12;t2++){
        const half8* vr = (const half8*)&QKV[6912 + (an*12+t2)*72 + ah*16];
        _Float16 wh = (_Float16)s[t2];
        o0 += vr[0]*wh; o1 += vr[1]*wh;
      }
      _Float16 ih = (_Float16)inv;
      ((half8*)qrow)[0]=o0*ih; ((half8*)qrow)[1]=o1*ih;
    }
    __syncthreads();

    // ---- Wo + residual(X) + LN1 ----
    half8 oa0 = *(const half8*)&QKV[r*72 + q*8];
    half8 oa1 = *(const half8*)&QKV[r*72 + 32 + q*8];
    float y[4][4];
    #pragma unroll
    for(int nt=0;nt<4;nt++){
      f32x4 acc={0.f,0.f,0.f,0.f};
      acc = __builtin_amdgcn_mfma_f32_16x16x32_f16(oa0, wov[(nt*2+0)*64+lane], acc,0,0,0);
      acc = __builtin_amdgcn_mfma_f32_16x16x32_f16(oa1, wov[(nt*2+1)*64+lane], acc,0,0,0);
      int col=nt*16+m; float bias=boL[col];
      #pragma unroll
      for(int rg=0;rg<4;rg++)
        y[nt][rg] = acc[rg] + bias + h2f(X[(w*16+q*4+rg)*72 + col]);
    }
    float mu[4], rs[4];
    #pragma unroll
    for(int rg=0;rg<4;rg++){
      float sm=(y[0][rg]+y[1][rg])+(y[2][rg]+y[3][rg]);
      sm+=__shfl_xor(sm,1); sm+=__shfl_xor(sm,2); sm+=__shfl_xor(sm,4); sm+=__shfl_xor(sm,8);
      mu[rg]=sm*(1.f/64.f);
      float d0=y[0][rg]-mu[rg],d1=y[1][rg]-mu[rg],d2=y[2][rg]-mu[rg],d3=y[3][rg]-mu[rg];
      float vv=(d0*d0+d1*d1)+(d2*d2+d3*d3);
      vv+=__shfl_xor(vv,1); vv+=__shfl_xor(vv,2); vv+=__shfl_xor(vv,4); vv+=__shfl_xor(vv,8);
      rs[rg]=rsqrtf(vv*(1.f/64.f)+1e-5f);
    }
    #pragma unroll
    for(int nt=0;nt<4;nt++){
      int col=nt*16+m; float g=g1L[col], be=be1L[col];
      #pragma unroll
      for(int rg=0;rg<4;rg++){
        float v=(y[nt][rg]-mu[rg])*rs[rg]*g+be;
        y[nt][rg]=v;                                  // FF residual (f32)
        QKV[(w*16+q*4+rg)*72 + col]=f2h(v);           // y -> wave-own rows
      }
    }

    // ---- FF1: y A-frags; H -> pitch-136 overlay ----
    half8 ya0 = *(const half8*)&QKV[r*72 + q*8];
    half8 ya1 = *(const half8*)&QKV[r*72 + 32 + q*8];
    #pragma unroll
    for(int nt=0;nt<8;nt++){
      f32x4 acc={0.f,0.f,0.f,0.f};
      acc = __builtin_amdgcn_mfma_f32_16x16x32_f16(ya0, w1v[(nt*2+0)*64+lane], acc,0,0,0);
      acc = __builtin_amdgcn_mfma_f32_16x16x32_f16(ya1, w1v[(nt*2+1)*64+lane], acc,0,0,0);
      float bias=b1L[nt*16+m];
      #pragma unroll
      for(int rg=0;rg<4;rg++)
        Hd[(w*16+q*4+rg)*136 + nt*16+m] = f2h(fmaxf(acc[rg]+bias, 0.f));
    }

    // ---- FF2 + residual y + LN2 ----
    half8 ha[4];
    #pragma unroll
    for(int c=0;c<4;c++)
      ha[c] = *(const half8*)&Hd[r*136 + c*32 + q*8];
    #pragma unroll
    for(int nt=0;nt<4;nt++){
      f32x4 acc={0.f,0.f,0.f,0.f};
      #pragma unroll
      for(int c=0;c<4;c++)
        acc = __builtin_amdgcn_mfma_f32_16x16x32_f16(ha[c], w2v[(nt*4+c)*64+lane], acc,0,0,0);
      int col=nt*16+m; float bias=b2L[col];
      #pragma unroll
      for(int rg=0;rg<4;rg++)
        y[nt][rg] = acc[rg] + bias + y[nt][rg];
    }
    #pragma unroll
    for(int rg=0;rg<4;rg++){
      float sm=(y[0][rg]+y[1][rg])+(y[2][rg]+y[3][rg]);
      sm+=__shfl_xor(sm,1); sm+=__shfl_xor(sm,2); sm+=__shfl_xor(sm,4); sm+=__shfl_xor(sm,8);
      mu[rg]=sm*(1.f/64.f);
      float d0=y[0][rg]-mu[rg],d1=y[1][rg]-mu[rg],d2=y[2][rg]-mu[rg],d3=y[3][rg]-mu[rg];
      float vv=(d0*d0+d1*d1)+(d2*d2+d3*d3);
      vv+=__shfl_xor(vv,1); vv+=__shfl_xor(vv,2); vv+=__shfl_xor(vv,4); vv+=__shfl_xor(vv,8);
      rs[rg]=rsqrtf(vv*(1.f/64.f)+1e-5f);
    }
    if(l==0){
      #pragma unroll
      for(int nt=0;nt<4;nt++){
        int col=nt*16+m; float g=g2L[col], be=be2L[col];
        #pragma unroll
        for(int rg=0;rg<4;rg++)
          X[(w*16+q*4+rg)*72 + col] = f2h((y[nt][rg]-mu[rg])*rs[rg]*g + be);
      }
      __syncthreads();   // before next layer's QKV scatter overwrites QKV regions
    } else {
      // fused prediction head: rows with t==11 are rg==3 of exactly one
      // q-group per node; condition uniform over the 16-lane m-group.
      int rc = w*16 + q*4 + 3;
      int nn = rc/12;
      if(rc - nn*12 == 11){
        float vfin[4];
        #pragma unroll
        for(int nt=0;nt<4;nt++){
          int col=nt*16+m;
          vfin[nt] = (y[nt][3]-mu[3])*rs[3]*g2L[col] + be2L[col];
        }
        int gm = blockIdx.x*4 + nn;
        unsigned bb=(unsigned)gm/N_, n2=(unsigned)gm-bb*N_;
        #pragma unroll
        for(int h3=0;h3<3;h3++){
          float p = vfin[0]*Wh[h3*64+m]    + vfin[1]*Wh[h3*64+16+m]
                  + vfin[2]*Wh[h3*64+32+m] + vfin[3]*Wh[h3*64+48+m];
          p += __shfl_xor(p,1); p += __shfl_xor(p,2);
          p += __shfl_xor(p,4); p += __shfl_xor(p,8);
          if(m==0) out[(bb*3+h3)*N_+n2] = p + bh[h3];
        }
      }
    }
  }
}

extern "C" void kernel_launch(void* const* d_in, const int* in_sizes, int n_in,
                              void* d_out, int out_size, void* d_ws, size_t ws_size,
                              hipStream_t stream)
{
  const float* x_seq=(const float*)d_in[0];
  const int*   ei   =(const int*)d_in[1];
  const float* W1   =(const float*)d_in[2];
  const float* as1  =(const float*)d_in[3];
  const float* ad1  =(const float*)d_in[4];
  const float* b1   =(const float*)d_in[5];
  const float* W2   =(const float*)d_in[6];
  const float* as2  =(const float*)d_in[7];
  const float* ad2  =(const float*)d_in[8];
  const float* b2   =(const float*)d_in[9];
  const float* Wqkv =(const float*)d_in[10];
  const float* bqkv =(const float*)d_in[11];
  const float* Wo   =(const float*)d_in[12];
  const float* bo   =(const float*)d_in[13];
  const float* Wf1  =(const float*)d_in[14];
  const float* bf1p =(const float*)d_in[15];
  const float* Wf2  =(const float*)d_in[16];
  const float* bf2p =(const float*)d_in[17];
  const float* g1   =(const float*)d_in[18];
  const float* be1  =(const float*)d_in[19];
  const float* g2   =(const float*)d_in[20];
  const float* be2  =(const float*)d_in[21];
  const float* Wh   =(const float*)d_in[22];
  const float* bh   =(const float*)d_in[23];

  // workspace layout (~112 MB)
  u16* seqh   = (u16*)d_ws;                     // [T][M][64] f16  24,576,000 u16
  float* asc  = (float*)(seqh + 24576000);      // [T][M][4]        1,536,000 f
  float* adc  = asc + 1536000;                  //                  1,536,000 f
  int* deg    = (int*)(adc + 1536000);
  int* cursor = deg + M_;
  int* offs   = cursor + M_;                    // M_+1 used
  int* bsums  = offs + (M_ + 2);
  int* boffs  = bsums + 128;
  int* csr    = boffs + 128;                    // ETOT
  u16* h2u    = (u16*)(csr + ETOT);             // [T][M][64]   24,576,000 u16
  u16* wqB    = h2u + (size_t)T_*M_*64;         // 24576
  u16* woB    = wqB + 24576;                    // 8192
  u16* w1B    = woB + 8192;                     // 16384
  u16* w2B    = w1B + 16384;                    // 16384
  float* peT  = (float*)(w2B + 16384);          // 768

  k_prep   <<<dim3(260), dim3(256), 0, stream>>>(Wqkv, Wo, Wf1, Wf2, wqB, woB, w1B, w2B, peT);

  // CSR build (edge list identical for all t)
  hipMemsetAsync(deg, 0, (size_t)2*M_*sizeof(int), stream);   // deg + cursor
  k_hist   <<<dim3((ETOT+255)/256), dim3(256), 0, stream>>>(ei, deg);
  k_scan1  <<<dim3(125), dim3(256), 0, stream>>>(deg, offs, bsums);
  k_scan2  <<<dim3(1),   dim3(128), 0, stream>>>(bsums, boffs);
  k_scan3  <<<dim3(125), dim3(256), 0, stream>>>(offs, boffs);
  k_scatter<<<dim3((ETOT+255)/256), dim3(256), 0, stream>>>(ei, offs, cursor, csr);

  k_gat12<<<dim3(500,T_), dim3(256), 0, stream>>>(x_seq, W1, as1, ad1, b1,
                                                  W2, as2, ad2, offs, csr, h2u, asc, adc);
  k_gat2b<<<dim3(500,T_), dim3(256), 0, stream>>>(h2u, asc, adc, b2, offs, csr, peT, seqh);

  k_layer2<<<dim3(8000), dim3(192), 0, stream>>>(seqh,
      wqB, woB, w1B, w2B,
      bqkv, bo, bf1p, bf2p,
      g1, be1, g2, be2,
      Wh, bh, (float*)d_out);
}

// Round 5
// 385.835 us; speedup vs baseline: 1.1821x; 1.0387x over previous
//
#include <hip/hip_runtime.h>
#include <hip/hip_bf16.h>

#define B_ 16
#define T_ 12
#define N_ 2000
#define E_ 8000
#define M_ 32000                 // B_*N_
#define ETOT (B_*E_ + M_)        // 160000 edges incl. self loops
#define D_ 64

typedef __hip_bfloat16 bf16;
typedef unsigned short u16;
typedef __attribute__((ext_vector_type(8))) _Float16 half8;
typedef __attribute__((ext_vector_type(2))) _Float16 h2v;
typedef __attribute__((ext_vector_type(4))) float f32x4;

__device__ __forceinline__ float bfu(u16 u){ return __uint_as_float(((unsigned int)u)<<16); }
__device__ __forceinline__ u16 f2bu(float f){
  unsigned int x = __float_as_uint(f);
  x += 0x7FFFu + ((x >> 16) & 1u);
  return (u16)(x >> 16);
}
__device__ __forceinline__ u16 f2h(float f){
  _Float16 h = (_Float16)f; u16 r; __builtin_memcpy(&r, &h, 2); return r;
}
__device__ __forceinline__ float h2f(u16 u){
  _Float16 h; __builtin_memcpy(&h, &u, 2); return (float)h;
}
__device__ __forceinline__ h2v u2h(unsigned u){ h2v r; __builtin_memcpy(&r,&u,4); return r; }

// multi-value butterfly reduce over a 16-lane group: lane m returns
// sum over the 16 lanes of value index m. 15 shfl, no runtime indexing.
__device__ __forceinline__ float redsel16(const float v[16], int m){
  float c8[8];
  #pragma unroll
  for(int i=0;i<8;i++){
    float send = (m&8)? v[i]   : v[i+8];
    float keep = (m&8)? v[i+8] : v[i];
    c8[i] = keep + __shfl_xor(send, 8);
  }
  float c4[4];
  #pragma unroll
  for(int i=0;i<4;i++){
    float send = (m&4)? c8[i]   : c8[i+4];
    float keep = (m&4)? c8[i+4] : c8[i];
    c4[i] = keep + __shfl_xor(send, 4);
  }
  float c2[2];
  #pragma unroll
  for(int i=0;i<2;i++){
    float send = (m&2)? c2[0]*0.f + c4[i] : c4[i+2];   // avoid self-ref typo
    float keep = (m&2)? c4[i+2] : c4[i];
    c2[i] = keep + __shfl_xor(((m&2)? c4[i] : c4[i+2]), 2);
    c2[i] = keep + __shfl_xor(send, 2);
  }
  float send = (m&1)? c2[0] : c2[1];
  float keep = (m&1)? c2[1] : c2[0];
  return keep + __shfl_xor(send, 1);
}

// ---------------- weight prep: f16 MFMA B-fragments + PE table ----------------
__global__ void k_prep(const float* __restrict__ Wqkv, const float* __restrict__ Wo,
                       const float* __restrict__ Wf1, const float* __restrict__ Wf2,
                       const float* __restrict__ W2g,
                       u16* __restrict__ wqB, u16* __restrict__ woB,
                       u16* __restrict__ w1B, u16* __restrict__ w2B,
                       float* __restrict__ peT, u16* __restrict__ w2gB){
  int i = blockIdx.x*256 + threadIdx.x;    // 268 blocks
  if(i < 24576){
    int l=i/12288, r=i-l*12288;
    int nt=r>>10, r2=r&1023, c=r2>>9, r3=r2&511, lane=r3>>3, jj=r3&7;
    int m=lane&15, q=lane>>4;
    wqB[i] = f2h(Wqkv[l*12288 + (nt*16+m)*64 + c*32 + q*8 + jj]);
  } else if(i < 32768){
    int k2=i-24576;
    int l=k2>>12, r=k2&4095;
    int nt=r>>10, r2=r&1023, c=r2>>9, r3=r2&511, lane=r3>>3, jj=r3&7;
    int m=lane&15, q=lane>>4;
    woB[k2] = f2h(Wo[l*4096 + (nt*16+m)*64 + c*32 + q*8 + jj]);
  } else if(i < 49152){
    int k2=i-32768;
    int l=k2>>13, r=k2&8191;
    int nt=r>>10, r2=r&1023, c=r2>>9, r3=r2&511, lane=r3>>3, jj=r3&7;
    int m=lane&15, q=lane>>4;
    w1B[k2] = f2h(Wf1[l*8192 + (nt*16+m)*64 + c*32 + q*8 + jj]);
  } else if(i < 65536){
    int k2=i-49152;
    int l=k2>>13, r=k2&8191;
    int nt=r>>11, r2=r&2047, c=r2>>9, r3=r2&511, lane=r3>>3, jj=r3&7;
    int m=lane&15, q=lane>>4;
    w2B[k2] = f2h(Wf2[l*8192 + (nt*16+m)*128 + c*32 + q*8 + jj]);
  } else {
    int i2 = i - 65536;
    if(i2 < 768){
      int t=i2>>6, ch=i2&63;
      float ang = (float)t * __expf(-0.14391156463f * (float)(ch & ~1));
      peT[i2] = (ch&1) ? __cosf(ang) : __sinf(ang);
    } else if(i2 < 768+2048){
      // GAT2 W2 [32][64] as B-frags: elem j = W2[q*8+j][nt*16+m]
      int i3 = i2-768;
      int nt=i3>>9, r=i3&511, lane=r>>3, j=r&7;
      int m=lane&15, q=lane>>4;
      w2gB[i3] = f2h(W2g[(q*8+j)*64 + nt*16 + m]);
    }
  }
}

// ---------------- CSR build ----------------
__global__ void k_hist(const int* __restrict__ ei, int* __restrict__ deg){
  int e = blockIdx.x*256 + threadIdx.x; if(e>=ETOT) return;
  int dst;
  if (e < B_*E_){ int b = e / E_; int k = e - b*E_; dst = ei[E_ + k] + b*N_; }
  else dst = e - B_*E_;
  atomicAdd(&deg[dst], 1);
}

__global__ void k_scan1(const int* __restrict__ deg, int* __restrict__ offs, int* __restrict__ bsums){
  __shared__ int s[256];
  int tid = threadIdx.x; int g = blockIdx.x*256 + tid;
  s[tid] = deg[g]; __syncthreads();
  for(int off=1; off<256; off<<=1){
    int a = (tid>=off) ? s[tid-off] : 0; __syncthreads();
    s[tid] += a; __syncthreads();
  }
  offs[g+1] = s[tid];
  if(tid==255) bsums[blockIdx.x] = s[255];
}

__global__ void k_scan2(const int* __restrict__ bsums, int* __restrict__ boffs){
  __shared__ int s[128];
  int tid = threadIdx.x;
  int v = (tid<125) ? bsums[tid] : 0;
  s[tid] = v; __syncthreads();
  for(int off=1; off<128; off<<=1){
    int a = (tid>=off) ? s[tid-off] : 0; __syncthreads();
    s[tid] += a; __syncthreads();
  }
  if(tid<125) boffs[tid] = s[tid] - v;
}

__global__ void k_scan3(int* __restrict__ offs, const int* __restrict__ boffs){
  int tid = threadIdx.x; int g = blockIdx.x*256 + tid;
  offs[g+1] += boffs[blockIdx.x];
  if(g==0) offs[0]=0;
}

// csr stores LOCAL src index (all edges intra-graph) -> gat kernels skip /N_
__global__ void k_scatter(const int* __restrict__ ei, const int* __restrict__ offs,
                          int* __restrict__ cursor, int* __restrict__ csr){
  int e = blockIdx.x*256 + threadIdx.x; if(e>=ETOT) return;
  int srcl, dst;
  if (e < B_*E_){ int b=e/E_; int k=e-b*E_; srcl=ei[k]; dst=ei[E_+k]+b*N_; }
  else { dst = e - B_*E_; int b=dst/N_; srcl = dst - b*N_; }
  int pos = atomicAdd(&cursor[dst], 1);
  csr[offs[dst]+pos] = srcl;
}

// ---------------- fused GAT1 + GAT2 feature/score (MFMA) ----------------
// One lane per (node,head): lane = q*16+m handles node m (of wave's 16) head q.
// GAT1 aggregate A[m,q] is lane-private (no shuffles); out1 row chunk
// relu(A*W1[q*8+j]+b1) IS the 16x16x32 A-fragment; W2 applied with 4 MFMAs
// (replaces 512 ds_read + 512 v_fma per thread of the old LDS matvec; kernel
// now uses no LDS and no barrier). D: lane holds rows q*4+rg, col nt*16+m.
// asc/adc recovered by multi-value butterfly (redsel16).
__global__ __launch_bounds__(256) void k_gat12(
  const float* __restrict__ x_seq, const float* __restrict__ W1,
  const float* __restrict__ as1, const float* __restrict__ ad1, const float* __restrict__ b1,
  const float* __restrict__ as2, const float* __restrict__ ad2,
  const int* __restrict__ offs, const int* __restrict__ csr,
  const u16* __restrict__ w2gB,
  u16* __restrict__ h2u, float* __restrict__ asc, float* __restrict__ adc)
{
  int tid = threadIdx.x, w = tid>>6, lane = tid&63;
  int m = lane&15, q = lane>>4;
  int t = blockIdx.y;
  int node = blockIdx.x*64 + w*16 + m;
  unsigned un=(unsigned)node, b=un/N_, n=un-b*N_;

  // W2 B-fragments (16 VGPR, loaded once; L2-hot)
  const half8* wb = (const half8*)w2gB;
  half8 w2f0 = wb[0*64+lane], w2f1 = wb[1*64+lane],
        w2f2 = wb[2*64+lane], w2f3 = wb[3*64+lane];

  // head-q GAT1 score weights
  float sS=0.f, sD=0.f;
  #pragma unroll
  for(int c=0;c<8;c++){ float wv=W1[q*8+c]; sS+=wv*as1[q*8+c]; sD+=wv*ad1[q*8+c]; }

  const float* xsl = x_seq + (size_t)(b*T_+t)*N_;
  float xm = xsl[n];
  int e0=offs[node], e1=offs[node+1];
  float sum=0.f, ax=0.f;
  for(int e=e0;e<e1;e++){
    float xv = xsl[csr[e]];
    float ee = xv*sS + xm*sD; ee = ee>0.f ? ee : 0.2f*ee;
    float wv = __expf(ee); sum += wv; ax += wv*xv;
  }
  float A = ax/(sum+1e-16f);

  // A-fragment: out1[m][q*8+j]
  half8 af;
  #pragma unroll
  for(int j=0;j<8;j++){
    float v = A*W1[q*8+j] + b1[q*8+j]; v = v>0.f?v:0.f;
    af[j] = (_Float16)v;
  }
  f32x4 ac0={0.f,0.f,0.f,0.f}, ac1=ac0, ac2=ac0, ac3=ac0;
  ac0 = __builtin_amdgcn_mfma_f32_16x16x32_f16(af, w2f0, ac0,0,0,0);
  ac1 = __builtin_amdgcn_mfma_f32_16x16x32_f16(af, w2f1, ac1,0,0,0);
  ac2 = __builtin_amdgcn_mfma_f32_16x16x32_f16(af, w2f2, ac2,0,0,0);
  ac3 = __builtin_amdgcn_mfma_f32_16x16x32_f16(af, w2f3, ac3,0,0,0);

  // h2u stores: D row q*4+rg -> node base+q*4+rg, col nt*16+m (bf16)
  size_t hbase = (size_t)t*M_;
  int ndbase = blockIdx.x*64 + w*16 + q*4;
  #pragma unroll
  for(int rg=0;rg<4;rg++){
    u16* row = h2u + (hbase + ndbase + rg)*64;
    row[ 0+m] = f2bu(ac0[rg]);
    row[16+m] = f2bu(ac1[rg]);
    row[32+m] = f2bu(ac2[rg]);
    row[48+m] = f2bu(ac3[rg]);
  }

  // asc/adc: score[h][rg] = sum_m acc[h][rg]*a2s[h*16+m]
  float a2sv[4], a2dv[4];
  #pragma unroll
  for(int h=0;h<4;h++){ a2sv[h]=as2[h*16+m]; a2dv[h]=ad2[h*16+m]; }
  float pa[16], pd[16];
  #pragma unroll
  for(int rg=0;rg<4;rg++){
    pa[0*4+rg]=ac0[rg]*a2sv[0]; pd[0*4+rg]=ac0[rg]*a2dv[0];
    pa[1*4+rg]=ac1[rg]*a2sv[1]; pd[1*4+rg]=ac1[rg]*a2dv[1];
    pa[2*4+rg]=ac2[rg]*a2sv[2]; pd[2*4+rg]=ac2[rg]*a2dv[2];
    pa[3*4+rg]=ac3[rg]*a2sv[3]; pd[3*4+rg]=ac3[rg]*a2dv[3];
  }
  float ra = redsel16(pa, m);   // lane m -> value h*4+rg with h=m>>2, rg=m&3
  float rd = redsel16(pd, m);
  {
    int h=m>>2, rg=m&3;
    size_t nd = hbase + ndbase + rg;
    asc[nd*4+h] = ra;
    adc[nd*4+h] = rd;
  }
}

// ---------------- GAT2 softmax-aggregate + bias + relu + PE(table); f16 out ------
__global__ __launch_bounds__(256) void k_gat2b(
  const u16* __restrict__ h2u, const float* __restrict__ asc, const float* __restrict__ adc,
  const float* __restrict__ b2, const int* __restrict__ offs, const int* __restrict__ csr,
  const float* __restrict__ peT, u16* __restrict__ seq)
{
  int t = blockIdx.y;
  int id = blockIdx.x*256 + threadIdx.x;
  int m = id>>2, h = id&3;
  unsigned um=(unsigned)m, b=um/N_;
  size_t base_s = (size_t)t*M_ + (size_t)b*N_;   // csr holds local indices
  float am = adc[((size_t)t*M_+m)*4+h];
  int e0=offs[m], e1=offs[m+1];
  float sum=0.f;
  float A[16];
  #pragma unroll
  for(int c=0;c<16;c++) A[c]=0.f;
  for(int e=e0;e<e1;e++){
    size_t s = base_s + (unsigned)csr[e];
    float ee = asc[s*4+h] + am; ee = ee>0.f ? ee : 0.2f*ee;
    float w = __expf(ee); sum += w;
    const uint2* hp = (const uint2*)(h2u + s*64 + h*16);
    #pragma unroll
    for(int c2=0;c2<4;c2++){
      uint2 p = hp[c2];
      A[4*c2+0] += w*bfu((u16)(p.x));
      A[4*c2+1] += w*bfu((u16)(p.x>>16));
      A[4*c2+2] += w*bfu((u16)(p.y));
      A[4*c2+3] += w*bfu((u16)(p.y>>16));
    }
  }
  float inv = 1.f/(sum + 1e-16f);
  #pragma unroll
  for(int c=0;c<16;c++){
    int ch = h*16 + c;
    float v = A[c]*inv + b2[ch]; v = v>0.f ? v : 0.f;
    seq[((size_t)t*M_ + m)*64 + ch] = f2h(v + peT[t*64+ch]);
  }
}

// ---------------- BOTH transformer layers + fused head (R16-measured form) -------
// X u16 [48][72]: layer input (wave-private rows). QKV u16 [3][48][72]; K,V
// overlaid by H[48][136]. A = activations (standard orientation; the operand
// swap was tried TWICE and both times tripled LDS bank conflicts -- do not
// retry). Register-carried residual (xres) was tried once: VGPR 68->84,
// VALUBusy -15pts, +48us -- do not retry.
__global__ __launch_bounds__(192) void k_layer2(
  const u16* __restrict__ seq,
  const u16* __restrict__ wqB, const u16* __restrict__ woB,
  const u16* __restrict__ w1B, const u16* __restrict__ w2B,
  const float* __restrict__ bqkv, const float* __restrict__ bo,
  const float* __restrict__ bf1,  const float* __restrict__ bf2,
  const float* __restrict__ g1,   const float* __restrict__ be1,
  const float* __restrict__ g2,   const float* __restrict__ be2,
  const float* __restrict__ Wh,   const float* __restrict__ bh,
  float* __restrict__ out)
{
  __shared__ __align__(16) u16 X[3456];      // [48][72] f16
  __shared__ __align__(16) u16 QKV[10368];   // [3][48][72]
  u16* Hd = QKV + 3456;                      // H[48][136] overlays K,V
  int tid=threadIdx.x, w=tid>>6, lane=tid&63;
  int m=lane&15, q=lane>>4;
  int r = w*16 + m;

  // stage X: wave w loads its own 16 rows (wave-private, no barrier needed).
  // Each row = 128B = 8 lanes x 16B; 2 dwordx4 loads/lane replace 16 scalar.
  #pragma unroll
  for(int half=0; half<2; half++){
    int rr = half*8 + (lane>>3);
    int row = w*16 + rr;
    int nn = row/12, tt = row-nn*12;
    const uint4* src = (const uint4*)(seq + ((size_t)tt*M_ + (size_t)blockIdx.x*4+nn)*64) + (lane&7);
    *((uint4*)&X[row*72] + (lane&7)) = *src;
  }

  #pragma unroll 1
  for(int l=0; l<2; l++){
    const half8* wqv = (const half8*)(wqB + (size_t)l*12288);
    const half8* wov = (const half8*)(woB + (size_t)l*4096);
    const half8* w1v = (const half8*)(w1B + (size_t)l*8192);
    const half8* w2v = (const half8*)(w2B + (size_t)l*8192);
    const float* bq = bqkv + l*192;
    const float* boL = bo + l*64;
    const float* b1L = bf1 + l*128;
    const float* b2L = bf2 + l*64;
    const float* g1L = g1 + l*64, *be1L = be1 + l*64;
    const float* g2L = g2 + l*64, *be2L = be2 + l*64;

    // ---- QKV projection: A-frags from X (wave-own rows) ----
    half8 xa0 = *(const half8*)&X[r*72 + q*8];
    half8 xa1 = *(const half8*)&X[r*72 + 32 + q*8];
    #pragma unroll
    for(int nt=0; nt<12; nt++){
      f32x4 acc={0.f,0.f,0.f,0.f};
      acc = __builtin_amdgcn_mfma_f32_16x16x32_f16(xa0, wqv[(nt*2+0)*64+lane], acc,0,0,0);
      acc = __builtin_amdgcn_mfma_f32_16x16x32_f16(xa1, wqv[(nt*2+1)*64+lane], acc,0,0,0);
      int cg = nt*16+m; float bias = bq[cg];
      int s = nt>>2, lc = cg&63;
      #pragma unroll
      for(int rg=0;rg<4;rg++){
        int row = w*16 + q*4 + rg;
        QKV[s*3456 + row*72 + lc] = f2h(acc[rg]+bias);
      }
    }
    __syncthreads();

    // ---- attention: 192 lanes = (node an, head ah, time at); fdot2 + pk_fma ----
    {
      int an = tid/48, rem = tid - an*48;
      int ah = rem/12, at = rem - ah*12;
      u16* qrow = &QKV[(an*12+at)*72 + ah*16];
      uint4 qa = ((const uint4*)qrow)[0], qb = ((const uint4*)qrow)[1];
      float s[12];
      #pragma unroll
      for(int t2=0;t2<12;t2++){
        const uint4* kp = (const uint4*)&QKV[3456 + (an*12+t2)*72 + ah*16];
        uint4 ka=kp[0], kb=kp[1];
        float d=0.f;
        d=__builtin_amdgcn_fdot2(u2h(qa.x),u2h(ka.x),d,false);
        d=__builtin_amdgcn_fdot2(u2h(qa.y),u2h(ka.y),d,false);
        d=__builtin_amdgcn_fdot2(u2h(qa.z),u2h(ka.z),d,false);
        d=__builtin_amdgcn_fdot2(u2h(qa.w),u2h(ka.w),d,false);
        d=__builtin_amdgcn_fdot2(u2h(qb.x),u2h(kb.x),d,false);
        d=__builtin_amdgcn_fdot2(u2h(qb.y),u2h(kb.y),d,false);
        d=__builtin_amdgcn_fdot2(u2h(qb.z),u2h(kb.z),d,false);
        d=__builtin_amdgcn_fdot2(u2h(qb.w),u2h(kb.w),d,false);
        s[t2] = d*0.25f;
      }
      float mx=s[0];
      #pragma unroll
      for(int t2=1;t2<12;t2++) mx=fmaxf(mx,s[t2]);
      float sum=0.f;
      #pragma unroll
      for(int t2=0;t2<12;t2++){ s[t2]=__expf(s[t2]-mx); sum+=s[t2]; }
      float inv=1.f/sum;
      half8 o0, o1;
      #pragma unroll
      for(int i=0;i<8;i++){ o0[i]=(_Float16)0.f; o1[i]=(_Float16)0.f; }
      #pragma unroll
      for(int t2=0;t2<12;t2++){
        const half8* vr = (const half8*)&QKV[6912 + (an*12+t2)*72 + ah*16];
        _Float16 wh = (_Float16)s[t2];
        o0 += vr[0]*wh; o1 += vr[1]*wh;
      }
      _Float16 ih = (_Float16)inv;
      ((half8*)qrow)[0]=o0*ih; ((half8*)qrow)[1]=o1*ih;
    }
    __syncthreads();

    // ---- Wo + residual(X) + LN1 ----
    half8 oa0 = *(const half8*)&QKV[r*72 + q*8];
    half8 oa1 = *(const half8*)&QKV[r*72 + 32 + q*8];
    float y[4][4];
    #pragma unroll
    for(int nt=0;nt<4;nt++){
      f32x4 acc={0.f,0.f,0.f,0.f};
      acc = __builtin_amdgcn_mfma_f32_16x16x32_f16(oa0, wov[(nt*2+0)*64+lane], acc,0,0,0);
      acc = __builtin_amdgcn_mfma_f32_16x16x32_f16(oa1, wov[(nt*2+1)*64+lane], acc,0,0,0);
      int col=nt*16+m; float bias=boL[col];
      #pragma unroll
      for(int rg=0;rg<4;rg++)
        y[nt][rg] = acc[rg] + bias + h2f(X[(w*16+q*4+rg)*72 + col]);
    }
    float mu[4], rs[4];
    #pragma unroll
    for(int rg=0;rg<4;rg++){
      float sm=(y[0][rg]+y[1][rg])+(y[2][rg]+y[3][rg]);
      sm+=__shfl_xor(sm,1); sm+=__shfl_xor(sm,2); sm+=__shfl_xor(sm,4); sm+=__shfl_xor(sm,8);
      mu[rg]=sm*(1.f/64.f);
      float d0=y[0][rg]-mu[rg],d1=y[1][rg]-mu[rg],d2=y[2][rg]-mu[rg],d3=y[3][rg]-mu[rg];
      float vv=(d0*d0+d1*d1)+(d2*d2+d3*d3);
      vv+=__shfl_xor(vv,1); vv+=__shfl_xor(vv,2); vv+=__shfl_xor(vv,4); vv+=__shfl_xor(vv,8);
      rs[rg]=rsqrtf(vv*(1.f/64.f)+1e-5f);
    }
    #pragma unroll
    for(int nt=0;nt<4;nt++){
      int col=nt*16+m; float g=g1L[col], be=be1L[col];
      #pragma unroll
      for(int rg=0;rg<4;rg++){
        float v=(y[nt][rg]-mu[rg])*rs[rg]*g+be;
        y[nt][rg]=v;                                  // FF residual (f32)
        QKV[(w*16+q*4+rg)*72 + col]=f2h(v);           // y -> wave-own rows
      }
    }

    // ---- FF1: y A-frags; H -> pitch-136 overlay ----
    half8 ya0 = *(const half8*)&QKV[r*72 + q*8];
    half8 ya1 = *(const half8*)&QKV[r*72 + 32 + q*8];
    #pragma unroll
    for(int nt=0;nt<8;nt++){
      f32x4 acc={0.f,0.f,0.f,0.f};
      acc = __builtin_amdgcn_mfma_f32_16x16x32_f16(ya0, w1v[(nt*2+0)*64+lane], acc,0,0,0);
      acc = __builtin_amdgcn_mfma_f32_16x16x32_f16(ya1, w1v[(nt*2+1)*64+lane], acc,0,0,0);
      float bias=b1L[nt*16+m];
      #pragma unroll
      for(int rg=0;rg<4;rg++)
        Hd[(w*16+q*4+rg)*136 + nt*16+m] = f2h(fmaxf(acc[rg]+bias, 0.f));
    }

    // ---- FF2 + residual y + LN2 ----
    half8 ha[4];
    #pragma unroll
    for(int c=0;c<4;c++)
      ha[c] = *(const half8*)&Hd[r*136 + c*32 + q*8];
    #pragma unroll
    for(int nt=0;nt<4;nt++){
      f32x4 acc={0.f,0.f,0.f,0.f};
      #pragma unroll
      for(int c=0;c<4;c++)
        acc = __builtin_amdgcn_mfma_f32_16x16x32_f16(ha[c], w2v[(nt*4+c)*64+lane], acc,0,0,0);
      int col=nt*16+m; float bias=b2L[col];
      #pragma unroll
      for(int rg=0;rg<4;rg++)
        y[nt][rg] = acc[rg] + bias + y[nt][rg];
    }
    #pragma unroll
    for(int rg=0;rg<4;rg++){
      float sm=(y[0][rg]+y[1][rg])+(y[2][rg]+y[3][rg]);
      sm+=__shfl_xor(sm,1); sm+=__shfl_xor(sm,2); sm+=__shfl_xor(sm,4); sm+=__shfl_xor(sm,8);
      mu[rg]=sm*(1.f/64.f);
      float d0=y[0][rg]-mu[rg],d1=y[1][rg]-mu[rg],d2=y[2][rg]-mu[rg],d3=y[3][rg]-mu[rg];
      float vv=(d0*d0+d1*d1)+(d2*d2+d3*d3);
      vv+=__shfl_xor(vv,1); vv+=__shfl_xor(vv,2); vv+=__shfl_xor(vv,4); vv+=__shfl_xor(vv,8);
      rs[rg]=rsqrtf(vv*(1.f/64.f)+1e-5f);
    }
    if(l==0){
      #pragma unroll
      for(int nt=0;nt<4;nt++){
        int col=nt*16+m; float g=g2L[col], be=be2L[col];
        #pragma unroll
        for(int rg=0;rg<4;rg++)
          X[(w*16+q*4+rg)*72 + col] = f2h((y[nt][rg]-mu[rg])*rs[rg]*g + be);
      }
      __syncthreads();   // before next layer's QKV scatter overwrites QKV regions
    } else {
      // fused prediction head: rows with t==11 are rg==3 of exactly one
      // q-group per node; condition uniform over the 16-lane m-group.
      int rc = w*16 + q*4 + 3;
      int nn = rc/12;
      if(rc - nn*12 == 11){
        float vfin[4];
        #pragma unroll
        for(int nt=0;nt<4;nt++){
          int col=nt*16+m;
          vfin[nt] = (y[nt][3]-mu[3])*rs[3]*g2L[col] + be2L[col];
        }
        int gm = blockIdx.x*4 + nn;
        unsigned bb=(unsigned)gm/N_, n2=(unsigned)gm-bb*N_;
        #pragma unroll
        for(int h3=0;h3<3;h3++){
          float p = vfin[0]*Wh[h3*64+m]    + vfin[1]*Wh[h3*64+16+m]
                  + vfin[2]*Wh[h3*64+32+m] + vfin[3]*Wh[h3*64+48+m];
          p += __shfl_xor(p,1); p += __shfl_xor(p,2);
          p += __shfl_xor(p,4); p += __shfl_xor(p,8);
          if(m==0) out[(bb*3+h3)*N_+n2] = p + bh[h3];
        }
      }
    }
  }
}

extern "C" void kernel_launch(void* const* d_in, const int* in_sizes, int n_in,
                              void* d_out, int out_size, void* d_ws, size_t ws_size,
                              hipStream_t stream)
{
  const float* x_seq=(const float*)d_in[0];
  const int*   ei   =(const int*)d_in[1];
  const float* W1   =(const float*)d_in[2];
  const float* as1  =(const float*)d_in[3];
  const float* ad1  =(const float*)d_in[4];
  const float* b1   =(const float*)d_in[5];
  const float* W2   =(const float*)d_in[6];
  const float* as2  =(const float*)d_in[7];
  const float* ad2  =(const float*)d_in[8];
  const float* b2   =(const float*)d_in[9];
  const float* Wqkv =(const float*)d_in[10];
  const float* bqkv =(const float*)d_in[11];
  const float* Wo   =(const float*)d_in[12];
  const float* bo   =(const float*)d_in[13];
  const float* Wf1  =(const float*)d_in[14];
  const float* bf1p =(const float*)d_in[15];
  const float* Wf2  =(const float*)d_in[16];
  const float* bf2p =(const float*)d_in[17];
  const float* g1   =(const float*)d_in[18];
  const float* be1  =(const float*)d_in[19];
  const float* g2   =(const float*)d_in[20];
  const float* be2  =(const float*)d_in[21];
  const float* Wh   =(const float*)d_in[22];
  const float* bh   =(const float*)d_in[23];

  // workspace layout (~112 MB)
  u16* seqh   = (u16*)d_ws;                     // [T][M][64] f16  24,576,000 u16
  float* asc  = (float*)(seqh + 24576000);      // [T][M][4]        1,536,000 f
  float* adc  = asc + 1536000;                  //                  1,536,000 f
  int* deg    = (int*)(adc + 1536000);
  int* cursor = deg + M_;
  int* offs   = cursor + M_;                    // M_+1 used
  int* bsums  = offs + (M_ + 2);
  int* boffs  = bsums + 128;
  int* csr    = boffs + 128;                    // ETOT
  u16* h2u    = (u16*)(csr + ETOT);             // [T][M][64]   24,576,000 u16
  u16* wqB    = h2u + (size_t)T_*M_*64;         // 24576
  u16* woB    = wqB + 24576;                    // 8192
  u16* w1B    = woB + 8192;                     // 16384
  u16* w2B    = w1B + 16384;                    // 16384
  float* peT  = (float*)(w2B + 16384);          // 768
  u16* w2gB   = (u16*)(peT + 768);              // 2048

  k_prep   <<<dim3(268), dim3(256), 0, stream>>>(Wqkv, Wo, Wf1, Wf2, W2,
                                                 wqB, woB, w1B, w2B, peT, w2gB);

  // CSR build (edge list identical for all t)
  hipMemsetAsync(deg, 0, (size_t)2*M_*sizeof(int), stream);   // deg + cursor
  k_hist   <<<dim3((ETOT+255)/256), dim3(256), 0, stream>>>(ei, deg);
  k_scan1  <<<dim3(125), dim3(256), 0, stream>>>(deg, offs, bsums);
  k_scan2  <<<dim3(1),   dim3(128), 0, stream>>>(bsums, boffs);
  k_scan3  <<<dim3(125), dim3(256), 0, stream>>>(offs, boffs);
  k_scatter<<<dim3((ETOT+255)/256), dim3(256), 0, stream>>>(ei, offs, cursor, csr);

  k_gat12<<<dim3(500,T_), dim3(256), 0, stream>>>(x_seq, W1, as1, ad1, b1,
                                                  as2, ad2, offs, csr, w2gB,
                                                  h2u, asc, adc);
  k_gat2b<<<dim3(500,T_), dim3(256), 0, stream>>>(h2u, asc, adc, b2, offs, csr, peT, seqh);

  k_layer2<<<dim3(8000), dim3(192), 0, stream>>>(seqh,
      wqB, woB, w1B, w2B,
      bqkv, bo, bf1p, bf2p,
      g1, be1, g2, be2,
      Wh, bh, (float*)d_out);
}

// Round 6
// 384.796 us; speedup vs baseline: 1.1853x; 1.0027x over previous
//
#include <hip/hip_runtime.h>
#include <hip/hip_bf16.h>

#define B_ 16
#define T_ 12
#define N_ 2000
#define E_ 8000
#define M_ 32000                 // B_*N_
#define ETOT (B_*E_ + M_)        // 160000 edges incl. self loops
#define D_ 64

typedef __hip_bfloat16 bf16;
typedef unsigned short u16;
typedef __attribute__((ext_vector_type(8))) _Float16 half8;
typedef __attribute__((ext_vector_type(2))) _Float16 h2v;
typedef __attribute__((ext_vector_type(4))) float f32x4;

__device__ __forceinline__ float bfu(u16 u){ return __uint_as_float(((unsigned int)u)<<16); }
__device__ __forceinline__ u16 f2bu(float f){
  unsigned int x = __float_as_uint(f);
  x += 0x7FFFu + ((x >> 16) & 1u);
  return (u16)(x >> 16);
}
__device__ __forceinline__ u16 f2h(float f){
  _Float16 h = (_Float16)f; u16 r; __builtin_memcpy(&r, &h, 2); return r;
}
__device__ __forceinline__ float h2f(u16 u){
  _Float16 h; __builtin_memcpy(&h, &u, 2); return (float)h;
}
__device__ __forceinline__ h2v u2h(unsigned u){ h2v r; __builtin_memcpy(&r,&u,4); return r; }

// multi-value butterfly reduce over a 16-lane group: lane m returns
// sum over the 16 lanes of value index m. (verified form -- do not edit)
__device__ __forceinline__ float redsel16(const float v[16], int m){
  float c8[8];
  #pragma unroll
  for(int i=0;i<8;i++){
    float send = (m&8)? v[i]   : v[i+8];
    float keep = (m&8)? v[i+8] : v[i];
    c8[i] = keep + __shfl_xor(send, 8);
  }
  float c4[4];
  #pragma unroll
  for(int i=0;i<4;i++){
    float send = (m&4)? c8[i]   : c8[i+4];
    float keep = (m&4)? c8[i+4] : c8[i];
    c4[i] = keep + __shfl_xor(send, 4);
  }
  float c2[2];
  #pragma unroll
  for(int i=0;i<2;i++){
    float send = (m&2)? c4[i]   : c4[i+2];
    float keep = (m&2)? c4[i+2] : c4[i];
    c2[i] = keep + __shfl_xor(send, 2);
  }
  float send = (m&1)? c2[0] : c2[1];
  float keep = (m&1)? c2[1] : c2[0];
  return keep + __shfl_xor(send, 1);
}

// ---------------- weight prep: f16 MFMA B-fragments + PE table ----------------
__global__ void k_prep(const float* __restrict__ Wqkv, const float* __restrict__ Wo,
                       const float* __restrict__ Wf1, const float* __restrict__ Wf2,
                       const float* __restrict__ W2g,
                       u16* __restrict__ wqB, u16* __restrict__ woB,
                       u16* __restrict__ w1B, u16* __restrict__ w2B,
                       float* __restrict__ peT, u16* __restrict__ w2gB){
  int i = blockIdx.x*256 + threadIdx.x;    // 268 blocks
  if(i < 24576){
    int l=i/12288, r=i-l*12288;
    int nt=r>>10, r2=r&1023, c=r2>>9, r3=r2&511, lane=r3>>3, jj=r3&7;
    int m=lane&15, q=lane>>4;
    wqB[i] = f2h(Wqkv[l*12288 + (nt*16+m)*64 + c*32 + q*8 + jj]);
  } else if(i < 32768){
    int k2=i-24576;
    int l=k2>>12, r=k2&4095;
    int nt=r>>10, r2=r&1023, c=r2>>9, r3=r2&511, lane=r3>>3, jj=r3&7;
    int m=lane&15, q=lane>>4;
    woB[k2] = f2h(Wo[l*4096 + (nt*16+m)*64 + c*32 + q*8 + jj]);
  } else if(i < 49152){
    int k2=i-32768;
    int l=k2>>13, r=k2&8191;
    int nt=r>>10, r2=r&1023, c=r2>>9, r3=r2&511, lane=r3>>3, jj=r3&7;
    int m=lane&15, q=lane>>4;
    w1B[k2] = f2h(Wf1[l*8192 + (nt*16+m)*64 + c*32 + q*8 + jj]);
  } else if(i < 65536){
    int k2=i-49152;
    int l=k2>>13, r=k2&8191;
    int nt=r>>11, r2=r&2047, c=r2>>9, r3=r2&511, lane=r3>>3, jj=r3&7;
    int m=lane&15, q=lane>>4;
    w2B[k2] = f2h(Wf2[l*8192 + (nt*16+m)*128 + c*32 + q*8 + jj]);
  } else {
    int i2 = i - 65536;
    if(i2 < 768){
      int t=i2>>6, ch=i2&63;
      float ang = (float)t * __expf(-0.14391156463f * (float)(ch & ~1));
      peT[i2] = (ch&1) ? __cosf(ang) : __sinf(ang);
    } else if(i2 < 768+2048){
      // GAT2 W2 [32][64] as B-frags: elem j = W2[q*8+j][nt*16+m]
      int i3 = i2-768;
      int nt=i3>>9, r=i3&511, lane=r>>3, j=r&7;
      int m=lane&15, q=lane>>4;
      w2gB[i3] = f2h(W2g[(q*8+j)*64 + nt*16 + m]);
    }
  }
}

// ---------------- CSR build ----------------
__global__ void k_hist(const int* __restrict__ ei, int* __restrict__ deg){
  int e = blockIdx.x*256 + threadIdx.x; if(e>=ETOT) return;
  int dst;
  if (e < B_*E_){ int b = e / E_; int k = e - b*E_; dst = ei[E_ + k] + b*N_; }
  else dst = e - B_*E_;
  atomicAdd(&deg[dst], 1);
}

__global__ void k_scan1(const int* __restrict__ deg, int* __restrict__ offs, int* __restrict__ bsums){
  __shared__ int s[256];
  int tid = threadIdx.x; int g = blockIdx.x*256 + tid;
  s[tid] = deg[g]; __syncthreads();
  for(int off=1; off<256; off<<=1){
    int a = (tid>=off) ? s[tid-off] : 0; __syncthreads();
    s[tid] += a; __syncthreads();
  }
  offs[g+1] = s[tid];
  if(tid==255) bsums[blockIdx.x] = s[255];
}

// merged scan2+scan3: every block redundantly scans the 125 block sums
// (trivial) and applies its own prefix. One launch instead of two.
__global__ void k_scan23(int* __restrict__ offs, const int* __restrict__ bsums){
  __shared__ int s[128];
  int tid = threadIdx.x; int g = blockIdx.x*256 + tid;
  if(tid<128) s[tid] = (tid<125) ? bsums[tid] : 0;
  __syncthreads();
  for(int off=1; off<128; off<<=1){
    int a = 0;
    if(tid<128 && tid>=off) a = s[tid-off];
    __syncthreads();
    if(tid<128) s[tid] += a;
    __syncthreads();
  }
  int boff = (blockIdx.x==0) ? 0 : s[blockIdx.x-1];
  offs[g+1] += boff;
  if(g==0) offs[0]=0;
}

// csr stores LOCAL src index (all edges intra-graph) -> gat kernels skip /N_
__global__ void k_scatter(const int* __restrict__ ei, const int* __restrict__ offs,
                          int* __restrict__ cursor, int* __restrict__ csr){
  int e = blockIdx.x*256 + threadIdx.x; if(e>=ETOT) return;
  int srcl, dst;
  if (e < B_*E_){ int b=e/E_; int k=e-b*E_; srcl=ei[k]; dst=ei[E_+k]+b*N_; }
  else { dst = e - B_*E_; int b=dst/N_; srcl = dst - b*N_; }
  int pos = atomicAdd(&cursor[dst], 1);
  csr[offs[dst]+pos] = srcl;
}

// ---------------- fused GAT1 + GAT2 feature/score (MFMA) ----------------
// One lane per (node,head); GAT1 aggregate lane-private; W2 via 4 MFMAs;
// no LDS, no barrier. (measured-good round-5 form)
__global__ __launch_bounds__(256) void k_gat12(
  const float* __restrict__ x_seq, const float* __restrict__ W1,
  const float* __restrict__ as1, const float* __restrict__ ad1, const float* __restrict__ b1,
  const float* __restrict__ as2, const float* __restrict__ ad2,
  const int* __restrict__ offs, const int* __restrict__ csr,
  const u16* __restrict__ w2gB,
  u16* __restrict__ h2u, float* __restrict__ asc, float* __restrict__ adc)
{
  int tid = threadIdx.x, w = tid>>6, lane = tid&63;
  int m = lane&15, q = lane>>4;
  int t = blockIdx.y;
  int node = blockIdx.x*64 + w*16 + m;
  unsigned un=(unsigned)node, b=un/N_, n=un-b*N_;

  // W2 B-fragments (16 VGPR, loaded once; L2-hot)
  const half8* wb = (const half8*)w2gB;
  half8 w2f0 = wb[0*64+lane], w2f1 = wb[1*64+lane],
        w2f2 = wb[2*64+lane], w2f3 = wb[3*64+lane];

  // head-q GAT1 score weights
  float sS=0.f, sD=0.f;
  #pragma unroll
  for(int c=0;c<8;c++){ float wv=W1[q*8+c]; sS+=wv*as1[q*8+c]; sD+=wv*ad1[q*8+c]; }

  const float* xsl = x_seq + (size_t)(b*T_+t)*N_;
  float xm = xsl[n];
  int e0=offs[node], e1=offs[node+1];
  float sum=0.f, ax=0.f;
  for(int e=e0;e<e1;e++){
    float xv = xsl[csr[e]];
    float ee = xv*sS + xm*sD; ee = ee>0.f ? ee : 0.2f*ee;
    float wv = __expf(ee); sum += wv; ax += wv*xv;
  }
  float A = ax/(sum+1e-16f);

  // A-fragment: out1[m][q*8+j]
  half8 af;
  #pragma unroll
  for(int j=0;j<8;j++){
    float v = A*W1[q*8+j] + b1[q*8+j]; v = v>0.f?v:0.f;
    af[j] = (_Float16)v;
  }
  f32x4 ac0={0.f,0.f,0.f,0.f}, ac1=ac0, ac2=ac0, ac3=ac0;
  ac0 = __builtin_amdgcn_mfma_f32_16x16x32_f16(af, w2f0, ac0,0,0,0);
  ac1 = __builtin_amdgcn_mfma_f32_16x16x32_f16(af, w2f1, ac1,0,0,0);
  ac2 = __builtin_amdgcn_mfma_f32_16x16x32_f16(af, w2f2, ac2,0,0,0);
  ac3 = __builtin_amdgcn_mfma_f32_16x16x32_f16(af, w2f3, ac3,0,0,0);

  // h2u stores: D row q*4+rg -> node base+q*4+rg, col nt*16+m (bf16)
  size_t hbase = (size_t)t*M_;
  int ndbase = blockIdx.x*64 + w*16 + q*4;
  #pragma unroll
  for(int rg=0;rg<4;rg++){
    u16* row = h2u + (hbase + ndbase + rg)*64;
    row[ 0+m] = f2bu(ac0[rg]);
    row[16+m] = f2bu(ac1[rg]);
    row[32+m] = f2bu(ac2[rg]);
    row[48+m] = f2bu(ac3[rg]);
  }

  // asc/adc: score[h][rg] = sum_m acc[h][rg]*a2s[h*16+m]
  float a2sv[4], a2dv[4];
  #pragma unroll
  for(int h=0;h<4;h++){ a2sv[h]=as2[h*16+m]; a2dv[h]=ad2[h*16+m]; }
  float pa[16], pd[16];
  #pragma unroll
  for(int rg=0;rg<4;rg++){
    pa[0*4+rg]=ac0[rg]*a2sv[0]; pd[0*4+rg]=ac0[rg]*a2dv[0];
    pa[1*4+rg]=ac1[rg]*a2sv[1]; pd[1*4+rg]=ac1[rg]*a2dv[1];
    pa[2*4+rg]=ac2[rg]*a2sv[2]; pd[2*4+rg]=ac2[rg]*a2dv[2];
    pa[3*4+rg]=ac3[rg]*a2sv[3]; pd[3*4+rg]=ac3[rg]*a2dv[3];
  }
  float ra = redsel16(pa, m);   // lane m -> value h*4+rg with h=m>>2, rg=m&3
  float rd = redsel16(pd, m);
  {
    int h=m>>2, rg=m&3;
    size_t nd = hbase + ndbase + rg;
    asc[nd*4+h] = ra;
    adc[nd*4+h] = rd;
  }
}

// ---------------- GAT2 softmax-aggregate + bias + relu + PE(table); f16 out ------
// Round-6: h2u gathers widened to uint4 (2 instrs/edge vs 4), seq stores
// packed to 2x uint4 (vs 16 scalar u16). Arithmetic bit-identical.
__global__ __launch_bounds__(256) void k_gat2b(
  const u16* __restrict__ h2u, const float* __restrict__ asc, const float* __restrict__ adc,
  const float* __restrict__ b2, const int* __restrict__ offs, const int* __restrict__ csr,
  const float* __restrict__ peT, u16* __restrict__ seq)
{
  int t = blockIdx.y;
  int id = blockIdx.x*256 + threadIdx.x;
  int m = id>>2, h = id&3;
  unsigned um=(unsigned)m, b=um/N_;
  size_t base_s = (size_t)t*M_ + (size_t)b*N_;   // csr holds local indices
  float am = adc[((size_t)t*M_+m)*4+h];
  int e0=offs[m], e1=offs[m+1];
  float sum=0.f;
  float A[16];
  #pragma unroll
  for(int c=0;c<16;c++) A[c]=0.f;
  for(int e=e0;e<e1;e++){
    size_t s = base_s + (unsigned)csr[e];
    float ee = asc[s*4+h] + am; ee = ee>0.f ? ee : 0.2f*ee;
    float w = __expf(ee); sum += w;
    const uint4* hp = (const uint4*)(h2u + s*64 + h*16);
    uint4 p0 = hp[0], p1 = hp[1];
    A[ 0] += w*bfu((u16)(p0.x)); A[ 1] += w*bfu((u16)(p0.x>>16));
    A[ 2] += w*bfu((u16)(p0.y)); A[ 3] += w*bfu((u16)(p0.y>>16));
    A[ 4] += w*bfu((u16)(p0.z)); A[ 5] += w*bfu((u16)(p0.z>>16));
    A[ 6] += w*bfu((u16)(p0.w)); A[ 7] += w*bfu((u16)(p0.w>>16));
    A[ 8] += w*bfu((u16)(p1.x)); A[ 9] += w*bfu((u16)(p1.x>>16));
    A[10] += w*bfu((u16)(p1.y)); A[11] += w*bfu((u16)(p1.y>>16));
    A[12] += w*bfu((u16)(p1.z)); A[13] += w*bfu((u16)(p1.z>>16));
    A[14] += w*bfu((u16)(p1.w)); A[15] += w*bfu((u16)(p1.w>>16));
  }
  float inv = 1.f/(sum + 1e-16f);
  u16 ov[16];
  #pragma unroll
  for(int c=0;c<16;c++){
    int ch = h*16 + c;
    float v = A[c]*inv + b2[ch]; v = v>0.f ? v : 0.f;
    ov[c] = f2h(v + peT[t*64+ch]);
  }
  uint4 o0, o1;
  o0.x = (unsigned)ov[0] | ((unsigned)ov[1]<<16);
  o0.y = (unsigned)ov[2] | ((unsigned)ov[3]<<16);
  o0.z = (unsigned)ov[4] | ((unsigned)ov[5]<<16);
  o0.w = (unsigned)ov[6] | ((unsigned)ov[7]<<16);
  o1.x = (unsigned)ov[8] | ((unsigned)ov[9]<<16);
  o1.y = (unsigned)ov[10]| ((unsigned)ov[11]<<16);
  o1.z = (unsigned)ov[12]| ((unsigned)ov[13]<<16);
  o1.w = (unsigned)ov[14]| ((unsigned)ov[15]<<16);
  uint4* op = (uint4*)(seq + ((size_t)t*M_ + m)*64 + h*16);
  op[0] = o0; op[1] = o1;
}

// ---------------- BOTH transformer layers + fused head (R16-measured form) -------
// X u16 [48][72]: layer input (wave-private rows). QKV u16 [3][48][72]; K,V
// overlaid by H[48][136]. A = activations (standard orientation; the operand
// swap was tried TWICE and both times tripled LDS bank conflicts -- do not
// retry). Register-carried residual (xres) was tried once: VGPR 68->84,
// VALUBusy -15pts, +48us -- do not retry.
__global__ __launch_bounds__(192) void k_layer2(
  const u16* __restrict__ seq,
  const u16* __restrict__ wqB, const u16* __restrict__ woB,
  const u16* __restrict__ w1B, const u16* __restrict__ w2B,
  const float* __restrict__ bqkv, const float* __restrict__ bo,
  const float* __restrict__ bf1,  const float* __restrict__ bf2,
  const float* __restrict__ g1,   const float* __restrict__ be1,
  const float* __restrict__ g2,   const float* __restrict__ be2,
  const float* __restrict__ Wh,   const float* __restrict__ bh,
  float* __restrict__ out)
{
  __shared__ __align__(16) u16 X[3456];      // [48][72] f16
  __shared__ __align__(16) u16 QKV[10368];   // [3][48][72]
  u16* Hd = QKV + 3456;                      // H[48][136] overlays K,V
  int tid=threadIdx.x, w=tid>>6, lane=tid&63;
  int m=lane&15, q=lane>>4;
  int r = w*16 + m;

  // stage X: wave w loads its own 16 rows (wave-private, no barrier needed).
  // Each row = 128B = 8 lanes x 16B; 2 dwordx4 loads/lane replace 16 scalar.
  #pragma unroll
  for(int half=0; half<2; half++){
    int rr = half*8 + (lane>>3);
    int row = w*16 + rr;
    int nn = row/12, tt = row-nn*12;
    const uint4* src = (const uint4*)(seq + ((size_t)tt*M_ + (size_t)blockIdx.x*4+nn)*64) + (lane&7);
    *((uint4*)&X[row*72] + (lane&7)) = *src;
  }

  #pragma unroll 1
  for(int l=0; l<2; l++){
    const half8* wqv = (const half8*)(wqB + (size_t)l*12288);
    const half8* wov = (const half8*)(woB + (size_t)l*4096);
    const half8* w1v = (const half8*)(w1B + (size_t)l*8192);
    const half8* w2v = (const half8*)(w2B + (size_t)l*8192);
    const float* bq = bqkv + l*192;
    const float* boL = bo + l*64;
    const float* b1L = bf1 + l*128;
    const float* b2L = bf2 + l*64;
    const float* g1L = g1 + l*64, *be1L = be1 + l*64;
    const float* g2L = g2 + l*64, *be2L = be2 + l*64;

    // ---- QKV projection: A-frags from X (wave-own rows) ----
    half8 xa0 = *(const half8*)&X[r*72 + q*8];
    half8 xa1 = *(const half8*)&X[r*72 + 32 + q*8];
    #pragma unroll
    for(int nt=0; nt<12; nt++){
      f32x4 acc={0.f,0.f,0.f,0.f};
      acc = __builtin_amdgcn_mfma_f32_16x16x32_f16(xa0, wqv[(nt*2+0)*64+lane], acc,0,0,0);
      acc = __builtin_amdgcn_mfma_f32_16x16x32_f16(xa1, wqv[(nt*2+1)*64+lane], acc,0,0,0);
      int cg = nt*16+m; float bias = bq[cg];
      int s = nt>>2, lc = cg&63;
      #pragma unroll
      for(int rg=0;rg<4;rg++){
        int row = w*16 + q*4 + rg;
        QKV[s*3456 + row*72 + lc] = f2h(acc[rg]+bias);
      }
    }
    __syncthreads();

    // ---- attention: 192 lanes = (node an, head ah, time at); fdot2 + pk_fma ----
    {
      int an = tid/48, rem = tid - an*48;
      int ah = rem/12, at = rem - ah*12;
      u16* qrow = &QKV[(an*12+at)*72 + ah*16];
      uint4 qa = ((const uint4*)qrow)[0], qb = ((const uint4*)qrow)[1];
      float s[12];
      #pragma unroll
      for(int t2=0;t2<12;t2++){
        const uint4* kp = (const uint4*)&QKV[3456 + (an*12+t2)*72 + ah*16];
        uint4 ka=kp[0], kb=kp[1];
        float d=0.f;
        d=__builtin_amdgcn_fdot2(u2h(qa.x),u2h(ka.x),d,false);
        d=__builtin_amdgcn_fdot2(u2h(qa.y),u2h(ka.y),d,false);
        d=__builtin_amdgcn_fdot2(u2h(qa.z),u2h(ka.z),d,false);
        d=__builtin_amdgcn_fdot2(u2h(qa.w),u2h(ka.w),d,false);
        d=__builtin_amdgcn_fdot2(u2h(qb.x),u2h(kb.x),d,false);
        d=__builtin_amdgcn_fdot2(u2h(qb.y),u2h(kb.y),d,false);
        d=__builtin_amdgcn_fdot2(u2h(qb.z),u2h(kb.z),d,false);
        d=__builtin_amdgcn_fdot2(u2h(qb.w),u2h(kb.w),d,false);
        s[t2] = d*0.25f;
      }
      float mx=s[0];
      #pragma unroll
      for(int t2=1;t2<12;t2++) mx=fmaxf(mx,s[t2]);
      float sum=0.f;
      #pragma unroll
      for(int t2=0;t2<12;t2++){ s[t2]=__expf(s[t2]-mx); sum+=s[t2]; }
      float inv=1.f/sum;
      half8 o0, o1;
      #pragma unroll
      for(int i=0;i<8;i++){ o0[i]=(_Float16)0.f; o1[i]=(_Float16)0.f; }
      #pragma unroll
      for(int t2=0;t2<12;t2++){
        const half8* vr = (const half8*)&QKV[6912 + (an*12+t2)*72 + ah*16];
        _Float16 wh = (_Float16)s[t2];
        o0 += vr[0]*wh; o1 += vr[1]*wh;
      }
      _Float16 ih = (_Float16)inv;
      ((half8*)qrow)[0]=o0*ih; ((half8*)qrow)[1]=o1*ih;
    }
    __syncthreads();

    // ---- Wo + residual(X) + LN1 ----
    half8 oa0 = *(const half8*)&QKV[r*72 + q*8];
    half8 oa1 = *(const half8*)&QKV[r*72 + 32 + q*8];
    float y[4][4];
    #pragma unroll
    for(int nt=0;nt<4;nt++){
      f32x4 acc={0.f,0.f,0.f,0.f};
      acc = __builtin_amdgcn_mfma_f32_16x16x32_f16(oa0, wov[(nt*2+0)*64+lane], acc,0,0,0);
      acc = __builtin_amdgcn_mfma_f32_16x16x32_f16(oa1, wov[(nt*2+1)*64+lane], acc,0,0,0);
      int col=nt*16+m; float bias=boL[col];
      #pragma unroll
      for(int rg=0;rg<4;rg++)
        y[nt][rg] = acc[rg] + bias + h2f(X[(w*16+q*4+rg)*72 + col]);
    }
    float mu[4], rs[4];
    #pragma unroll
    for(int rg=0;rg<4;rg++){
      float sm=(y[0][rg]+y[1][rg])+(y[2][rg]+y[3][rg]);
      sm+=__shfl_xor(sm,1); sm+=__shfl_xor(sm,2); sm+=__shfl_xor(sm,4); sm+=__shfl_xor(sm,8);
      mu[rg]=sm*(1.f/64.f);
      float d0=y[0][rg]-mu[rg],d1=y[1][rg]-mu[rg],d2=y[2][rg]-mu[rg],d3=y[3][rg]-mu[rg];
      float vv=(d0*d0+d1*d1)+(d2*d2+d3*d3);
      vv+=__shfl_xor(vv,1); vv+=__shfl_xor(vv,2); vv+=__shfl_xor(vv,4); vv+=__shfl_xor(vv,8);
      rs[rg]=rsqrtf(vv*(1.f/64.f)+1e-5f);
    }
    #pragma unroll
    for(int nt=0;nt<4;nt++){
      int col=nt*16+m; float g=g1L[col], be=be1L[col];
      #pragma unroll
      for(int rg=0;rg<4;rg++){
        float v=(y[nt][rg]-mu[rg])*rs[rg]*g+be;
        y[nt][rg]=v;                                  // FF residual (f32)
        QKV[(w*16+q*4+rg)*72 + col]=f2h(v);           // y -> wave-own rows
      }
    }

    // ---- FF1: y A-frags; H -> pitch-136 overlay ----
    half8 ya0 = *(const half8*)&QKV[r*72 + q*8];
    half8 ya1 = *(const half8*)&QKV[r*72 + 32 + q*8];
    #pragma unroll
    for(int nt=0;nt<8;nt++){
      f32x4 acc={0.f,0.f,0.f,0.f};
      acc = __builtin_amdgcn_mfma_f32_16x16x32_f16(ya0, w1v[(nt*2+0)*64+lane], acc,0,0,0);
      acc = __builtin_amdgcn_mfma_f32_16x16x32_f16(ya1, w1v[(nt*2+1)*64+lane], acc,0,0,0);
      float bias=b1L[nt*16+m];
      #pragma unroll
      for(int rg=0;rg<4;rg++)
        Hd[(w*16+q*4+rg)*136 + nt*16+m] = f2h(fmaxf(acc[rg]+bias, 0.f));
    }

    // ---- FF2 + residual y + LN2 ----
    half8 ha[4];
    #pragma unroll
    for(int c=0;c<4;c++)
      ha[c] = *(const half8*)&Hd[r*136 + c*32 + q*8];
    #pragma unroll
    for(int nt=0;nt<4;nt++){
      f32x4 acc={0.f,0.f,0.f,0.f};
      #pragma unroll
      for(int c=0;c<4;c++)
        acc = __builtin_amdgcn_mfma_f32_16x16x32_f16(ha[c], w2v[(nt*4+c)*64+lane], acc,0,0,0);
      int col=nt*16+m; float bias=b2L[col];
      #pragma unroll
      for(int rg=0;rg<4;rg++)
        y[nt][rg] = acc[rg] + bias + y[nt][rg];
    }
    #pragma unroll
    for(int rg=0;rg<4;rg++){
      float sm=(y[0][rg]+y[1][rg])+(y[2][rg]+y[3][rg]);
      sm+=__shfl_xor(sm,1); sm+=__shfl_xor(sm,2); sm+=__shfl_xor(sm,4); sm+=__shfl_xor(sm,8);
      mu[rg]=sm*(1.f/64.f);
      float d0=y[0][rg]-mu[rg],d1=y[1][rg]-mu[rg],d2=y[2][rg]-mu[rg],d3=y[3][rg]-mu[rg];
      float vv=(d0*d0+d1*d1)+(d2*d2+d3*d3);
      vv+=__shfl_xor(vv,1); vv+=__shfl_xor(vv,2); vv+=__shfl_xor(vv,4); vv+=__shfl_xor(vv,8);
      rs[rg]=rsqrtf(vv*(1.f/64.f)+1e-5f);
    }
    if(l==0){
      #pragma unroll
      for(int nt=0;nt<4;nt++){
        int col=nt*16+m; float g=g2L[col], be=be2L[col];
        #pragma unroll
        for(int rg=0;rg<4;rg++)
          X[(w*16+q*4+rg)*72 + col] = f2h((y[nt][rg]-mu[rg])*rs[rg]*g + be);
      }
      __syncthreads();   // before next layer's QKV scatter overwrites QKV regions
    } else {
      // fused prediction head: rows with t==11 are rg==3 of exactly one
      // q-group per node; condition uniform over the 16-lane m-group.
      int rc = w*16 + q*4 + 3;
      int nn = rc/12;
      if(rc - nn*12 == 11){
        float vfin[4];
        #pragma unroll
        for(int nt=0;nt<4;nt++){
          int col=nt*16+m;
          vfin[nt] = (y[nt][3]-mu[3])*rs[3]*g2L[col] + be2L[col];
        }
        int gm = blockIdx.x*4 + nn;
        unsigned bb=(unsigned)gm/N_, n2=(unsigned)gm-bb*N_;
        #pragma unroll
        for(int h3=0;h3<3;h3++){
          float p = vfin[0]*Wh[h3*64+m]    + vfin[1]*Wh[h3*64+16+m]
                  + vfin[2]*Wh[h3*64+32+m] + vfin[3]*Wh[h3*64+48+m];
          p += __shfl_xor(p,1); p += __shfl_xor(p,2);
          p += __shfl_xor(p,4); p += __shfl_xor(p,8);
          if(m==0) out[(bb*3+h3)*N_+n2] = p + bh[h3];
        }
      }
    }
  }
}

extern "C" void kernel_launch(void* const* d_in, const int* in_sizes, int n_in,
                              void* d_out, int out_size, void* d_ws, size_t ws_size,
                              hipStream_t stream)
{
  const float* x_seq=(const float*)d_in[0];
  const int*   ei   =(const int*)d_in[1];
  const float* W1   =(const float*)d_in[2];
  const float* as1  =(const float*)d_in[3];
  const float* ad1  =(const float*)d_in[4];
  const float* b1   =(const float*)d_in[5];
  const float* W2   =(const float*)d_in[6];
  const float* as2  =(const float*)d_in[7];
  const float* ad2  =(const float*)d_in[8];
  const float* b2   =(const float*)d_in[9];
  const float* Wqkv =(const float*)d_in[10];
  const float* bqkv =(const float*)d_in[11];
  const float* Wo   =(const float*)d_in[12];
  const float* bo   =(const float*)d_in[13];
  const float* Wf1  =(const float*)d_in[14];
  const float* bf1p =(const float*)d_in[15];
  const float* Wf2  =(const float*)d_in[16];
  const float* bf2p =(const float*)d_in[17];
  const float* g1   =(const float*)d_in[18];
  const float* be1  =(const float*)d_in[19];
  const float* g2   =(const float*)d_in[20];
  const float* be2  =(const float*)d_in[21];
  const float* Wh   =(const float*)d_in[22];
  const float* bh   =(const float*)d_in[23];

  // workspace layout (~112 MB)
  u16* seqh   = (u16*)d_ws;                     // [T][M][64] f16  24,576,000 u16
  float* asc  = (float*)(seqh + 24576000);      // [T][M][4]        1,536,000 f
  float* adc  = asc + 1536000;                  //                  1,536,000 f
  int* deg    = (int*)(adc + 1536000);
  int* cursor = deg + M_;
  int* offs   = cursor + M_;                    // M_+1 used
  int* bsums  = offs + (M_ + 2);
  int* boffs  = bsums + 128;
  int* csr    = boffs + 128;                    // ETOT
  u16* h2u    = (u16*)(csr + ETOT);             // [T][M][64]   24,576,000 u16
  u16* wqB    = h2u + (size_t)T_*M_*64;         // 24576
  u16* woB    = wqB + 24576;                    // 8192
  u16* w1B    = woB + 8192;                     // 16384
  u16* w2B    = w1B + 16384;                    // 16384
  float* peT  = (float*)(w2B + 16384);          // 768
  u16* w2gB   = (u16*)(peT + 768);              // 2048

  k_prep   <<<dim3(268), dim3(256), 0, stream>>>(Wqkv, Wo, Wf1, Wf2, W2,
                                                 wqB, woB, w1B, w2B, peT, w2gB);

  // CSR build (edge list identical for all t)
  hipMemsetAsync(deg, 0, (size_t)2*M_*sizeof(int), stream);   // deg + cursor
  k_hist   <<<dim3((ETOT+255)/256), dim3(256), 0, stream>>>(ei, deg);
  k_scan1  <<<dim3(125), dim3(256), 0, stream>>>(deg, offs, bsums);
  k_scan23 <<<dim3(125), dim3(256), 0, stream>>>(offs, bsums);
  k_scatter<<<dim3((ETOT+255)/256), dim3(256), 0, stream>>>(ei, offs, cursor, csr);

  k_gat12<<<dim3(500,T_), dim3(256), 0, stream>>>(x_seq, W1, as1, ad1, b1,
                                                  as2, ad2, offs, csr, w2gB,
                                                  h2u, asc, adc);
  k_gat2b<<<dim3(500,T_), dim3(256), 0, stream>>>(h2u, asc, adc, b2, offs, csr, peT, seqh);

  k_layer2<<<dim3(8000), dim3(192), 0, stream>>>(seqh,
      wqB, woB, w1B, w2B,
      bqkv, bo, bf1p, bf2p,
      g1, be1, g2, be2,
      Wh, bh, (float*)d_out);
}

// Round 7
// 374.459 us; speedup vs baseline: 1.2181x; 1.0276x over previous
//
#include <hip/hip_runtime.h>
#include <hip/hip_bf16.h>

#define B_ 16
#define T_ 12
#define N_ 2000
#define E_ 8000
#define M_ 32000                 // B_*N_
#define ETOT (B_*E_ + M_)        // 160000 edges incl. self loops
#define D_ 64

typedef __hip_bfloat16 bf16;
typedef unsigned short u16;
typedef __attribute__((ext_vector_type(8))) _Float16 half8;
typedef __attribute__((ext_vector_type(2))) _Float16 h2v;
typedef __attribute__((ext_vector_type(4))) float f32x4;

__device__ __forceinline__ float bfu(u16 u){ return __uint_as_float(((unsigned int)u)<<16); }
__device__ __forceinline__ u16 f2bu(float f){
  unsigned int x = __float_as_uint(f);
  x += 0x7FFFu + ((x >> 16) & 1u);
  return (u16)(x >> 16);
}
__device__ __forceinline__ u16 f2h(float f){
  _Float16 h = (_Float16)f; u16 r; __builtin_memcpy(&r, &h, 2); return r;
}
__device__ __forceinline__ float h2f(u16 u){
  _Float16 h; __builtin_memcpy(&h, &u, 2); return (float)h;
}
__device__ __forceinline__ h2v u2h(unsigned u){ h2v r; __builtin_memcpy(&r,&u,4); return r; }

// multi-value butterfly reduce over a 16-lane group: lane m returns
// sum over the 16 lanes of value index m. (verified form -- do not edit)
__device__ __forceinline__ float redsel16(const float v[16], int m){
  float c8[8];
  #pragma unroll
  for(int i=0;i<8;i++){
    float send = (m&8)? v[i]   : v[i+8];
    float keep = (m&8)? v[i+8] : v[i];
    c8[i] = keep + __shfl_xor(send, 8);
  }
  float c4[4];
  #pragma unroll
  for(int i=0;i<4;i++){
    float send = (m&4)? c8[i]   : c8[i+4];
    float keep = (m&4)? c8[i+4] : c8[i];
    c4[i] = keep + __shfl_xor(send, 4);
  }
  float c2[2];
  #pragma unroll
  for(int i=0;i<2;i++){
    float send = (m&2)? c4[i]   : c4[i+2];
    float keep = (m&2)? c4[i+2] : c4[i];
    c2[i] = keep + __shfl_xor(send, 2);
  }
  float send = (m&1)? c2[0] : c2[1];
  float keep = (m&1)? c2[1] : c2[0];
  return keep + __shfl_xor(send, 1);
}

// ---------------- weight prep: f16 MFMA B-fragments + PE table ----------------
__global__ void k_prep(const float* __restrict__ Wqkv, const float* __restrict__ Wo,
                       const float* __restrict__ Wf1, const float* __restrict__ Wf2,
                       const float* __restrict__ W2g,
                       u16* __restrict__ wqB, u16* __restrict__ woB,
                       u16* __restrict__ w1B, u16* __restrict__ w2B,
                       float* __restrict__ peT, u16* __restrict__ w2gB){
  int i = blockIdx.x*256 + threadIdx.x;    // 268 blocks
  if(i < 24576){
    int l=i/12288, r=i-l*12288;
    int nt=r>>10, r2=r&1023, c=r2>>9, r3=r2&511, lane=r3>>3, jj=r3&7;
    int m=lane&15, q=lane>>4;
    wqB[i] = f2h(Wqkv[l*12288 + (nt*16+m)*64 + c*32 + q*8 + jj]);
  } else if(i < 32768){
    int k2=i-24576;
    int l=k2>>12, r=k2&4095;
    int nt=r>>10, r2=r&1023, c=r2>>9, r3=r2&511, lane=r3>>3, jj=r3&7;
    int m=lane&15, q=lane>>4;
    woB[k2] = f2h(Wo[l*4096 + (nt*16+m)*64 + c*32 + q*8 + jj]);
  } else if(i < 49152){
    int k2=i-32768;
    int l=k2>>13, r=k2&8191;
    int nt=r>>10, r2=r&1023, c=r2>>9, r3=r2&511, lane=r3>>3, jj=r3&7;
    int m=lane&15, q=lane>>4;
    w1B[k2] = f2h(Wf1[l*8192 + (nt*16+m)*64 + c*32 + q*8 + jj]);
  } else if(i < 65536){
    int k2=i-49152;
    int l=k2>>13, r=k2&8191;
    int nt=r>>11, r2=r&2047, c=r2>>9, r3=r2&511, lane=r3>>3, jj=r3&7;
    int m=lane&15, q=lane>>4;
    w2B[k2] = f2h(Wf2[l*8192 + (nt*16+m)*128 + c*32 + q*8 + jj]);
  } else {
    int i2 = i - 65536;
    if(i2 < 768){
      int t=i2>>6, ch=i2&63;
      float ang = (float)t * __expf(-0.14391156463f * (float)(ch & ~1));
      peT[i2] = (ch&1) ? __cosf(ang) : __sinf(ang);
    } else if(i2 < 768+2048){
      // GAT2 W2 [32][64] as B-frags: elem j = W2[q*8+j][nt*16+m]
      int i3 = i2-768;
      int nt=i3>>9, r=i3&511, lane=r>>3, j=r&7;
      int m=lane&15, q=lane>>4;
      w2gB[i3] = f2h(W2g[(q*8+j)*64 + nt*16 + m]);
    }
  }
}

// ---------------- CSR build ----------------
__global__ void k_hist(const int* __restrict__ ei, int* __restrict__ deg){
  int e = blockIdx.x*256 + threadIdx.x; if(e>=ETOT) return;
  int dst;
  if (e < B_*E_){ int b = e / E_; int k = e - b*E_; dst = ei[E_ + k] + b*N_; }
  else dst = e - B_*E_;
  atomicAdd(&deg[dst], 1);
}

__global__ void k_scan1(const int* __restrict__ deg, int* __restrict__ offs, int* __restrict__ bsums){
  __shared__ int s[256];
  int tid = threadIdx.x; int g = blockIdx.x*256 + tid;
  s[tid] = deg[g]; __syncthreads();
  for(int off=1; off<256; off<<=1){
    int a = (tid>=off) ? s[tid-off] : 0; __syncthreads();
    s[tid] += a; __syncthreads();
  }
  offs[g+1] = s[tid];
  if(tid==255) bsums[blockIdx.x] = s[255];
}

// merged scan2+scan3: every block redundantly scans the 125 block sums
// (trivial) and applies its own prefix. One launch instead of two.
__global__ void k_scan23(int* __restrict__ offs, const int* __restrict__ bsums){
  __shared__ int s[128];
  int tid = threadIdx.x; int g = blockIdx.x*256 + tid;
  if(tid<128) s[tid] = (tid<125) ? bsums[tid] : 0;
  __syncthreads();
  for(int off=1; off<128; off<<=1){
    int a = 0;
    if(tid<128 && tid>=off) a = s[tid-off];
    __syncthreads();
    if(tid<128) s[tid] += a;
    __syncthreads();
  }
  int boff = (blockIdx.x==0) ? 0 : s[blockIdx.x-1];
  offs[g+1] += boff;
  if(g==0) offs[0]=0;
}

// csr stores LOCAL src index (all edges intra-graph) -> gat kernels skip /N_
__global__ void k_scatter(const int* __restrict__ ei, const int* __restrict__ offs,
                          int* __restrict__ cursor, int* __restrict__ csr){
  int e = blockIdx.x*256 + threadIdx.x; if(e>=ETOT) return;
  int srcl, dst;
  if (e < B_*E_){ int b=e/E_; int k=e-b*E_; srcl=ei[k]; dst=ei[E_+k]+b*N_; }
  else { dst = e - B_*E_; int b=dst/N_; srcl = dst - b*N_; }
  int pos = atomicAdd(&cursor[dst], 1);
  csr[offs[dst]+pos] = srcl;
}

// ---------------- fused GAT1 + GAT2 feature/score (MFMA) ----------------
// Lane q*16+m: node m (of wave's 16), head q. Round-7: edge loop split
// 4-ways across the q-lanes (lane processes edges e0+q, e0+q+4, ...) with
// all 4 heads accumulated, then butterfly over shfl_xor(16/32) -- restores
// the round-0 parallel-edge structure (5 exp/lane instead of round-5's 20)
// while keeping the MFMA W2 epilogue. Summation order == round-0 form.
__global__ __launch_bounds__(256) void k_gat12(
  const float* __restrict__ x_seq, const float* __restrict__ W1,
  const float* __restrict__ as1, const float* __restrict__ ad1, const float* __restrict__ b1,
  const float* __restrict__ as2, const float* __restrict__ ad2,
  const int* __restrict__ offs, const int* __restrict__ csr,
  const u16* __restrict__ w2gB,
  u16* __restrict__ h2u, float* __restrict__ asc, float* __restrict__ adc)
{
  int tid = threadIdx.x, w = tid>>6, lane = tid&63;
  int m = lane&15, q = lane>>4;
  int t = blockIdx.y;
  int node = blockIdx.x*64 + w*16 + m;
  unsigned un=(unsigned)node, b=un/N_, n=un-b*N_;

  // W2 B-fragments (16 VGPR, loaded once; L2-hot)
  const half8* wb = (const half8*)w2gB;
  half8 w2f0 = wb[0*64+lane], w2f1 = wb[1*64+lane],
        w2f2 = wb[2*64+lane], w2f3 = wb[3*64+lane];

  // all-head GAT1 score weights (scalar-cached loads)
  float sS[4], sD[4];
  #pragma unroll
  for(int h=0;h<4;h++){
    float a=0.f, d=0.f;
    #pragma unroll
    for(int c=0;c<8;c++){ float wv=W1[h*8+c]; a+=wv*as1[h*8+c]; d+=wv*ad1[h*8+c]; }
    sS[h]=a; sD[h]=d;
  }

  const float* xsl = x_seq + (size_t)(b*T_+t)*N_;
  float xm = xsl[n];
  int e0=offs[node], e1=offs[node+1];
  float sum[4]={0.f,0.f,0.f,0.f}, ax[4]={0.f,0.f,0.f,0.f};
  for(int e=e0+q; e<e1; e+=4){
    float xv = xsl[csr[e]];
    #pragma unroll
    for(int h=0;h<4;h++){
      float ee = xv*sS[h] + xm*sD[h]; ee = ee>0.f ? ee : 0.2f*ee;
      float wv = __expf(ee); sum[h]+=wv; ax[h]+=wv*xv;
    }
  }
  // q-dimension lives in lane bits 4-5: butterfly over xor 16, 32
  #pragma unroll
  for(int h=0;h<4;h++){
    sum[h] += __shfl_xor(sum[h],16); sum[h] += __shfl_xor(sum[h],32);
    ax[h]  += __shfl_xor(ax[h],16);  ax[h]  += __shfl_xor(ax[h],32);
  }
  float A = ax[q]/(sum[q]+1e-16f);

  // A-fragment: out1[m][q*8+j]
  half8 af;
  #pragma unroll
  for(int j=0;j<8;j++){
    float v = A*W1[q*8+j] + b1[q*8+j]; v = v>0.f?v:0.f;
    af[j] = (_Float16)v;
  }
  f32x4 ac0={0.f,0.f,0.f,0.f}, ac1=ac0, ac2=ac0, ac3=ac0;
  ac0 = __builtin_amdgcn_mfma_f32_16x16x32_f16(af, w2f0, ac0,0,0,0);
  ac1 = __builtin_amdgcn_mfma_f32_16x16x32_f16(af, w2f1, ac1,0,0,0);
  ac2 = __builtin_amdgcn_mfma_f32_16x16x32_f16(af, w2f2, ac2,0,0,0);
  ac3 = __builtin_amdgcn_mfma_f32_16x16x32_f16(af, w2f3, ac3,0,0,0);

  // h2u stores: D row q*4+rg -> node base+q*4+rg, col nt*16+m (bf16)
  size_t hbase = (size_t)t*M_;
  int ndbase = blockIdx.x*64 + w*16 + q*4;
  #pragma unroll
  for(int rg=0;rg<4;rg++){
    u16* row = h2u + (hbase + ndbase + rg)*64;
    row[ 0+m] = f2bu(ac0[rg]);
    row[16+m] = f2bu(ac1[rg]);
    row[32+m] = f2bu(ac2[rg]);
    row[48+m] = f2bu(ac3[rg]);
  }

  // asc/adc: score[h][rg] = sum_m acc[h][rg]*a2s[h*16+m]
  float a2sv[4], a2dv[4];
  #pragma unroll
  for(int h=0;h<4;h++){ a2sv[h]=as2[h*16+m]; a2dv[h]=ad2[h*16+m]; }
  float pa[16], pd[16];
  #pragma unroll
  for(int rg=0;rg<4;rg++){
    pa[0*4+rg]=ac0[rg]*a2sv[0]; pd[0*4+rg]=ac0[rg]*a2dv[0];
    pa[1*4+rg]=ac1[rg]*a2sv[1]; pd[1*4+rg]=ac1[rg]*a2dv[1];
    pa[2*4+rg]=ac2[rg]*a2sv[2]; pd[2*4+rg]=ac2[rg]*a2dv[2];
    pa[3*4+rg]=ac3[rg]*a2sv[3]; pd[3*4+rg]=ac3[rg]*a2dv[3];
  }
  float ra = redsel16(pa, m);   // lane m -> value h*4+rg with h=m>>2, rg=m&3
  float rd = redsel16(pd, m);
  {
    int h=m>>2, rg=m&3;
    size_t nd = hbase + ndbase + rg;
    asc[nd*4+h] = ra;
    adc[nd*4+h] = rd;
  }
}

// ---------------- GAT2 softmax-aggregate + bias + relu + PE(table); f16 out ------
// uint4 gathers + packed uint4 stores (round-6 measured form).
__global__ __launch_bounds__(256) void k_gat2b(
  const u16* __restrict__ h2u, const float* __restrict__ asc, const float* __restrict__ adc,
  const float* __restrict__ b2, const int* __restrict__ offs, const int* __restrict__ csr,
  const float* __restrict__ peT, u16* __restrict__ seq)
{
  int t = blockIdx.y;
  int id = blockIdx.x*256 + threadIdx.x;
  int m = id>>2, h = id&3;
  unsigned um=(unsigned)m, b=um/N_;
  size_t base_s = (size_t)t*M_ + (size_t)b*N_;   // csr holds local indices
  float am = adc[((size_t)t*M_+m)*4+h];
  int e0=offs[m], e1=offs[m+1];
  float sum=0.f;
  float A[16];
  #pragma unroll
  for(int c=0;c<16;c++) A[c]=0.f;
  for(int e=e0;e<e1;e++){
    size_t s = base_s + (unsigned)csr[e];
    float ee = asc[s*4+h] + am; ee = ee>0.f ? ee : 0.2f*ee;
    float w = __expf(ee); sum += w;
    const uint4* hp = (const uint4*)(h2u + s*64 + h*16);
    uint4 p0 = hp[0], p1 = hp[1];
    A[ 0] += w*bfu((u16)(p0.x)); A[ 1] += w*bfu((u16)(p0.x>>16));
    A[ 2] += w*bfu((u16)(p0.y)); A[ 3] += w*bfu((u16)(p0.y>>16));
    A[ 4] += w*bfu((u16)(p0.z)); A[ 5] += w*bfu((u16)(p0.z>>16));
    A[ 6] += w*bfu((u16)(p0.w)); A[ 7] += w*bfu((u16)(p0.w>>16));
    A[ 8] += w*bfu((u16)(p1.x)); A[ 9] += w*bfu((u16)(p1.x>>16));
    A[10] += w*bfu((u16)(p1.y)); A[11] += w*bfu((u16)(p1.y>>16));
    A[12] += w*bfu((u16)(p1.z)); A[13] += w*bfu((u16)(p1.z>>16));
    A[14] += w*bfu((u16)(p1.w)); A[15] += w*bfu((u16)(p1.w>>16));
  }
  float inv = 1.f/(sum + 1e-16f);
  u16 ov[16];
  #pragma unroll
  for(int c=0;c<16;c++){
    int ch = h*16 + c;
    float v = A[c]*inv + b2[ch]; v = v>0.f ? v : 0.f;
    ov[c] = f2h(v + peT[t*64+ch]);
  }
  uint4 o0, o1;
  o0.x = (unsigned)ov[0] | ((unsigned)ov[1]<<16);
  o0.y = (unsigned)ov[2] | ((unsigned)ov[3]<<16);
  o0.z = (unsigned)ov[4] | ((unsigned)ov[5]<<16);
  o0.w = (unsigned)ov[6] | ((unsigned)ov[7]<<16);
  o1.x = (unsigned)ov[8] | ((unsigned)ov[9]<<16);
  o1.y = (unsigned)ov[10]| ((unsigned)ov[11]<<16);
  o1.z = (unsigned)ov[12]| ((unsigned)ov[13]<<16);
  o1.w = (unsigned)ov[14]| ((unsigned)ov[15]<<16);
  uint4* op = (uint4*)(seq + ((size_t)t*M_ + m)*64 + h*16);
  op[0] = o0; op[1] = o1;
}

// ---------------- BOTH transformer layers + fused head (R16-measured form) -------
// X u16 [48][72]: layer input (wave-private rows). QKV u16 [3][48][72]; K,V
// overlaid by H[48][136]. A = activations (standard orientation; the operand
// swap was tried TWICE and both times tripled LDS bank conflicts -- do not
// retry). Register-carried residual (xres) was tried once: VGPR 68->84,
// VALUBusy -15pts, +48us -- do not retry.
__global__ __launch_bounds__(192) void k_layer2(
  const u16* __restrict__ seq,
  const u16* __restrict__ wqB, const u16* __restrict__ woB,
  const u16* __restrict__ w1B, const u16* __restrict__ w2B,
  const float* __restrict__ bqkv, const float* __restrict__ bo,
  const float* __restrict__ bf1,  const float* __restrict__ bf2,
  const float* __restrict__ g1,   const float* __restrict__ be1,
  const float* __restrict__ g2,   const float* __restrict__ be2,
  const float* __restrict__ Wh,   const float* __restrict__ bh,
  float* __restrict__ out)
{
  __shared__ __align__(16) u16 X[3456];      // [48][72] f16
  __shared__ __align__(16) u16 QKV[10368];   // [3][48][72]
  u16* Hd = QKV + 3456;                      // H[48][136] overlays K,V
  int tid=threadIdx.x, w=tid>>6, lane=tid&63;
  int m=lane&15, q=lane>>4;
  int r = w*16 + m;

  // stage X: wave w loads its own 16 rows (wave-private, no barrier needed).
  // Each row = 128B = 8 lanes x 16B; 2 dwordx4 loads/lane replace 16 scalar.
  #pragma unroll
  for(int half=0; half<2; half++){
    int rr = half*8 + (lane>>3);
    int row = w*16 + rr;
    int nn = row/12, tt = row-nn*12;
    const uint4* src = (const uint4*)(seq + ((size_t)tt*M_ + (size_t)blockIdx.x*4+nn)*64) + (lane&7);
    *((uint4*)&X[row*72] + (lane&7)) = *src;
  }

  #pragma unroll 1
  for(int l=0; l<2; l++){
    const half8* wqv = (const half8*)(wqB + (size_t)l*12288);
    const half8* wov = (const half8*)(woB + (size_t)l*4096);
    const half8* w1v = (const half8*)(w1B + (size_t)l*8192);
    const half8* w2v = (const half8*)(w2B + (size_t)l*8192);
    const float* bq = bqkv + l*192;
    const float* boL = bo + l*64;
    const float* b1L = bf1 + l*128;
    const float* b2L = bf2 + l*64;
    const float* g1L = g1 + l*64, *be1L = be1 + l*64;
    const float* g2L = g2 + l*64, *be2L = be2 + l*64;

    // ---- QKV projection: A-frags from X (wave-own rows) ----
    half8 xa0 = *(const half8*)&X[r*72 + q*8];
    half8 xa1 = *(const half8*)&X[r*72 + 32 + q*8];
    #pragma unroll
    for(int nt=0; nt<12; nt++){
      f32x4 acc={0.f,0.f,0.f,0.f};
      acc = __builtin_amdgcn_mfma_f32_16x16x32_f16(xa0, wqv[(nt*2+0)*64+lane], acc,0,0,0);
      acc = __builtin_amdgcn_mfma_f32_16x16x32_f16(xa1, wqv[(nt*2+1)*64+lane], acc,0,0,0);
      int cg = nt*16+m; float bias = bq[cg];
      int s = nt>>2, lc = cg&63;
      #pragma unroll
      for(int rg=0;rg<4;rg++){
        int row = w*16 + q*4 + rg;
        QKV[s*3456 + row*72 + lc] = f2h(acc[rg]+bias);
      }
    }
    __syncthreads();

    // ---- attention: 192 lanes = (node an, head ah, time at); fdot2 + pk_fma ----
    {
      int an = tid/48, rem = tid - an*48;
      int ah = rem/12, at = rem - ah*12;
      u16* qrow = &QKV[(an*12+at)*72 + ah*16];
      uint4 qa = ((const uint4*)qrow)[0], qb = ((const uint4*)qrow)[1];
      float s[12];
      #pragma unroll
      for(int t2=0;t2<12;t2++){
        const uint4* kp = (const uint4*)&QKV[3456 + (an*12+t2)*72 + ah*16];
        uint4 ka=kp[0], kb=kp[1];
        float d=0.f;
        d=__builtin_amdgcn_fdot2(u2h(qa.x),u2h(ka.x),d,false);
        d=__builtin_amdgcn_fdot2(u2h(qa.y),u2h(ka.y),d,false);
        d=__builtin_amdgcn_fdot2(u2h(qa.z),u2h(ka.z),d,false);
        d=__builtin_amdgcn_fdot2(u2h(qa.w),u2h(ka.w),d,false);
        d=__builtin_amdgcn_fdot2(u2h(qb.x),u2h(kb.x),d,false);
        d=__builtin_amdgcn_fdot2(u2h(qb.y),u2h(kb.y),d,false);
        d=__builtin_amdgcn_fdot2(u2h(qb.z),u2h(kb.z),d,false);
        d=__builtin_amdgcn_fdot2(u2h(qb.w),u2h(kb.w),d,false);
        s[t2] = d*0.25f;
      }
      float mx=s[0];
      #pragma unroll
      for(int t2=1;t2<12;t2++) mx=fmaxf(mx,s[t2]);
      float sum=0.f;
      #pragma unroll
      for(int t2=0;t2<12;t2++){ s[t2]=__expf(s[t2]-mx); sum+=s[t2]; }
      float inv=1.f/sum;
      half8 o0, o1;
      #pragma unroll
      for(int i=0;i<8;i++){ o0[i]=(_Float16)0.f; o1[i]=(_Float16)0.f; }
      #pragma unroll
      for(int t2=0;t2<12;t2++){
        const half8* vr = (const half8*)&QKV[6912 + (an*12+t2)*72 + ah*16];
        _Float16 wh = (_Float16)s[t2];
        o0 += vr[0]*wh; o1 += vr[1]*wh;
      }
      _Float16 ih = (_Float16)inv;
      ((half8*)qrow)[0]=o0*ih; ((half8*)qrow)[1]=o1*ih;
    }
    __syncthreads();

    // ---- Wo + residual(X) + LN1 ----
    half8 oa0 = *(const half8*)&QKV[r*72 + q*8];
    half8 oa1 = *(const half8*)&QKV[r*72 + 32 + q*8];
    float y[4][4];
    #pragma unroll
    for(int nt=0;nt<4;nt++){
      f32x4 acc={0.f,0.f,0.f,0.f};
      acc = __builtin_amdgcn_mfma_f32_16x16x32_f16(oa0, wov[(nt*2+0)*64+lane], acc,0,0,0);
      acc = __builtin_amdgcn_mfma_f32_16x16x32_f16(oa1, wov[(nt*2+1)*64+lane], acc,0,0,0);
      int col=nt*16+m; float bias=boL[col];
      #pragma unroll
      for(int rg=0;rg<4;rg++)
        y[nt][rg] = acc[rg] + bias + h2f(X[(w*16+q*4+rg)*72 + col]);
    }
    float mu[4], rs[4];
    #pragma unroll
    for(int rg=0;rg<4;rg++){
      float sm=(y[0][rg]+y[1][rg])+(y[2][rg]+y[3][rg]);
      sm+=__shfl_xor(sm,1); sm+=__shfl_xor(sm,2); sm+=__shfl_xor(sm,4); sm+=__shfl_xor(sm,8);
      mu[rg]=sm*(1.f/64.f);
      float d0=y[0][rg]-mu[rg],d1=y[1][rg]-mu[rg],d2=y[2][rg]-mu[rg],d3=y[3][rg]-mu[rg];
      float vv=(d0*d0+d1*d1)+(d2*d2+d3*d3);
      vv+=__shfl_xor(vv,1); vv+=__shfl_xor(vv,2); vv+=__shfl_xor(vv,4); vv+=__shfl_xor(vv,8);
      rs[rg]=rsqrtf(vv*(1.f/64.f)+1e-5f);
    }
    #pragma unroll
    for(int nt=0;nt<4;nt++){
      int col=nt*16+m; float g=g1L[col], be=be1L[col];
      #pragma unroll
      for(int rg=0;rg<4;rg++){
        float v=(y[nt][rg]-mu[rg])*rs[rg]*g+be;
        y[nt][rg]=v;                                  // FF residual (f32)
        QKV[(w*16+q*4+rg)*72 + col]=f2h(v);           // y -> wave-own rows
      }
    }

    // ---- FF1: y A-frags; H -> pitch-136 overlay ----
    half8 ya0 = *(const half8*)&QKV[r*72 + q*8];
    half8 ya1 = *(const half8*)&QKV[r*72 + 32 + q*8];
    #pragma unroll
    for(int nt=0;nt<8;nt++){
      f32x4 acc={0.f,0.f,0.f,0.f};
      acc = __builtin_amdgcn_mfma_f32_16x16x32_f16(ya0, w1v[(nt*2+0)*64+lane], acc,0,0,0);
      acc = __builtin_amdgcn_mfma_f32_16x16x32_f16(ya1, w1v[(nt*2+1)*64+lane], acc,0,0,0);
      float bias=b1L[nt*16+m];
      #pragma unroll
      for(int rg=0;rg<4;rg++)
        Hd[(w*16+q*4+rg)*136 + nt*16+m] = f2h(fmaxf(acc[rg]+bias, 0.f));
    }

    // ---- FF2 + residual y + LN2 ----
    half8 ha[4];
    #pragma unroll
    for(int c=0;c<4;c++)
      ha[c] = *(const half8*)&Hd[r*136 + c*32 + q*8];
    #pragma unroll
    for(int nt=0;nt<4;nt++){
      f32x4 acc={0.f,0.f,0.f,0.f};
      #pragma unroll
      for(int c=0;c<4;c++)
        acc = __builtin_amdgcn_mfma_f32_16x16x32_f16(ha[c], w2v[(nt*4+c)*64+lane], acc,0,0,0);
      int col=nt*16+m; float bias=b2L[col];
      #pragma unroll
      for(int rg=0;rg<4;rg++)
        y[nt][rg] = acc[rg] + bias + y[nt][rg];
    }
    #pragma unroll
    for(int rg=0;rg<4;rg++){
      float sm=(y[0][rg]+y[1][rg])+(y[2][rg]+y[3][rg]);
      sm+=__shfl_xor(sm,1); sm+=__shfl_xor(sm,2); sm+=__shfl_xor(sm,4); sm+=__shfl_xor(sm,8);
      mu[rg]=sm*(1.f/64.f);
      float d0=y[0][rg]-mu[rg],d1=y[1][rg]-mu[rg],d2=y[2][rg]-mu[rg],d3=y[3][rg]-mu[rg];
      float vv=(d0*d0+d1*d1)+(d2*d2+d3*d3);
      vv+=__shfl_xor(vv,1); vv+=__shfl_xor(vv,2); vv+=__shfl_xor(vv,4); vv+=__shfl_xor(vv,8);
      rs[rg]=rsqrtf(vv*(1.f/64.f)+1e-5f);
    }
    if(l==0){
      #pragma unroll
      for(int nt=0;nt<4;nt++){
        int col=nt*16+m; float g=g2L[col], be=be2L[col];
        #pragma unroll
        for(int rg=0;rg<4;rg++)
          X[(w*16+q*4+rg)*72 + col] = f2h((y[nt][rg]-mu[rg])*rs[rg]*g + be);
      }
      __syncthreads();   // before next layer's QKV scatter overwrites QKV regions
    } else {
      // fused prediction head: rows with t==11 are rg==3 of exactly one
      // q-group per node; condition uniform over the 16-lane m-group.
      int rc = w*16 + q*4 + 3;
      int nn = rc/12;
      if(rc - nn*12 == 11){
        float vfin[4];
        #pragma unroll
        for(int nt=0;nt<4;nt++){
          int col=nt*16+m;
          vfin[nt] = (y[nt][3]-mu[3])*rs[3]*g2L[col] + be2L[col];
        }
        int gm = blockIdx.x*4 + nn;
        unsigned bb=(unsigned)gm/N_, n2=(unsigned)gm-bb*N_;
        #pragma unroll
        for(int h3=0;h3<3;h3++){
          float p = vfin[0]*Wh[h3*64+m]    + vfin[1]*Wh[h3*64+16+m]
                  + vfin[2]*Wh[h3*64+32+m] + vfin[3]*Wh[h3*64+48+m];
          p += __shfl_xor(p,1); p += __shfl_xor(p,2);
          p += __shfl_xor(p,4); p += __shfl_xor(p,8);
          if(m==0) out[(bb*3+h3)*N_+n2] = p + bh[h3];
        }
      }
    }
  }
}

extern "C" void kernel_launch(void* const* d_in, const int* in_sizes, int n_in,
                              void* d_out, int out_size, void* d_ws, size_t ws_size,
                              hipStream_t stream)
{
  const float* x_seq=(const float*)d_in[0];
  const int*   ei   =(const int*)d_in[1];
  const float* W1   =(const float*)d_in[2];
  const float* as1  =(const float*)d_in[3];
  const float* ad1  =(const float*)d_in[4];
  const float* b1   =(const float*)d_in[5];
  const float* W2   =(const float*)d_in[6];
  const float* as2  =(const float*)d_in[7];
  const float* ad2  =(const float*)d_in[8];
  const float* b2   =(const float*)d_in[9];
  const float* Wqkv =(const float*)d_in[10];
  const float* bqkv =(const float*)d_in[11];
  const float* Wo   =(const float*)d_in[12];
  const float* bo   =(const float*)d_in[13];
  const float* Wf1  =(const float*)d_in[14];
  const float* bf1p =(const float*)d_in[15];
  const float* Wf2  =(const float*)d_in[16];
  const float* bf2p =(const float*)d_in[17];
  const float* g1   =(const float*)d_in[18];
  const float* be1  =(const float*)d_in[19];
  const float* g2   =(const float*)d_in[20];
  const float* be2  =(const float*)d_in[21];
  const float* Wh   =(const float*)d_in[22];
  const float* bh   =(const float*)d_in[23];

  // workspace layout (~112 MB)
  u16* seqh   = (u16*)d_ws;                     // [T][M][64] f16  24,576,000 u16
  float* asc  = (float*)(seqh + 24576000);      // [T][M][4]        1,536,000 f
  float* adc  = asc + 1536000;                  //                  1,536,000 f
  int* deg    = (int*)(adc + 1536000);
  int* cursor = deg + M_;
  int* offs   = cursor + M_;                    // M_+1 used
  int* bsums  = offs + (M_ + 2);
  int* boffs  = bsums + 128;
  int* csr    = boffs + 128;                    // ETOT
  u16* h2u    = (u16*)(csr + ETOT);             // [T][M][64]   24,576,000 u16
  u16* wqB    = h2u + (size_t)T_*M_*64;         // 24576
  u16* woB    = wqB + 24576;                    // 8192
  u16* w1B    = woB + 8192;                     // 16384
  u16* w2B    = w1B + 16384;                    // 16384
  float* peT  = (float*)(w2B + 16384);          // 768
  u16* w2gB   = (u16*)(peT + 768);              // 2048

  k_prep   <<<dim3(268), dim3(256), 0, stream>>>(Wqkv, Wo, Wf1, Wf2, W2,
                                                 wqB, woB, w1B, w2B, peT, w2gB);

  // CSR build (edge list identical for all t)
  hipMemsetAsync(deg, 0, (size_t)2*M_*sizeof(int), stream);   // deg + cursor
  k_hist   <<<dim3((ETOT+255)/256), dim3(256), 0, stream>>>(ei, deg);
  k_scan1  <<<dim3(125), dim3(256), 0, stream>>>(deg, offs, bsums);
  k_scan23 <<<dim3(125), dim3(256), 0, stream>>>(offs, bsums);
  k_scatter<<<dim3((ETOT+255)/256), dim3(256), 0, stream>>>(ei, offs, cursor, csr);

  k_gat12<<<dim3(500,T_), dim3(256), 0, stream>>>(x_seq, W1, as1, ad1, b1,
                                                  as2, ad2, offs, csr, w2gB,
                                                  h2u, asc, adc);
  k_gat2b<<<dim3(500,T_), dim3(256), 0, stream>>>(h2u, asc, adc, b2, offs, csr, peT, seqh);

  k_layer2<<<dim3(8000), dim3(192), 0, stream>>>(seqh,
      wqB, woB, w1B, w2B,
      bqkv, bo, bf1p, bf2p,
      g1, be1, g2, be2,
      Wh, bh, (float*)d_out);
}

// Round 8
// 371.372 us; speedup vs baseline: 1.2282x; 1.0083x over previous
//
#include <hip/hip_runtime.h>
#include <hip/hip_bf16.h>

#define B_ 16
#define T_ 12
#define N_ 2000
#define E_ 8000
#define M_ 32000                 // B_*N_
#define ETOT (B_*E_ + M_)        // 160000 edges incl. self loops
#define D_ 64

typedef __hip_bfloat16 bf16;
typedef unsigned short u16;
typedef __attribute__((ext_vector_type(8))) _Float16 half8;
typedef __attribute__((ext_vector_type(2))) _Float16 h2v;
typedef __attribute__((ext_vector_type(4))) float f32x4;

__device__ __forceinline__ float bfu(u16 u){ return __uint_as_float(((unsigned int)u)<<16); }
__device__ __forceinline__ u16 f2bu(float f){
  unsigned int x = __float_as_uint(f);
  x += 0x7FFFu + ((x >> 16) & 1u);
  return (u16)(x >> 16);
}
__device__ __forceinline__ u16 f2h(float f){
  _Float16 h = (_Float16)f; u16 r; __builtin_memcpy(&r, &h, 2); return r;
}
__device__ __forceinline__ float h2f(u16 u){
  _Float16 h; __builtin_memcpy(&h, &u, 2); return (float)h;
}
__device__ __forceinline__ h2v u2h(unsigned u){ h2v r; __builtin_memcpy(&r,&u,4); return r; }

// ---------------- weight prep: f16 MFMA fragments + PE table ----------------
__global__ void k_prep(const float* __restrict__ Wqkv, const float* __restrict__ Wo,
                       const float* __restrict__ Wf1, const float* __restrict__ Wf2,
                       const float* __restrict__ W2g,
                       u16* __restrict__ wqB, u16* __restrict__ woB,
                       u16* __restrict__ w1B, u16* __restrict__ w2B,
                       float* __restrict__ peT, u16* __restrict__ w2gB){
  int i = blockIdx.x*256 + threadIdx.x;    // 268 blocks
  if(i < 24576){
    int l=i/12288, r=i-l*12288;
    int nt=r>>10, r2=r&1023, c=r2>>9, r3=r2&511, lane=r3>>3, jj=r3&7;
    int m=lane&15, q=lane>>4;
    wqB[i] = f2h(Wqkv[l*12288 + (nt*16+m)*64 + c*32 + q*8 + jj]);
  } else if(i < 32768){
    int k2=i-24576;
    int l=k2>>12, r=k2&4095;
    int nt=r>>10, r2=r&1023, c=r2>>9, r3=r2&511, lane=r3>>3, jj=r3&7;
    int m=lane&15, q=lane>>4;
    woB[k2] = f2h(Wo[l*4096 + (nt*16+m)*64 + c*32 + q*8 + jj]);
  } else if(i < 49152){
    int k2=i-32768;
    int l=k2>>13, r=k2&8191;
    int nt=r>>10, r2=r&1023, c=r2>>9, r3=r2&511, lane=r3>>3, jj=r3&7;
    int m=lane&15, q=lane>>4;
    w1B[k2] = f2h(Wf1[l*8192 + (nt*16+m)*64 + c*32 + q*8 + jj]);
  } else if(i < 65536){
    int k2=i-49152;
    int l=k2>>13, r=k2&8191;
    int nt=r>>11, r2=r&2047, c=r2>>9, r3=r2&511, lane=r3>>3, jj=r3&7;
    int m=lane&15, q=lane>>4;
    w2B[k2] = f2h(Wf2[l*8192 + (nt*16+m)*128 + c*32 + q*8 + jj]);
  } else {
    int i2 = i - 65536;
    if(i2 < 768){
      int t=i2>>6, ch=i2&63;
      float ang = (float)t * __expf(-0.14391156463f * (float)(ch & ~1));
      peT[i2] = (ch&1) ? __cosf(ang) : __sinf(ang);
    } else if(i2 < 768+2048){
      // GAT2 W2 [32][64] as dual frags: elem j = W2[q*8+j][nt*16+m]
      int i3 = i2-768;
      int nt=i3>>9, r=i3&511, lane=r>>3, j=r&7;
      int m=lane&15, q=lane>>4;
      w2gB[i3] = f2h(W2g[(q*8+j)*64 + nt*16 + m]);
    }
  }
}

// ---------------- CSR build ----------------
__global__ void k_hist(const int* __restrict__ ei, int* __restrict__ deg){
  int e = blockIdx.x*256 + threadIdx.x; if(e>=ETOT) return;
  int dst;
  if (e < B_*E_){ int b = e / E_; int k = e - b*E_; dst = ei[E_ + k] + b*N_; }
  else dst = e - B_*E_;
  atomicAdd(&deg[dst], 1);
}

__global__ void k_scan1(const int* __restrict__ deg, int* __restrict__ offs, int* __restrict__ bsums){
  __shared__ int s[256];
  int tid = threadIdx.x; int g = blockIdx.x*256 + tid;
  s[tid] = deg[g]; __syncthreads();
  for(int off=1; off<256; off<<=1){
    int a = (tid>=off) ? s[tid-off] : 0; __syncthreads();
    s[tid] += a; __syncthreads();
  }
  offs[g+1] = s[tid];
  if(tid==255) bsums[blockIdx.x] = s[255];
}

// merged scan2+scan3: every block redundantly scans the 125 block sums
// (trivial) and applies its own prefix. One launch instead of two.
__global__ void k_scan23(int* __restrict__ offs, const int* __restrict__ bsums){
  __shared__ int s[128];
  int tid = threadIdx.x; int g = blockIdx.x*256 + tid;
  if(tid<128) s[tid] = (tid<125) ? bsums[tid] : 0;
  __syncthreads();
  for(int off=1; off<128; off<<=1){
    int a = 0;
    if(tid<128 && tid>=off) a = s[tid-off];
    __syncthreads();
    if(tid<128) s[tid] += a;
    __syncthreads();
  }
  int boff = (blockIdx.x==0) ? 0 : s[blockIdx.x-1];
  offs[g+1] += boff;
  if(g==0) offs[0]=0;
}

// csr stores LOCAL src index (all edges intra-graph) -> gat kernels skip /N_
__global__ void k_scatter(const int* __restrict__ ei, const int* __restrict__ offs,
                          int* __restrict__ cursor, int* __restrict__ csr){
  int e = blockIdx.x*256 + threadIdx.x; if(e>=ETOT) return;
  int srcl, dst;
  if (e < B_*E_){ int b=e/E_; int k=e-b*E_; srcl=ei[k]; dst=ei[E_+k]+b*N_; }
  else { dst = e - B_*E_; int b=dst/N_; srcl = dst - b*N_; }
  int pos = atomicAdd(&cursor[dst], 1);
  csr[offs[dst]+pos] = srcl;
}

// ---------------- fused GAT1 + GAT2 feature/score (MFMA) ----------------
// Lane q*16+m: node m (of wave's 16), head q. Edge loop split 4-ways across
// q-lanes (round-7 measured form). Round-8: operand-SWAPPED MFMAs
// (D = W2^T @ out1^T): lane holds ITS OWN node m's channels nt*16+q*4..+3
// -> h2u written as 4 uint2 (was 16 scalar u16); asc/adc via per-head
// butterfly (16 shfl, was 2x redsel16 = 30). No LDS in this kernel, so the
// k_layer2 swap-regression mechanism (LDS bank conflicts) cannot apply.
__global__ __launch_bounds__(256) void k_gat12(
  const float* __restrict__ x_seq, const float* __restrict__ W1,
  const float* __restrict__ as1, const float* __restrict__ ad1, const float* __restrict__ b1,
  const float* __restrict__ as2, const float* __restrict__ ad2,
  const int* __restrict__ offs, const int* __restrict__ csr,
  const u16* __restrict__ w2gB,
  u16* __restrict__ h2u, float* __restrict__ asc, float* __restrict__ adc)
{
  int tid = threadIdx.x, w = tid>>6, lane = tid&63;
  int m = lane&15, q = lane>>4;
  int t = blockIdx.y;
  int node = blockIdx.x*64 + w*16 + m;
  unsigned un=(unsigned)node, b=un/N_, n=un-b*N_;

  // W2 fragments (16 VGPR, loaded once; L2-hot)
  const half8* wb = (const half8*)w2gB;
  half8 w2f0 = wb[0*64+lane], w2f1 = wb[1*64+lane],
        w2f2 = wb[2*64+lane], w2f3 = wb[3*64+lane];

  // all-head GAT1 score weights
  float sS[4], sD[4];
  #pragma unroll
  for(int h=0;h<4;h++){
    float a=0.f, d=0.f;
    #pragma unroll
    for(int c=0;c<8;c++){ float wv=W1[h*8+c]; a+=wv*as1[h*8+c]; d+=wv*ad1[h*8+c]; }
    sS[h]=a; sD[h]=d;
  }

  const float* xsl = x_seq + (size_t)(b*T_+t)*N_;
  float xm = xsl[n];
  int e0=offs[node], e1=offs[node+1];
  float sum[4]={0.f,0.f,0.f,0.f}, ax[4]={0.f,0.f,0.f,0.f};
  for(int e=e0+q; e<e1; e+=4){
    float xv = xsl[csr[e]];
    #pragma unroll
    for(int h=0;h<4;h++){
      float ee = xv*sS[h] + xm*sD[h]; ee = ee>0.f ? ee : 0.2f*ee;
      float wv = __expf(ee); sum[h]+=wv; ax[h]+=wv*xv;
    }
  }
  // q-dimension lives in lane bits 4-5: butterfly over xor 16, 32
  #pragma unroll
  for(int h=0;h<4;h++){
    sum[h] += __shfl_xor(sum[h],16); sum[h] += __shfl_xor(sum[h],32);
    ax[h]  += __shfl_xor(ax[h],16);  ax[h]  += __shfl_xor(ax[h],32);
  }
  float A = ax[q]/(sum[q]+1e-16f);

  // fragment: out1[m][q*8+j] (A-layout == B-layout dual)
  half8 af;
  #pragma unroll
  for(int j=0;j<8;j++){
    float v = A*W1[q*8+j] + b1[q*8+j]; v = v>0.f?v:0.f;
    af[j] = (_Float16)v;
  }
  // swapped: D[ch][node]; ac_nt[rg] = h2[node m][nt*16 + q*4 + rg]
  f32x4 ac0={0.f,0.f,0.f,0.f}, ac1=ac0, ac2=ac0, ac3=ac0;
  ac0 = __builtin_amdgcn_mfma_f32_16x16x32_f16(w2f0, af, ac0,0,0,0);
  ac1 = __builtin_amdgcn_mfma_f32_16x16x32_f16(w2f1, af, ac1,0,0,0);
  ac2 = __builtin_amdgcn_mfma_f32_16x16x32_f16(w2f2, af, ac2,0,0,0);
  ac3 = __builtin_amdgcn_mfma_f32_16x16x32_f16(w2f3, af, ac3,0,0,0);

  size_t nd = (size_t)t*M_ + node;
  u16* row = h2u + nd*64;
  {
    uint2 p;
    p.x = (unsigned)f2bu(ac0[0]) | ((unsigned)f2bu(ac0[1])<<16);
    p.y = (unsigned)f2bu(ac0[2]) | ((unsigned)f2bu(ac0[3])<<16);
    *(uint2*)(row + 0*16 + q*4) = p;
    p.x = (unsigned)f2bu(ac1[0]) | ((unsigned)f2bu(ac1[1])<<16);
    p.y = (unsigned)f2bu(ac1[2]) | ((unsigned)f2bu(ac1[3])<<16);
    *(uint2*)(row + 1*16 + q*4) = p;
    p.x = (unsigned)f2bu(ac2[0]) | ((unsigned)f2bu(ac2[1])<<16);
    p.y = (unsigned)f2bu(ac2[2]) | ((unsigned)f2bu(ac2[3])<<16);
    *(uint2*)(row + 2*16 + q*4) = p;
    p.x = (unsigned)f2bu(ac3[0]) | ((unsigned)f2bu(ac3[1])<<16);
    p.y = (unsigned)f2bu(ac3[2]) | ((unsigned)f2bu(ac3[3])<<16);
    *(uint2*)(row + 3*16 + q*4) = p;
  }

  // asc/adc: per-head partial over this lane's 4 channels, butterfly over q
  const float* a2sp = as2 + q*4;
  const float* a2dp = ad2 + q*4;
  float ps[4], pd[4];
  ps[0]=ac0[0]*a2sp[ 0]+ac0[1]*a2sp[ 1]+ac0[2]*a2sp[ 2]+ac0[3]*a2sp[ 3];
  ps[1]=ac1[0]*a2sp[16]+ac1[1]*a2sp[17]+ac1[2]*a2sp[18]+ac1[3]*a2sp[19];
  ps[2]=ac2[0]*a2sp[32]+ac2[1]*a2sp[33]+ac2[2]*a2sp[34]+ac2[3]*a2sp[35];
  ps[3]=ac3[0]*a2sp[48]+ac3[1]*a2sp[49]+ac3[2]*a2sp[50]+ac3[3]*a2sp[51];
  pd[0]=ac0[0]*a2dp[ 0]+ac0[1]*a2dp[ 1]+ac0[2]*a2dp[ 2]+ac0[3]*a2dp[ 3];
  pd[1]=ac1[0]*a2dp[16]+ac1[1]*a2dp[17]+ac1[2]*a2dp[18]+ac1[3]*a2dp[19];
  pd[2]=ac2[0]*a2dp[32]+ac2[1]*a2dp[33]+ac2[2]*a2dp[34]+ac2[3]*a2dp[35];
  pd[3]=ac3[0]*a2dp[48]+ac3[1]*a2dp[49]+ac3[2]*a2dp[50]+ac3[3]*a2dp[51];
  #pragma unroll
  for(int h=0;h<4;h++){
    ps[h] += __shfl_xor(ps[h],16); ps[h] += __shfl_xor(ps[h],32);
    pd[h] += __shfl_xor(pd[h],16); pd[h] += __shfl_xor(pd[h],32);
  }
  // lane q stores head q (static selects, no runtime indexing)
  float ra = (q&1) ? ((q&2)? ps[3]:ps[1]) : ((q&2)? ps[2]:ps[0]);
  float rd = (q&1) ? ((q&2)? pd[3]:pd[1]) : ((q&2)? pd[2]:pd[0]);
  asc[nd*4+q] = ra;
  adc[nd*4+q] = rd;
}

// ---------------- GAT2 softmax-aggregate + bias + relu + PE(table); f16 out ------
// Round-8: edge loop split across lane pairs (j=0/1 take alternating edges;
// serial chain 5 -> 2.5 iters -- gat2b diagnosed latency-bound from the
// round-6 null on request-widening + round-7 win on chain-shortening).
// id = m*8 + j*4 + h keeps the 4 h-lanes adjacent: each row gather is still
// one coalesced 128B. Butterfly shfl_xor(4) merges; each lane stores its
// 8-channel half as one uint4.
__global__ __launch_bounds__(256) void k_gat2b(
  const u16* __restrict__ h2u, const float* __restrict__ asc, const float* __restrict__ adc,
  const float* __restrict__ b2, const int* __restrict__ offs, const int* __restrict__ csr,
  const float* __restrict__ peT, u16* __restrict__ seq)
{
  int t = blockIdx.y;
  int id = blockIdx.x*256 + threadIdx.x;   // 1000*256 = M_*8
  int m = id>>3, j = (id>>2)&1, h = id&3;
  unsigned um=(unsigned)m, b=um/N_;
  size_t base_s = (size_t)t*M_ + (size_t)b*N_;   // csr holds local indices
  float am = adc[((size_t)t*M_+m)*4+h];
  int e0=offs[m], e1=offs[m+1];
  float sum=0.f;
  float A[16];
  #pragma unroll
  for(int c=0;c<16;c++) A[c]=0.f;
  for(int e=e0+j; e<e1; e+=2){
    size_t s = base_s + (unsigned)csr[e];
    float ee = asc[s*4+h] + am; ee = ee>0.f ? ee : 0.2f*ee;
    float w = __expf(ee); sum += w;
    const uint4* hp = (const uint4*)(h2u + s*64 + h*16);
    uint4 p0 = hp[0], p1 = hp[1];
    A[ 0] += w*bfu((u16)(p0.x)); A[ 1] += w*bfu((u16)(p0.x>>16));
    A[ 2] += w*bfu((u16)(p0.y)); A[ 3] += w*bfu((u16)(p0.y>>16));
    A[ 4] += w*bfu((u16)(p0.z)); A[ 5] += w*bfu((u16)(p0.z>>16));
    A[ 6] += w*bfu((u16)(p0.w)); A[ 7] += w*bfu((u16)(p0.w>>16));
    A[ 8] += w*bfu((u16)(p1.x)); A[ 9] += w*bfu((u16)(p1.x>>16));
    A[10] += w*bfu((u16)(p1.y)); A[11] += w*bfu((u16)(p1.y>>16));
    A[12] += w*bfu((u16)(p1.z)); A[13] += w*bfu((u16)(p1.z>>16));
    A[14] += w*bfu((u16)(p1.w)); A[15] += w*bfu((u16)(p1.w>>16));
  }
  // merge the two edge-halves (partner lane: id xor 4)
  sum += __shfl_xor(sum,4);
  #pragma unroll
  for(int c=0;c<16;c++) A[c] += __shfl_xor(A[c],4);

  float inv = 1.f/(sum + 1e-16f);
  u16 ov[8];
  #pragma unroll
  for(int c=0;c<8;c++){
    int ch = h*16 + j*8 + c;
    float v = A[j*8+c]*inv + b2[ch]; v = v>0.f ? v : 0.f;
    ov[c] = f2h(v + peT[t*64+ch]);
  }
  uint4 o;
  o.x = (unsigned)ov[0] | ((unsigned)ov[1]<<16);
  o.y = (unsigned)ov[2] | ((unsigned)ov[3]<<16);
  o.z = (unsigned)ov[4] | ((unsigned)ov[5]<<16);
  o.w = (unsigned)ov[6] | ((unsigned)ov[7]<<16);
  *(uint4*)(seq + ((size_t)t*M_ + m)*64 + h*16 + j*8) = o;
}

// ---------------- BOTH transformer layers + fused head (R16-measured form) -------
// X u16 [48][72]: layer input (wave-private rows). QKV u16 [3][48][72]; K,V
// overlaid by H[48][136]. A = activations (standard orientation; the operand
// swap was tried TWICE and both times tripled LDS bank conflicts -- do not
// retry). Register-carried residual (xres) was tried once: VGPR 68->84,
// VALUBusy -15pts, +48us -- do not retry. UNCHANGED since round 4.
__global__ __launch_bounds__(192) void k_layer2(
  const u16* __restrict__ seq,
  const u16* __restrict__ wqB, const u16* __restrict__ woB,
  const u16* __restrict__ w1B, const u16* __restrict__ w2B,
  const float* __restrict__ bqkv, const float* __restrict__ bo,
  const float* __restrict__ bf1,  const float* __restrict__ bf2,
  const float* __restrict__ g1,   const float* __restrict__ be1,
  const float* __restrict__ g2,   const float* __restrict__ be2,
  const float* __restrict__ Wh,   const float* __restrict__ bh,
  float* __restrict__ out)
{
  __shared__ __align__(16) u16 X[3456];      // [48][72] f16
  __shared__ __align__(16) u16 QKV[10368];   // [3][48][72]
  u16* Hd = QKV + 3456;                      // H[48][136] overlays K,V
  int tid=threadIdx.x, w=tid>>6, lane=tid&63;
  int m=lane&15, q=lane>>4;
  int r = w*16 + m;

  // stage X: wave w loads its own 16 rows (wave-private, no barrier needed).
  // Each row = 128B = 8 lanes x 16B; 2 dwordx4 loads/lane replace 16 scalar.
  #pragma unroll
  for(int half=0; half<2; half++){
    int rr = half*8 + (lane>>3);
    int row = w*16 + rr;
    int nn = row/12, tt = row-nn*12;
    const uint4* src = (const uint4*)(seq + ((size_t)tt*M_ + (size_t)blockIdx.x*4+nn)*64) + (lane&7);
    *((uint4*)&X[row*72] + (lane&7)) = *src;
  }

  #pragma unroll 1
  for(int l=0; l<2; l++){
    const half8* wqv = (const half8*)(wqB + (size_t)l*12288);
    const half8* wov = (const half8*)(woB + (size_t)l*4096);
    const half8* w1v = (const half8*)(w1B + (size_t)l*8192);
    const half8* w2v = (const half8*)(w2B + (size_t)l*8192);
    const float* bq = bqkv + l*192;
    const float* boL = bo + l*64;
    const float* b1L = bf1 + l*128;
    const float* b2L = bf2 + l*64;
    const float* g1L = g1 + l*64, *be1L = be1 + l*64;
    const float* g2L = g2 + l*64, *be2L = be2 + l*64;

    // ---- QKV projection: A-frags from X (wave-own rows) ----
    half8 xa0 = *(const half8*)&X[r*72 + q*8];
    half8 xa1 = *(const half8*)&X[r*72 + 32 + q*8];
    #pragma unroll
    for(int nt=0; nt<12; nt++){
      f32x4 acc={0.f,0.f,0.f,0.f};
      acc = __builtin_amdgcn_mfma_f32_16x16x32_f16(xa0, wqv[(nt*2+0)*64+lane], acc,0,0,0);
      acc = __builtin_amdgcn_mfma_f32_16x16x32_f16(xa1, wqv[(nt*2+1)*64+lane], acc,0,0,0);
      int cg = nt*16+m; float bias = bq[cg];
      int s = nt>>2, lc = cg&63;
      #pragma unroll
      for(int rg=0;rg<4;rg++){
        int row = w*16 + q*4 + rg;
        QKV[s*3456 + row*72 + lc] = f2h(acc[rg]+bias);
      }
    }
    __syncthreads();

    // ---- attention: 192 lanes = (node an, head ah, time at); fdot2 + pk_fma ----
    {
      int an = tid/48, rem = tid - an*48;
      int ah = rem/12, at = rem - ah*12;
      u16* qrow = &QKV[(an*12+at)*72 + ah*16];
      uint4 qa = ((const uint4*)qrow)[0], qb = ((const uint4*)qrow)[1];
      float s[12];
      #pragma unroll
      for(int t2=0;t2<12;t2++){
        const uint4* kp = (const uint4*)&QKV[3456 + (an*12+t2)*72 + ah*16];
        uint4 ka=kp[0], kb=kp[1];
        float d=0.f;
        d=__builtin_amdgcn_fdot2(u2h(qa.x),u2h(ka.x),d,false);
        d=__builtin_amdgcn_fdot2(u2h(qa.y),u2h(ka.y),d,false);
        d=__builtin_amdgcn_fdot2(u2h(qa.z),u2h(ka.z),d,false);
        d=__builtin_amdgcn_fdot2(u2h(qa.w),u2h(ka.w),d,false);
        d=__builtin_amdgcn_fdot2(u2h(qb.x),u2h(kb.x),d,false);
        d=__builtin_amdgcn_fdot2(u2h(qb.y),u2h(kb.y),d,false);
        d=__builtin_amdgcn_fdot2(u2h(qb.z),u2h(kb.z),d,false);
        d=__builtin_amdgcn_fdot2(u2h(qb.w),u2h(kb.w),d,false);
        s[t2] = d*0.25f;
      }
      float mx=s[0];
      #pragma unroll
      for(int t2=1;t2<12;t2++) mx=fmaxf(mx,s[t2]);
      float sum=0.f;
      #pragma unroll
      for(int t2=0;t2<12;t2++){ s[t2]=__expf(s[t2]-mx); sum+=s[t2]; }
      float inv=1.f/sum;
      half8 o0, o1;
      #pragma unroll
      for(int i=0;i<8;i++){ o0[i]=(_Float16)0.f; o1[i]=(_Float16)0.f; }
      #pragma unroll
      for(int t2=0;t2<12;t2++){
        const half8* vr = (const half8*)&QKV[6912 + (an*12+t2)*72 + ah*16];
        _Float16 wh = (_Float16)s[t2];
        o0 += vr[0]*wh; o1 += vr[1]*wh;
      }
      _Float16 ih = (_Float16)inv;
      ((half8*)qrow)[0]=o0*ih; ((half8*)qrow)[1]=o1*ih;
    }
    __syncthreads();

    // ---- Wo + residual(X) + LN1 ----
    half8 oa0 = *(const half8*)&QKV[r*72 + q*8];
    half8 oa1 = *(const half8*)&QKV[r*72 + 32 + q*8];
    float y[4][4];
    #pragma unroll
    for(int nt=0;nt<4;nt++){
      f32x4 acc={0.f,0.f,0.f,0.f};
      acc = __builtin_amdgcn_mfma_f32_16x16x32_f16(oa0, wov[(nt*2+0)*64+lane], acc,0,0,0);
      acc = __builtin_amdgcn_mfma_f32_16x16x32_f16(oa1, wov[(nt*2+1)*64+lane], acc,0,0,0);
      int col=nt*16+m; float bias=boL[col];
      #pragma unroll
      for(int rg=0;rg<4;rg++)
        y[nt][rg] = acc[rg] + bias + h2f(X[(w*16+q*4+rg)*72 + col]);
    }
    float mu[4], rs[4];
    #pragma unroll
    for(int rg=0;rg<4;rg++){
      float sm=(y[0][rg]+y[1][rg])+(y[2][rg]+y[3][rg]);
      sm+=__shfl_xor(sm,1); sm+=__shfl_xor(sm,2); sm+=__shfl_xor(sm,4); sm+=__shfl_xor(sm,8);
      mu[rg]=sm*(1.f/64.f);
      float d0=y[0][rg]-mu[rg],d1=y[1][rg]-mu[rg],d2=y[2][rg]-mu[rg],d3=y[3][rg]-mu[rg];
      float vv=(d0*d0+d1*d1)+(d2*d2+d3*d3);
      vv+=__shfl_xor(vv,1); vv+=__shfl_xor(vv,2); vv+=__shfl_xor(vv,4); vv+=__shfl_xor(vv,8);
      rs[rg]=rsqrtf(vv*(1.f/64.f)+1e-5f);
    }
    #pragma unroll
    for(int nt=0;nt<4;nt++){
      int col=nt*16+m; float g=g1L[col], be=be1L[col];
      #pragma unroll
      for(int rg=0;rg<4;rg++){
        float v=(y[nt][rg]-mu[rg])*rs[rg]*g+be;
        y[nt][rg]=v;                                  // FF residual (f32)
        QKV[(w*16+q*4+rg)*72 + col]=f2h(v);           // y -> wave-own rows
      }
    }

    // ---- FF1: y A-frags; H -> pitch-136 overlay ----
    half8 ya0 = *(const half8*)&QKV[r*72 + q*8];
    half8 ya1 = *(const half8*)&QKV[r*72 + 32 + q*8];
    #pragma unroll
    for(int nt=0;nt<8;nt++){
      f32x4 acc={0.f,0.f,0.f,0.f};
      acc = __builtin_amdgcn_mfma_f32_16x16x32_f16(ya0, w1v[(nt*2+0)*64+lane], acc,0,0,0);
      acc = __builtin_amdgcn_mfma_f32_16x16x32_f16(ya1, w1v[(nt*2+1)*64+lane], acc,0,0,0);
      float bias=b1L[nt*16+m];
      #pragma unroll
      for(int rg=0;rg<4;rg++)
        Hd[(w*16+q*4+rg)*136 + nt*16+m] = f2h(fmaxf(acc[rg]+bias, 0.f));
    }

    // ---- FF2 + residual y + LN2 ----
    half8 ha[4];
    #pragma unroll
    for(int c=0;c<4;c++)
      ha[c] = *(const half8*)&Hd[r*136 + c*32 + q*8];
    #pragma unroll
    for(int nt=0;nt<4;nt++){
      f32x4 acc={0.f,0.f,0.f,0.f};
      #pragma unroll
      for(int c=0;c<4;c++)
        acc = __builtin_amdgcn_mfma_f32_16x16x32_f16(ha[c], w2v[(nt*4+c)*64+lane], acc,0,0,0);
      int col=nt*16+m; float bias=b2L[col];
      #pragma unroll
      for(int rg=0;rg<4;rg++)
        y[nt][rg] = acc[rg] + bias + y[nt][rg];
    }
    #pragma unroll
    for(int rg=0;rg<4;rg++){
      float sm=(y[0][rg]+y[1][rg])+(y[2][rg]+y[3][rg]);
      sm+=__shfl_xor(sm,1); sm+=__shfl_xor(sm,2); sm+=__shfl_xor(sm,4); sm+=__shfl_xor(sm,8);
      mu[rg]=sm*(1.f/64.f);
      float d0=y[0][rg]-mu[rg],d1=y[1][rg]-mu[rg],d2=y[2][rg]-mu[rg],d3=y[3][rg]-mu[rg];
      float vv=(d0*d0+d1*d1)+(d2*d2+d3*d3);
      vv+=__shfl_xor(vv,1); vv+=__shfl_xor(vv,2); vv+=__shfl_xor(vv,4); vv+=__shfl_xor(vv,8);
      rs[rg]=rsqrtf(vv*(1.f/64.f)+1e-5f);
    }
    if(l==0){
      #pragma unroll
      for(int nt=0;nt<4;nt++){
        int col=nt*16+m; float g=g2L[col], be=be2L[col];
        #pragma unroll
        for(int rg=0;rg<4;rg++)
          X[(w*16+q*4+rg)*72 + col] = f2h((y[nt][rg]-mu[rg])*rs[rg]*g + be);
      }
      __syncthreads();   // before next layer's QKV scatter overwrites QKV regions
    } else {
      // fused prediction head: rows with t==11 are rg==3 of exactly one
      // q-group per node; condition uniform over the 16-lane m-group.
      int rc = w*16 + q*4 + 3;
      int nn = rc/12;
      if(rc - nn*12 == 11){
        float vfin[4];
        #pragma unroll
        for(int nt=0;nt<4;nt++){
          int col=nt*16+m;
          vfin[nt] = (y[nt][3]-mu[3])*rs[3]*g2L[col] + be2L[col];
        }
        int gm = blockIdx.x*4 + nn;
        unsigned bb=(unsigned)gm/N_, n2=(unsigned)gm-bb*N_;
        #pragma unroll
        for(int h3=0;h3<3;h3++){
          float p = vfin[0]*Wh[h3*64+m]    + vfin[1]*Wh[h3*64+16+m]
                  + vfin[2]*Wh[h3*64+32+m] + vfin[3]*Wh[h3*64+48+m];
          p += __shfl_xor(p,1); p += __shfl_xor(p,2);
          p += __shfl_xor(p,4); p += __shfl_xor(p,8);
          if(m==0) out[(bb*3+h3)*N_+n2] = p + bh[h3];
        }
      }
    }
  }
}

extern "C" void kernel_launch(void* const* d_in, const int* in_sizes, int n_in,
                              void* d_out, int out_size, void* d_ws, size_t ws_size,
                              hipStream_t stream)
{
  const float* x_seq=(const float*)d_in[0];
  const int*   ei   =(const int*)d_in[1];
  const float* W1   =(const float*)d_in[2];
  const float* as1  =(const float*)d_in[3];
  const float* ad1  =(const float*)d_in[4];
  const float* b1   =(const float*)d_in[5];
  const float* W2   =(const float*)d_in[6];
  const float* as2  =(const float*)d_in[7];
  const float* ad2  =(const float*)d_in[8];
  const float* b2   =(const float*)d_in[9];
  const float* Wqkv =(const float*)d_in[10];
  const float* bqkv =(const float*)d_in[11];
  const float* Wo   =(const float*)d_in[12];
  const float* bo   =(const float*)d_in[13];
  const float* Wf1  =(const float*)d_in[14];
  const float* bf1p =(const float*)d_in[15];
  const float* Wf2  =(const float*)d_in[16];
  const float* bf2p =(const float*)d_in[17];
  const float* g1   =(const float*)d_in[18];
  const float* be1  =(const float*)d_in[19];
  const float* g2   =(const float*)d_in[20];
  const float* be2  =(const float*)d_in[21];
  const float* Wh   =(const float*)d_in[22];
  const float* bh   =(const float*)d_in[23];

  // workspace layout (~112 MB)
  u16* seqh   = (u16*)d_ws;                     // [T][M][64] f16  24,576,000 u16
  float* asc  = (float*)(seqh + 24576000);      // [T][M][4]        1,536,000 f
  float* adc  = asc + 1536000;                  //                  1,536,000 f
  int* deg    = (int*)(adc + 1536000);
  int* cursor = deg + M_;
  int* offs   = cursor + M_;                    // M_+1 used
  int* bsums  = offs + (M_ + 2);
  int* boffs  = bsums + 128;
  int* csr    = boffs + 128;                    // ETOT
  u16* h2u    = (u16*)(csr + ETOT);             // [T][M][64]   24,576,000 u16
  u16* wqB    = h2u + (size_t)T_*M_*64;         // 24576
  u16* woB    = wqB + 24576;                    // 8192
  u16* w1B    = woB + 8192;                     // 16384
  u16* w2B    = w1B + 16384;                    // 16384
  float* peT  = (float*)(w2B + 16384);          // 768
  u16* w2gB   = (u16*)(peT + 768);              // 2048

  k_prep   <<<dim3(268), dim3(256), 0, stream>>>(Wqkv, Wo, Wf1, Wf2, W2,
                                                 wqB, woB, w1B, w2B, peT, w2gB);

  // CSR build (edge list identical for all t)
  hipMemsetAsync(deg, 0, (size_t)2*M_*sizeof(int), stream);   // deg + cursor
  k_hist   <<<dim3((ETOT+255)/256), dim3(256), 0, stream>>>(ei, deg);
  k_scan1  <<<dim3(125), dim3(256), 0, stream>>>(deg, offs, bsums);
  k_scan23 <<<dim3(125), dim3(256), 0, stream>>>(offs, bsums);
  k_scatter<<<dim3((ETOT+255)/256), dim3(256), 0, stream>>>(ei, offs, cursor, csr);

  k_gat12<<<dim3(500,T_), dim3(256), 0, stream>>>(x_seq, W1, as1, ad1, b1,
                                                  as2, ad2, offs, csr, w2gB,
                                                  h2u, asc, adc);
  k_gat2b<<<dim3(1000,T_), dim3(256), 0, stream>>>(h2u, asc, adc, b2, offs, csr, peT, seqh);

  k_layer2<<<dim3(8000), dim3(192), 0, stream>>>(seqh,
      wqB, woB, w1B, w2B,
      bqkv, bo, bf1p, bf2p,
      g1, be1, g2, be2,
      Wh, bh, (float*)d_out);
}

// Round 9
// 355.453 us; speedup vs baseline: 1.2832x; 1.0448x over previous
//
#include <hip/hip_runtime.h>
#include <hip/hip_bf16.h>

#define B_ 16
#define T_ 12
#define N_ 2000
#define E_ 8000
#define M_ 32000                 // B_*N_
#define ETOT (B_*E_ + M_)        // 160000 edges incl. self loops
#define D_ 64

typedef __hip_bfloat16 bf16;
typedef unsigned short u16;
typedef __attribute__((ext_vector_type(8))) _Float16 half8;
typedef __attribute__((ext_vector_type(2))) _Float16 h2v;
typedef __attribute__((ext_vector_type(4))) float f32x4;

__device__ __forceinline__ float bfu(u16 u){ return __uint_as_float(((unsigned int)u)<<16); }
__device__ __forceinline__ u16 f2bu(float f){
  unsigned int x = __float_as_uint(f);
  x += 0x7FFFu + ((x >> 16) & 1u);
  return (u16)(x >> 16);
}
__device__ __forceinline__ u16 f2h(float f){
  _Float16 h = (_Float16)f; u16 r; __builtin_memcpy(&r, &h, 2); return r;
}
__device__ __forceinline__ float h2f(u16 u){
  _Float16 h; __builtin_memcpy(&h, &u, 2); return (float)h;
}
__device__ __forceinline__ h2v u2h(unsigned u){ h2v r; __builtin_memcpy(&r,&u,4); return r; }

// bijective XCD-aware block swizzle (m204 form): blocks with x%8==k map to a
// CONTIGUOUS chunk of work -> each XCD's L2 sees ~1/8 of the gather working
// set instead of all of it. Pure remap; per-thread arithmetic unchanged.
__device__ __forceinline__ int xcd_swz(int x, int n){
  int q = n>>3, r = n&7;
  int xcd = x&7, idx = x>>3;
  int base = (xcd<r) ? xcd*(q+1) : r*(q+1) + (xcd-r)*q;
  return base + idx;
}

// ---------------- weight prep: f16 MFMA fragments + PE table ----------------
__global__ void k_prep(const float* __restrict__ Wqkv, const float* __restrict__ Wo,
                       const float* __restrict__ Wf1, const float* __restrict__ Wf2,
                       const float* __restrict__ W2g,
                       u16* __restrict__ wqB, u16* __restrict__ woB,
                       u16* __restrict__ w1B, u16* __restrict__ w2B,
                       float* __restrict__ peT, u16* __restrict__ w2gB){
  int i = blockIdx.x*256 + threadIdx.x;    // 268 blocks
  if(i < 24576){
    int l=i/12288, r=i-l*12288;
    int nt=r>>10, r2=r&1023, c=r2>>9, r3=r2&511, lane=r3>>3, jj=r3&7;
    int m=lane&15, q=lane>>4;
    wqB[i] = f2h(Wqkv[l*12288 + (nt*16+m)*64 + c*32 + q*8 + jj]);
  } else if(i < 32768){
    int k2=i-24576;
    int l=k2>>12, r=k2&4095;
    int nt=r>>10, r2=r&1023, c=r2>>9, r3=r2&511, lane=r3>>3, jj=r3&7;
    int m=lane&15, q=lane>>4;
    woB[k2] = f2h(Wo[l*4096 + (nt*16+m)*64 + c*32 + q*8 + jj]);
  } else if(i < 49152){
    int k2=i-32768;
    int l=k2>>13, r=k2&8191;
    int nt=r>>10, r2=r&1023, c=r2>>9, r3=r2&511, lane=r3>>3, jj=r3&7;
    int m=lane&15, q=lane>>4;
    w1B[k2] = f2h(Wf1[l*8192 + (nt*16+m)*64 + c*32 + q*8 + jj]);
  } else if(i < 65536){
    int k2=i-49152;
    int l=k2>>13, r=k2&8191;
    int nt=r>>11, r2=r&2047, c=r2>>9, r3=r2&511, lane=r3>>3, jj=r3&7;
    int m=lane&15, q=lane>>4;
    w2B[k2] = f2h(Wf2[l*8192 + (nt*16+m)*128 + c*32 + q*8 + jj]);
  } else {
    int i2 = i - 65536;
    if(i2 < 768){
      int t=i2>>6, ch=i2&63;
      float ang = (float)t * __expf(-0.14391156463f * (float)(ch & ~1));
      peT[i2] = (ch&1) ? __cosf(ang) : __sinf(ang);
    } else if(i2 < 768+2048){
      // GAT2 W2 [32][64] as dual frags: elem j = W2[q*8+j][nt*16+m]
      int i3 = i2-768;
      int nt=i3>>9, r=i3&511, lane=r>>3, j=r&7;
      int m=lane&15, q=lane>>4;
      w2gB[i3] = f2h(W2g[(q*8+j)*64 + nt*16 + m]);
    }
  }
}

// ---------------- CSR build ----------------
__global__ void k_hist(const int* __restrict__ ei, int* __restrict__ deg){
  int e = blockIdx.x*256 + threadIdx.x; if(e>=ETOT) return;
  int dst;
  if (e < B_*E_){ int b = e / E_; int k = e - b*E_; dst = ei[E_ + k] + b*N_; }
  else dst = e - B_*E_;
  atomicAdd(&deg[dst], 1);
}

__global__ void k_scan1(const int* __restrict__ deg, int* __restrict__ offs, int* __restrict__ bsums){
  __shared__ int s[256];
  int tid = threadIdx.x; int g = blockIdx.x*256 + tid;
  s[tid] = deg[g]; __syncthreads();
  for(int off=1; off<256; off<<=1){
    int a = (tid>=off) ? s[tid-off] : 0; __syncthreads();
    s[tid] += a; __syncthreads();
  }
  offs[g+1] = s[tid];
  if(tid==255) bsums[blockIdx.x] = s[255];
}

// merged scan2+scan3: every block redundantly scans the 125 block sums
// (trivial) and applies its own prefix. One launch instead of two.
__global__ void k_scan23(int* __restrict__ offs, const int* __restrict__ bsums){
  __shared__ int s[128];
  int tid = threadIdx.x; int g = blockIdx.x*256 + tid;
  if(tid<128) s[tid] = (tid<125) ? bsums[tid] : 0;
  __syncthreads();
  for(int off=1; off<128; off<<=1){
    int a = 0;
    if(tid<128 && tid>=off) a = s[tid-off];
    __syncthreads();
    if(tid<128) s[tid] += a;
    __syncthreads();
  }
  int boff = (blockIdx.x==0) ? 0 : s[blockIdx.x-1];
  offs[g+1] += boff;
  if(g==0) offs[0]=0;
}

// csr stores LOCAL src index (all edges intra-graph) -> gat kernels skip /N_
__global__ void k_scatter(const int* __restrict__ ei, const int* __restrict__ offs,
                          int* __restrict__ cursor, int* __restrict__ csr){
  int e = blockIdx.x*256 + threadIdx.x; if(e>=ETOT) return;
  int srcl, dst;
  if (e < B_*E_){ int b=e/E_; int k=e-b*E_; srcl=ei[k]; dst=ei[E_+k]+b*N_; }
  else { dst = e - B_*E_; int b=dst/N_; srcl = dst - b*N_; }
  int pos = atomicAdd(&cursor[dst], 1);
  csr[offs[dst]+pos] = srcl;
}

// ---------------- fused GAT1 + GAT2 feature/score (MFMA) ----------------
// Lane q*16+m: node m (of wave's 16), head q. Edge loop split 4-ways across
// q-lanes (round-7). Operand-swapped MFMAs + packed stores (round-8).
// Round-9: XCD-swizzled block mapping (contiguous node chunk per XCD).
__global__ __launch_bounds__(256) void k_gat12(
  const float* __restrict__ x_seq, const float* __restrict__ W1,
  const float* __restrict__ as1, const float* __restrict__ ad1, const float* __restrict__ b1,
  const float* __restrict__ as2, const float* __restrict__ ad2,
  const int* __restrict__ offs, const int* __restrict__ csr,
  const u16* __restrict__ w2gB,
  u16* __restrict__ h2u, float* __restrict__ asc, float* __restrict__ adc)
{
  int tid = threadIdx.x, w = tid>>6, lane = tid&63;
  int m = lane&15, q = lane>>4;
  int t = blockIdx.y;
  int bx = xcd_swz(blockIdx.x, 500);
  int node = bx*64 + w*16 + m;
  unsigned un=(unsigned)node, b=un/N_, n=un-b*N_;

  // W2 fragments (16 VGPR, loaded once; L2-hot)
  const half8* wb = (const half8*)w2gB;
  half8 w2f0 = wb[0*64+lane], w2f1 = wb[1*64+lane],
        w2f2 = wb[2*64+lane], w2f3 = wb[3*64+lane];

  // all-head GAT1 score weights
  float sS[4], sD[4];
  #pragma unroll
  for(int h=0;h<4;h++){
    float a=0.f, d=0.f;
    #pragma unroll
    for(int c=0;c<8;c++){ float wv=W1[h*8+c]; a+=wv*as1[h*8+c]; d+=wv*ad1[h*8+c]; }
    sS[h]=a; sD[h]=d;
  }

  const float* xsl = x_seq + (size_t)(b*T_+t)*N_;
  float xm = xsl[n];
  int e0=offs[node], e1=offs[node+1];
  float sum[4]={0.f,0.f,0.f,0.f}, ax[4]={0.f,0.f,0.f,0.f};
  for(int e=e0+q; e<e1; e+=4){
    float xv = xsl[csr[e]];
    #pragma unroll
    for(int h=0;h<4;h++){
      float ee = xv*sS[h] + xm*sD[h]; ee = ee>0.f ? ee : 0.2f*ee;
      float wv = __expf(ee); sum[h]+=wv; ax[h]+=wv*xv;
    }
  }
  // q-dimension lives in lane bits 4-5: butterfly over xor 16, 32
  #pragma unroll
  for(int h=0;h<4;h++){
    sum[h] += __shfl_xor(sum[h],16); sum[h] += __shfl_xor(sum[h],32);
    ax[h]  += __shfl_xor(ax[h],16);  ax[h]  += __shfl_xor(ax[h],32);
  }
  float A = ax[q]/(sum[q]+1e-16f);

  // fragment: out1[m][q*8+j] (A-layout == B-layout dual)
  half8 af;
  #pragma unroll
  for(int j=0;j<8;j++){
    float v = A*W1[q*8+j] + b1[q*8+j]; v = v>0.f?v:0.f;
    af[j] = (_Float16)v;
  }
  // swapped: D[ch][node]; ac_nt[rg] = h2[node m][nt*16 + q*4 + rg]
  f32x4 ac0={0.f,0.f,0.f,0.f}, ac1=ac0, ac2=ac0, ac3=ac0;
  ac0 = __builtin_amdgcn_mfma_f32_16x16x32_f16(w2f0, af, ac0,0,0,0);
  ac1 = __builtin_amdgcn_mfma_f32_16x16x32_f16(w2f1, af, ac1,0,0,0);
  ac2 = __builtin_amdgcn_mfma_f32_16x16x32_f16(w2f2, af, ac2,0,0,0);
  ac3 = __builtin_amdgcn_mfma_f32_16x16x32_f16(w2f3, af, ac3,0,0,0);

  size_t nd = (size_t)t*M_ + node;
  u16* row = h2u + nd*64;
  {
    uint2 p;
    p.x = (unsigned)f2bu(ac0[0]) | ((unsigned)f2bu(ac0[1])<<16);
    p.y = (unsigned)f2bu(ac0[2]) | ((unsigned)f2bu(ac0[3])<<16);
    *(uint2*)(row + 0*16 + q*4) = p;
    p.x = (unsigned)f2bu(ac1[0]) | ((unsigned)f2bu(ac1[1])<<16);
    p.y = (unsigned)f2bu(ac1[2]) | ((unsigned)f2bu(ac1[3])<<16);
    *(uint2*)(row + 1*16 + q*4) = p;
    p.x = (unsigned)f2bu(ac2[0]) | ((unsigned)f2bu(ac2[1])<<16);
    p.y = (unsigned)f2bu(ac2[2]) | ((unsigned)f2bu(ac2[3])<<16);
    *(uint2*)(row + 2*16 + q*4) = p;
    p.x = (unsigned)f2bu(ac3[0]) | ((unsigned)f2bu(ac3[1])<<16);
    p.y = (unsigned)f2bu(ac3[2]) | ((unsigned)f2bu(ac3[3])<<16);
    *(uint2*)(row + 3*16 + q*4) = p;
  }

  // asc/adc: per-head partial over this lane's 4 channels, butterfly over q
  const float* a2sp = as2 + q*4;
  const float* a2dp = ad2 + q*4;
  float ps[4], pd[4];
  ps[0]=ac0[0]*a2sp[ 0]+ac0[1]*a2sp[ 1]+ac0[2]*a2sp[ 2]+ac0[3]*a2sp[ 3];
  ps[1]=ac1[0]*a2sp[16]+ac1[1]*a2sp[17]+ac1[2]*a2sp[18]+ac1[3]*a2sp[19];
  ps[2]=ac2[0]*a2sp[32]+ac2[1]*a2sp[33]+ac2[2]*a2sp[34]+ac2[3]*a2sp[35];
  ps[3]=ac3[0]*a2sp[48]+ac3[1]*a2sp[49]+ac3[2]*a2sp[50]+ac3[3]*a2sp[51];
  pd[0]=ac0[0]*a2dp[ 0]+ac0[1]*a2dp[ 1]+ac0[2]*a2dp[ 2]+ac0[3]*a2dp[ 3];
  pd[1]=ac1[0]*a2dp[16]+ac1[1]*a2dp[17]+ac1[2]*a2dp[18]+ac1[3]*a2dp[19];
  pd[2]=ac2[0]*a2dp[32]+ac2[1]*a2dp[33]+ac2[2]*a2dp[34]+ac2[3]*a2dp[35];
  pd[3]=ac3[0]*a2dp[48]+ac3[1]*a2dp[49]+ac3[2]*a2dp[50]+ac3[3]*a2dp[51];
  #pragma unroll
  for(int h=0;h<4;h++){
    ps[h] += __shfl_xor(ps[h],16); ps[h] += __shfl_xor(ps[h],32);
    pd[h] += __shfl_xor(pd[h],16); pd[h] += __shfl_xor(pd[h],32);
  }
  // lane q stores head q (static selects, no runtime indexing)
  float ra = (q&1) ? ((q&2)? ps[3]:ps[1]) : ((q&2)? ps[2]:ps[0]);
  float rd = (q&1) ? ((q&2)? pd[3]:pd[1]) : ((q&2)? pd[2]:pd[0]);
  asc[nd*4+q] = ra;
  adc[nd*4+q] = rd;
}

// ---------------- GAT2 softmax-aggregate + bias + relu + PE(table); f16 out ------
// Round-8 lane-pair edge split; round-9: XCD-swizzled block mapping so each
// XCD gathers from a contiguous ~4000-node h2u slice (~512KB, L2-resident)
// instead of the full 4MB/t working set (L2 capacity thrash).
__global__ __launch_bounds__(256) void k_gat2b(
  const u16* __restrict__ h2u, const float* __restrict__ asc, const float* __restrict__ adc,
  const float* __restrict__ b2, const int* __restrict__ offs, const int* __restrict__ csr,
  const float* __restrict__ peT, u16* __restrict__ seq)
{
  int t = blockIdx.y;
  int id = xcd_swz(blockIdx.x, 1000)*256 + threadIdx.x;   // 1000*256 = M_*8
  int m = id>>3, j = (id>>2)&1, h = id&3;
  unsigned um=(unsigned)m, b=um/N_;
  size_t base_s = (size_t)t*M_ + (size_t)b*N_;   // csr holds local indices
  float am = adc[((size_t)t*M_+m)*4+h];
  int e0=offs[m], e1=offs[m+1];
  float sum=0.f;
  float A[16];
  #pragma unroll
  for(int c=0;c<16;c++) A[c]=0.f;
  for(int e=e0+j; e<e1; e+=2){
    size_t s = base_s + (unsigned)csr[e];
    float ee = asc[s*4+h] + am; ee = ee>0.f ? ee : 0.2f*ee;
    float w = __expf(ee); sum += w;
    const uint4* hp = (const uint4*)(h2u + s*64 + h*16);
    uint4 p0 = hp[0], p1 = hp[1];
    A[ 0] += w*bfu((u16)(p0.x)); A[ 1] += w*bfu((u16)(p0.x>>16));
    A[ 2] += w*bfu((u16)(p0.y)); A[ 3] += w*bfu((u16)(p0.y>>16));
    A[ 4] += w*bfu((u16)(p0.z)); A[ 5] += w*bfu((u16)(p0.z>>16));
    A[ 6] += w*bfu((u16)(p0.w)); A[ 7] += w*bfu((u16)(p0.w>>16));
    A[ 8] += w*bfu((u16)(p1.x)); A[ 9] += w*bfu((u16)(p1.x>>16));
    A[10] += w*bfu((u16)(p1.y)); A[11] += w*bfu((u16)(p1.y>>16));
    A[12] += w*bfu((u16)(p1.z)); A[13] += w*bfu((u16)(p1.z>>16));
    A[14] += w*bfu((u16)(p1.w)); A[15] += w*bfu((u16)(p1.w>>16));
  }
  // merge the two edge-halves (partner lane: id xor 4 == tid xor 4)
  sum += __shfl_xor(sum,4);
  #pragma unroll
  for(int c=0;c<16;c++) A[c] += __shfl_xor(A[c],4);

  float inv = 1.f/(sum + 1e-16f);
  u16 ov[8];
  #pragma unroll
  for(int c=0;c<8;c++){
    int ch = h*16 + j*8 + c;
    float v = A[j*8+c]*inv + b2[ch]; v = v>0.f ? v : 0.f;
    ov[c] = f2h(v + peT[t*64+ch]);
  }
  uint4 o;
  o.x = (unsigned)ov[0] | ((unsigned)ov[1]<<16);
  o.y = (unsigned)ov[2] | ((unsigned)ov[3]<<16);
  o.z = (unsigned)ov[4] | ((unsigned)ov[5]<<16);
  o.w = (unsigned)ov[6] | ((unsigned)ov[7]<<16);
  *(uint4*)(seq + ((size_t)t*M_ + m)*64 + h*16 + j*8) = o;
}

// ---------------- BOTH transformer layers + fused head (R16-measured form) -------
// X u16 [48][72]: layer input (wave-private rows). QKV u16 [3][48][72]; K,V
// overlaid by H[48][136]. A = activations (standard orientation; the operand
// swap was tried TWICE and both times tripled LDS bank conflicts -- do not
// retry). Register-carried residual (xres) was tried once: VGPR 68->84,
// VALUBusy -15pts, +48us -- do not retry. UNCHANGED since round 4.
__global__ __launch_bounds__(192) void k_layer2(
  const u16* __restrict__ seq,
  const u16* __restrict__ wqB, const u16* __restrict__ woB,
  const u16* __restrict__ w1B, const u16* __restrict__ w2B,
  const float* __restrict__ bqkv, const float* __restrict__ bo,
  const float* __restrict__ bf1,  const float* __restrict__ bf2,
  const float* __restrict__ g1,   const float* __restrict__ be1,
  const float* __restrict__ g2,   const float* __restrict__ be2,
  const float* __restrict__ Wh,   const float* __restrict__ bh,
  float* __restrict__ out)
{
  __shared__ __align__(16) u16 X[3456];      // [48][72] f16
  __shared__ __align__(16) u16 QKV[10368];   // [3][48][72]
  u16* Hd = QKV + 3456;                      // H[48][136] overlays K,V
  int tid=threadIdx.x, w=tid>>6, lane=tid&63;
  int m=lane&15, q=lane>>4;
  int r = w*16 + m;

  // stage X: wave w loads its own 16 rows (wave-private, no barrier needed).
  // Each row = 128B = 8 lanes x 16B; 2 dwordx4 loads/lane replace 16 scalar.
  #pragma unroll
  for(int half=0; half<2; half++){
    int rr = half*8 + (lane>>3);
    int row = w*16 + rr;
    int nn = row/12, tt = row-nn*12;
    const uint4* src = (const uint4*)(seq + ((size_t)tt*M_ + (size_t)blockIdx.x*4+nn)*64) + (lane&7);
    *((uint4*)&X[row*72] + (lane&7)) = *src;
  }

  #pragma unroll 1
  for(int l=0; l<2; l++){
    const half8* wqv = (const half8*)(wqB + (size_t)l*12288);
    const half8* wov = (const half8*)(woB + (size_t)l*4096);
    const half8* w1v = (const half8*)(w1B + (size_t)l*8192);
    const half8* w2v = (const half8*)(w2B + (size_t)l*8192);
    const float* bq = bqkv + l*192;
    const float* boL = bo + l*64;
    const float* b1L = bf1 + l*128;
    const float* b2L = bf2 + l*64;
    const float* g1L = g1 + l*64, *be1L = be1 + l*64;
    const float* g2L = g2 + l*64, *be2L = be2 + l*64;

    // ---- QKV projection: A-frags from X (wave-own rows) ----
    half8 xa0 = *(const half8*)&X[r*72 + q*8];
    half8 xa1 = *(const half8*)&X[r*72 + 32 + q*8];
    #pragma unroll
    for(int nt=0; nt<12; nt++){
      f32x4 acc={0.f,0.f,0.f,0.f};
      acc = __builtin_amdgcn_mfma_f32_16x16x32_f16(xa0, wqv[(nt*2+0)*64+lane], acc,0,0,0);
      acc = __builtin_amdgcn_mfma_f32_16x16x32_f16(xa1, wqv[(nt*2+1)*64+lane], acc,0,0,0);
      int cg = nt*16+m; float bias = bq[cg];
      int s = nt>>2, lc = cg&63;
      #pragma unroll
      for(int rg=0;rg<4;rg++){
        int row = w*16 + q*4 + rg;
        QKV[s*3456 + row*72 + lc] = f2h(acc[rg]+bias);
      }
    }
    __syncthreads();

    // ---- attention: 192 lanes = (node an, head ah, time at); fdot2 + pk_fma ----
    {
      int an = tid/48, rem = tid - an*48;
      int ah = rem/12, at = rem - ah*12;
      u16* qrow = &QKV[(an*12+at)*72 + ah*16];
      uint4 qa = ((const uint4*)qrow)[0], qb = ((const uint4*)qrow)[1];
      float s[12];
      #pragma unroll
      for(int t2=0;t2<12;t2++){
        const uint4* kp = (const uint4*)&QKV[3456 + (an*12+t2)*72 + ah*16];
        uint4 ka=kp[0], kb=kp[1];
        float d=0.f;
        d=__builtin_amdgcn_fdot2(u2h(qa.x),u2h(ka.x),d,false);
        d=__builtin_amdgcn_fdot2(u2h(qa.y),u2h(ka.y),d,false);
        d=__builtin_amdgcn_fdot2(u2h(qa.z),u2h(ka.z),d,false);
        d=__builtin_amdgcn_fdot2(u2h(qa.w),u2h(ka.w),d,false);
        d=__builtin_amdgcn_fdot2(u2h(qb.x),u2h(kb.x),d,false);
        d=__builtin_amdgcn_fdot2(u2h(qb.y),u2h(kb.y),d,false);
        d=__builtin_amdgcn_fdot2(u2h(qb.z),u2h(kb.z),d,false);
        d=__builtin_amdgcn_fdot2(u2h(qb.w),u2h(kb.w),d,false);
        s[t2] = d*0.25f;
      }
      float mx=s[0];
      #pragma unroll
      for(int t2=1;t2<12;t2++) mx=fmaxf(mx,s[t2]);
      float sum=0.f;
      #pragma unroll
      for(int t2=0;t2<12;t2++){ s[t2]=__expf(s[t2]-mx); sum+=s[t2]; }
      float inv=1.f/sum;
      half8 o0, o1;
      #pragma unroll
      for(int i=0;i<8;i++){ o0[i]=(_Float16)0.f; o1[i]=(_Float16)0.f; }
      #pragma unroll
      for(int t2=0;t2<12;t2++){
        const half8* vr = (const half8*)&QKV[6912 + (an*12+t2)*72 + ah*16];
        _Float16 wh = (_Float16)s[t2];
        o0 += vr[0]*wh; o1 += vr[1]*wh;
      }
      _Float16 ih = (_Float16)inv;
      ((half8*)qrow)[0]=o0*ih; ((half8*)qrow)[1]=o1*ih;
    }
    __syncthreads();

    // ---- Wo + residual(X) + LN1 ----
    half8 oa0 = *(const half8*)&QKV[r*72 + q*8];
    half8 oa1 = *(const half8*)&QKV[r*72 + 32 + q*8];
    float y[4][4];
    #pragma unroll
    for(int nt=0;nt<4;nt++){
      f32x4 acc={0.f,0.f,0.f,0.f};
      acc = __builtin_amdgcn_mfma_f32_16x16x32_f16(oa0, wov[(nt*2+0)*64+lane], acc,0,0,0);
      acc = __builtin_amdgcn_mfma_f32_16x16x32_f16(oa1, wov[(nt*2+1)*64+lane], acc,0,0,0);
      int col=nt*16+m; float bias=boL[col];
      #pragma unroll
      for(int rg=0;rg<4;rg++)
        y[nt][rg] = acc[rg] + bias + h2f(X[(w*16+q*4+rg)*72 + col]);
    }
    float mu[4], rs[4];
    #pragma unroll
    for(int rg=0;rg<4;rg++){
      float sm=(y[0][rg]+y[1][rg])+(y[2][rg]+y[3][rg]);
      sm+=__shfl_xor(sm,1); sm+=__shfl_xor(sm,2); sm+=__shfl_xor(sm,4); sm+=__shfl_xor(sm,8);
      mu[rg]=sm*(1.f/64.f);
      float d0=y[0][rg]-mu[rg],d1=y[1][rg]-mu[rg],d2=y[2][rg]-mu[rg],d3=y[3][rg]-mu[rg];
      float vv=(d0*d0+d1*d1)+(d2*d2+d3*d3);
      vv+=__shfl_xor(vv,1); vv+=__shfl_xor(vv,2); vv+=__shfl_xor(vv,4); vv+=__shfl_xor(vv,8);
      rs[rg]=rsqrtf(vv*(1.f/64.f)+1e-5f);
    }
    #pragma unroll
    for(int nt=0;nt<4;nt++){
      int col=nt*16+m; float g=g1L[col], be=be1L[col];
      #pragma unroll
      for(int rg=0;rg<4;rg++){
        float v=(y[nt][rg]-mu[rg])*rs[rg]*g+be;
        y[nt][rg]=v;                                  // FF residual (f32)
        QKV[(w*16+q*4+rg)*72 + col]=f2h(v);           // y -> wave-own rows
      }
    }

    // ---- FF1: y A-frags; H -> pitch-136 overlay ----
    half8 ya0 = *(const half8*)&QKV[r*72 + q*8];
    half8 ya1 = *(const half8*)&QKV[r*72 + 32 + q*8];
    #pragma unroll
    for(int nt=0;nt<8;nt++){
      f32x4 acc={0.f,0.f,0.f,0.f};
      acc = __builtin_amdgcn_mfma_f32_16x16x32_f16(ya0, w1v[(nt*2+0)*64+lane], acc,0,0,0);
      acc = __builtin_amdgcn_mfma_f32_16x16x32_f16(ya1, w1v[(nt*2+1)*64+lane], acc,0,0,0);
      float bias=b1L[nt*16+m];
      #pragma unroll
      for(int rg=0;rg<4;rg++)
        Hd[(w*16+q*4+rg)*136 + nt*16+m] = f2h(fmaxf(acc[rg]+bias, 0.f));
    }

    // ---- FF2 + residual y + LN2 ----
    half8 ha[4];
    #pragma unroll
    for(int c=0;c<4;c++)
      ha[c] = *(const half8*)&Hd[r*136 + c*32 + q*8];
    #pragma unroll
    for(int nt=0;nt<4;nt++){
      f32x4 acc={0.f,0.f,0.f,0.f};
      #pragma unroll
      for(int c=0;c<4;c++)
        acc = __builtin_amdgcn_mfma_f32_16x16x32_f16(ha[c], w2v[(nt*4+c)*64+lane], acc,0,0,0);
      int col=nt*16+m; float bias=b2L[col];
      #pragma unroll
      for(int rg=0;rg<4;rg++)
        y[nt][rg] = acc[rg] + bias + y[nt][rg];
    }
    #pragma unroll
    for(int rg=0;rg<4;rg++){
      float sm=(y[0][rg]+y[1][rg])+(y[2][rg]+y[3][rg]);
      sm+=__shfl_xor(sm,1); sm+=__shfl_xor(sm,2); sm+=__shfl_xor(sm,4); sm+=__shfl_xor(sm,8);
      mu[rg]=sm*(1.f/64.f);
      float d0=y[0][rg]-mu[rg],d1=y[1][rg]-mu[rg],d2=y[2][rg]-mu[rg],d3=y[3][rg]-mu[rg];
      float vv=(d0*d0+d1*d1)+(d2*d2+d3*d3);
      vv+=__shfl_xor(vv,1); vv+=__shfl_xor(vv,2); vv+=__shfl_xor(vv,4); vv+=__shfl_xor(vv,8);
      rs[rg]=rsqrtf(vv*(1.f/64.f)+1e-5f);
    }
    if(l==0){
      #pragma unroll
      for(int nt=0;nt<4;nt++){
        int col=nt*16+m; float g=g2L[col], be=be2L[col];
        #pragma unroll
        for(int rg=0;rg<4;rg++)
          X[(w*16+q*4+rg)*72 + col] = f2h((y[nt][rg]-mu[rg])*rs[rg]*g + be);
      }
      __syncthreads();   // before next layer's QKV scatter overwrites QKV regions
    } else {
      // fused prediction head: rows with t==11 are rg==3 of exactly one
      // q-group per node; condition uniform over the 16-lane m-group.
      int rc = w*16 + q*4 + 3;
      int nn = rc/12;
      if(rc - nn*12 == 11){
        float vfin[4];
        #pragma unroll
        for(int nt=0;nt<4;nt++){
          int col=nt*16+m;
          vfin[nt] = (y[nt][3]-mu[3])*rs[3]*g2L[col] + be2L[col];
        }
        int gm = blockIdx.x*4 + nn;
        unsigned bb=(unsigned)gm/N_, n2=(unsigned)gm-bb*N_;
        #pragma unroll
        for(int h3=0;h3<3;h3++){
          float p = vfin[0]*Wh[h3*64+m]    + vfin[1]*Wh[h3*64+16+m]
                  + vfin[2]*Wh[h3*64+32+m] + vfin[3]*Wh[h3*64+48+m];
          p += __shfl_xor(p,1); p += __shfl_xor(p,2);
          p += __shfl_xor(p,4); p += __shfl_xor(p,8);
          if(m==0) out[(bb*3+h3)*N_+n2] = p + bh[h3];
        }
      }
    }
  }
}

extern "C" void kernel_launch(void* const* d_in, const int* in_sizes, int n_in,
                              void* d_out, int out_size, void* d_ws, size_t ws_size,
                              hipStream_t stream)
{
  const float* x_seq=(const float*)d_in[0];
  const int*   ei   =(const int*)d_in[1];
  const float* W1   =(const float*)d_in[2];
  const float* as1  =(const float*)d_in[3];
  const float* ad1  =(const float*)d_in[4];
  const float* b1   =(const float*)d_in[5];
  const float* W2   =(const float*)d_in[6];
  const float* as2  =(const float*)d_in[7];
  const float* ad2  =(const float*)d_in[8];
  const float* b2   =(const float*)d_in[9];
  const float* Wqkv =(const float*)d_in[10];
  const float* bqkv =(const float*)d_in[11];
  const float* Wo   =(const float*)d_in[12];
  const float* bo   =(const float*)d_in[13];
  const float* Wf1  =(const float*)d_in[14];
  const float* bf1p =(const float*)d_in[15];
  const float* Wf2  =(const float*)d_in[16];
  const float* bf2p =(const float*)d_in[17];
  const float* g1   =(const float*)d_in[18];
  const float* be1  =(const float*)d_in[19];
  const float* g2   =(const float*)d_in[20];
  const float* be2  =(const float*)d_in[21];
  const float* Wh   =(const float*)d_in[22];
  const float* bh   =(const float*)d_in[23];

  // workspace layout (~112 MB)
  u16* seqh   = (u16*)d_ws;                     // [T][M][64] f16  24,576,000 u16
  float* asc  = (float*)(seqh + 24576000);      // [T][M][4]        1,536,000 f
  float* adc  = asc + 1536000;                  //                  1,536,000 f
  int* deg    = (int*)(adc + 1536000);
  int* cursor = deg + M_;
  int* offs   = cursor + M_;                    // M_+1 used
  int* bsums  = offs + (M_ + 2);
  int* boffs  = bsums + 128;
  int* csr    = boffs + 128;                    // ETOT
  u16* h2u    = (u16*)(csr + ETOT);             // [T][M][64]   24,576,000 u16
  u16* wqB    = h2u + (size_t)T_*M_*64;         // 24576
  u16* woB    = wqB + 24576;                    // 8192
  u16* w1B    = woB + 8192;                     // 16384
  u16* w2B    = w1B + 16384;                    // 16384
  float* peT  = (float*)(w2B + 16384);          // 768
  u16* w2gB   = (u16*)(peT + 768);              // 2048

  k_prep   <<<dim3(268), dim3(256), 0, stream>>>(Wqkv, Wo, Wf1, Wf2, W2,
                                                 wqB, woB, w1B, w2B, peT, w2gB);

  // CSR build (edge list identical for all t)
  hipMemsetAsync(deg, 0, (size_t)2*M_*sizeof(int), stream);   // deg + cursor
  k_hist   <<<dim3((ETOT+255)/256), dim3(256), 0, stream>>>(ei, deg);
  k_scan1  <<<dim3(125), dim3(256), 0, stream>>>(deg, offs, bsums);
  k_scan23 <<<dim3(125), dim3(256), 0, stream>>>(offs, bsums);
  k_scatter<<<dim3((ETOT+255)/256), dim3(256), 0, stream>>>(ei, offs, cursor, csr);

  k_gat12<<<dim3(500,T_), dim3(256), 0, stream>>>(x_seq, W1, as1, ad1, b1,
                                                  as2, ad2, offs, csr, w2gB,
                                                  h2u, asc, adc);
  k_gat2b<<<dim3(1000,T_), dim3(256), 0, stream>>>(h2u, asc, adc, b2, offs, csr, peT, seqh);

  k_layer2<<<dim3(8000), dim3(192), 0, stream>>>(seqh,
      wqB, woB, w1B, w2B,
      bqkv, bo, bf1p, bf2p,
      g1, be1, g2, be2,
      Wh, bh, (float*)d_out);
}